// Round 1
// baseline (3357.090 us; speedup 1.0000x reference)
//
#include <hip/hip_runtime.h>
#include <math.h>

#define BB 8
#define LL 4096
#define DD 64
#define KK 24
#define NN 8192
#define LOGN 13

typedef float2 cplx;

__device__ __forceinline__ float bf16_to_f(unsigned short h) {
    union { unsigned u; float f; } v; v.u = ((unsigned)h) << 16; return v.f;
}

// ---------------- FFT primitives (in-LDS, 256 threads, N=8192) ----------------
// DIF forward: natural-order input -> bit-reversed output, sign = -1
__device__ __forceinline__ void fft_dif(float2* a) {
    const int tid = threadIdx.x;
    for (int lh = LOGN - 1; lh >= 0; --lh) {
        const int half = 1 << lh;
        const float tw = -6.28318530717958647692f / (float)(2 << lh);
#pragma unroll
        for (int bb = 0; bb < NN / 2 / 256; ++bb) {
            int t = tid + (bb << 8);
            int j = t & (half - 1);
            int i0 = ((t >> lh) << (lh + 1)) + j;
            float2 u = a[i0], v = a[i0 + half];
            float sn, cs;
            __sincosf(tw * (float)j, &sn, &cs);
            float dx = u.x - v.x, dy = u.y - v.y;
            a[i0] = make_float2(u.x + v.x, u.y + v.y);
            a[i0 + half] = make_float2(dx * cs - dy * sn, dx * sn + dy * cs);
        }
        __syncthreads();
    }
}

// DIT inverse: bit-reversed input -> natural output, sign = +1, NO 1/N scale
__device__ __forceinline__ void fft_dit(float2* a) {
    const int tid = threadIdx.x;
    for (int lh = 0; lh < LOGN; ++lh) {
        const int half = 1 << lh;
        const float tw = 6.28318530717958647692f / (float)(2 << lh);
#pragma unroll
        for (int bb = 0; bb < NN / 2 / 256; ++bb) {
            int t = tid + (bb << 8);
            int j = t & (half - 1);
            int i0 = ((t >> lh) << (lh + 1)) + j;
            float2 u = a[i0], v = a[i0 + half];
            float sn, cs;
            __sincosf(tw * (float)j, &sn, &cs);
            float wx = v.x * cs - v.y * sn;
            float wy = v.x * sn + v.y * cs;
            a[i0] = make_float2(u.x + wx, u.y + wy);
            a[i0 + half] = make_float2(u.x - wx, u.y - wy);
        }
        __syncthreads();
    }
}

// ---------------- kernels ----------------

__global__ __launch_bounds__(256) void k_tobf16(const float* __restrict__ src,
                                                unsigned short* __restrict__ dst, int n) {
    int i = blockIdx.x * 256 + threadIdx.x;
    if (i < n) {
        union { float f; unsigned u; } v; v.f = src[i];
        unsigned r = (v.u + 0x7FFFu + ((v.u >> 16) & 1u)) >> 16;
        dst[i] = (unsigned short)r;
    }
}

// V[f,k] = FFT(eig_vecs[:,k] * lambda_k^0.25 / N), all 8192 bins (bit-reversed order)
__global__ __launch_bounds__(256) void k_fft_filters(const float* __restrict__ eig_vals,
                                                     const float* __restrict__ eig_vecs,
                                                     float2* __restrict__ Vb) {
    __shared__ float2 a[NN];
    const int k = blockIdx.x, tid = threadIdx.x;
    const float alpha = powf(eig_vals[k], 0.25f) * (1.0f / (float)NN);
    for (int t = tid; t < LL; t += 256)
        a[t] = make_float2(eig_vecs[t * KK + k] * alpha, 0.f);
    for (int t = LL + tid; t < NN; t += 256)
        a[t] = make_float2(0.f, 0.f);
    __syncthreads();
    fft_dif(a);
    for (int r = tid; r < NN; r += 256)
        Vb[(size_t)r * KK + k] = a[r];
}

// U[b,f,c] = FFT(x[b,:,c] zero-padded), bit-reversed bins
__global__ __launch_bounds__(256) void k_fft_x(const float* __restrict__ x,
                                               float2* __restrict__ Ub) {
    __shared__ float2 a[NN];
    const int b = blockIdx.x >> 6, c = blockIdx.x & 63;
    const int tid = threadIdx.x;
    for (int l = tid; l < LL; l += 256)
        a[l] = make_float2(x[((size_t)b * LL + l) * DD + c], 0.f);
    for (int l = LL + tid; l < NN; l += 256)
        a[l] = make_float2(0.f, 0.f);
    __syncthreads();
    fft_dif(a);
    for (int r = tid; r < NN; r += 256)
        Ub[((size_t)b * NN + r) * DD + c] = a[r];
}

// Per-frequency: G[c,o] = sum_k V[f,k]*mphi[k*64+c,o]; S[b,f,o] = sum_c U[b,f,c]*G[c,o]
// Sb may alias Ub (each wg reads its f's U into LDS before overwriting).
#define FT 8
__global__ __launch_bounds__(256) void k_modulate(const float2* __restrict__ Vb,
                                                  const float2* __restrict__ Ub,
                                                  const unsigned short* __restrict__ mphi_b,
                                                  float2* __restrict__ Sb) {
    __shared__ __align__(16) float2 Gs[4096];
    __shared__ __align__(16) float2 Us[512];
    __shared__ float2 Vs[KK];
    const int tid = threadIdx.x;
    const int b2 = tid >> 5;   // 0..7
    const int op = tid & 31;   // o-pair
    for (int fi = 0; fi < FT; ++fi) {
        const int f = blockIdx.x * FT + fi;
        if (tid < KK) Vs[tid] = Vb[(size_t)f * KK + tid];
        {
            int e = tid;
            Us[e] = Ub[((size_t)(e >> 6) * NN + f) * DD + (e & 63)];
            e += 256;
            Us[e] = Ub[((size_t)(e >> 6) * NN + f) * DD + (e & 63)];
        }
        __syncthreads();
#pragma unroll
        for (int e = tid; e < 4096; e += 256) {
            int c = e >> 6, o = e & 63;
            float gx = 0.f, gy = 0.f;
#pragma unroll
            for (int k = 0; k < KK; ++k) {
                float m = bf16_to_f(mphi_b[(k * 64 + c) * 64 + o]);
                gx += Vs[k].x * m;
                gy += Vs[k].y * m;
            }
            Gs[e] = make_float2(gx, gy);
        }
        __syncthreads();
        {
            float s0x = 0.f, s0y = 0.f, s1x = 0.f, s1y = 0.f;
#pragma unroll
            for (int c = 0; c < 64; ++c) {
                float2 u = Us[b2 * 64 + c];
                float4 g = *(const float4*)&Gs[c * 64 + op * 2];
                s0x += u.x * g.x - u.y * g.y;
                s0y += u.x * g.y + u.y * g.x;
                s1x += u.x * g.z - u.y * g.w;
                s1y += u.x * g.w + u.y * g.z;
            }
            size_t base = ((size_t)b2 * NN + f) * DD + op * 2;
            Sb[base]     = make_float2(s0x, s0y);
            Sb[base + 1] = make_float2(s1x, s1y);
        }
        __syncthreads();
    }
}

// delta_phi[b,l,o] = Re(IFFT(S[b,:,o]))[l]
__global__ __launch_bounds__(256) void k_ifft(const float2* __restrict__ Sb,
                                              float* __restrict__ deltas) {
    __shared__ float2 a[NN];
    const int b = blockIdx.x >> 6, o = blockIdx.x & 63;
    const int tid = threadIdx.x;
    for (int r = tid; r < NN; r += 256)
        a[r] = Sb[((size_t)b * NN + r) * DD + o];
    __syncthreads();
    fft_dit(a);
    for (int l = tid; l < LL; l += 256)
        deltas[((size_t)b * LL + l) * DD + o] = a[l].x;
}

// deltas += AR-U: sum_{ku<=2} m_u[o,i,ku]*x[l-ku,i]  (32 l-rows per block)
__global__ __launch_bounds__(256) void k_aru(const float* __restrict__ x,
                                             const float* __restrict__ m_u,
                                             float* __restrict__ deltas) {
    __shared__ float mu_s[64 * 193];        // [o][i*3+ku] padded (193)
    __shared__ float xs[34 * 64];           // rows l0-2 .. l0+31
    const int tid = threadIdx.x;
    const int b = blockIdx.x >> 7;
    const int l0 = (blockIdx.x & 127) * 32;
    for (int idx = tid; idx < 64 * 192; idx += 256) {
        int o = idx / 192;
        int rem = idx - o * 192;
        mu_s[o * 193 + rem] = m_u[idx];
    }
    for (int idx = tid; idx < 34 * 64; idx += 256) {
        int rr = idx >> 6, i = idx & 63;
        int gl = l0 - 2 + rr;
        xs[idx] = (gl >= 0) ? x[((size_t)b * LL + gl) * DD + i] : 0.f;
    }
    __syncthreads();
    const int o = tid & 63, lsub = tid >> 6;
    for (int lb = 0; lb < 8; ++lb) {
        int ll = lsub * 8 + lb;
        int r = ll + 2;
        float acc = 0.f;
#pragma unroll
        for (int i = 0; i < 64; ++i) {
            int mb = o * 193 + i * 3;
            acc += mu_s[mb]     * xs[r * 64 + i]
                 + mu_s[mb + 1] * xs[(r - 1) * 64 + i]
                 + mu_s[mb + 2] * xs[(r - 2) * 64 + i];
        }
        deltas[((size_t)b * LL + l0 + ll) * DD + o] += acc;
    }
}

// Companion matrix M (128x128): rows<64: [A1|A2]=m_y[r*128+c]; rows>=64: shifted identity
__global__ __launch_bounds__(256) void k_companion(const float* __restrict__ m_y,
                                                   float* __restrict__ M) {
    int idx = blockIdx.x * 256 + threadIdx.x;
    int r = idx >> 7, c = idx & 127;
    M[idx] = (r < 64) ? m_y[r * 128 + c] : ((c == r - 64) ? 1.f : 0.f);
}

__global__ __launch_bounds__(256) void k_matsq(const float* __restrict__ A,
                                               float* __restrict__ C) {
    int idx = blockIdx.x * 256 + threadIdx.x;
    int r = idx >> 7, c = idx & 127;
    float acc = 0.f;
#pragma unroll
    for (int i = 0; i < 128; ++i) acc += A[r * 128 + i] * A[i * 128 + c];
    C[idx] = acc;
}

// F1: per (b, chunk j): zero-init local recurrence, record terminal state [y63;y62]
__global__ __launch_bounds__(64, 1) void k_chunk_local(const float* __restrict__ deltas,
                                                       const float* __restrict__ m_y,
                                                       float* __restrict__ term) {
    const int b = blockIdx.x >> 6, j = blockIdx.x & 63;
    const int o = threadIdx.x;
    __shared__ __align__(16) float y1s[64];
    __shared__ __align__(16) float y2s[64];
    float a1r[64], a2r[64];
#pragma unroll
    for (int i4 = 0; i4 < 16; ++i4) {
        float4 v1 = *(const float4*)&m_y[o * 128 + i4 * 4];
        float4 v2 = *(const float4*)&m_y[o * 128 + 64 + i4 * 4];
        a1r[4 * i4] = v1.x; a1r[4 * i4 + 1] = v1.y; a1r[4 * i4 + 2] = v1.z; a1r[4 * i4 + 3] = v1.w;
        a2r[4 * i4] = v2.x; a2r[4 * i4 + 1] = v2.y; a2r[4 * i4 + 2] = v2.z; a2r[4 * i4 + 3] = v2.w;
    }
    y1s[o] = 0.f; y2s[o] = 0.f;
    __syncthreads();
    const float* dl = &deltas[(((size_t)b * LL) + j * 64) * DD + o];
    for (int t = 0; t < 64; ++t) {
        float acc = dl[t * DD];
#pragma unroll
        for (int i4 = 0; i4 < 16; ++i4) {
            float4 w1 = *(const float4*)&y1s[i4 * 4];
            float4 w2 = *(const float4*)&y2s[i4 * 4];
            acc += a1r[4 * i4] * w1.x + a1r[4 * i4 + 1] * w1.y + a1r[4 * i4 + 2] * w1.z + a1r[4 * i4 + 3] * w1.w
                 + a2r[4 * i4] * w2.x + a2r[4 * i4 + 1] * w2.y + a2r[4 * i4 + 2] * w2.z + a2r[4 * i4 + 3] * w2.w;
        }
        __syncthreads();
        y2s[o] = y1s[o];
        y1s[o] = acc;
        __syncthreads();
    }
    term[((size_t)b * 64 + j) * 128 + o] = y1s[o];
    term[((size_t)b * 64 + j) * 128 + 64 + o] = y2s[o];
}

// F2: per batch, sequential over 64 chunk boundaries: s_{j+1} = M^64 s_j + term_j
__global__ __launch_bounds__(128, 1) void k_boundary(const float* __restrict__ P,
                                                     const float* __restrict__ term,
                                                     float* __restrict__ sstate) {
    const int b = blockIdx.x;
    const int r = threadIdx.x;
    __shared__ __align__(16) float scur[128];
    float p[128];
#pragma unroll
    for (int i4 = 0; i4 < 32; ++i4) {
        float4 v = *(const float4*)&P[r * 128 + i4 * 4];
        p[4 * i4] = v.x; p[4 * i4 + 1] = v.y; p[4 * i4 + 2] = v.z; p[4 * i4 + 3] = v.w;
    }
    scur[r] = 0.f;
    __syncthreads();
    for (int j = 0; j < 64; ++j) {
        sstate[((size_t)b * 64 + j) * 128 + r] = scur[r];
        float acc = term[((size_t)b * 64 + j) * 128 + r];
#pragma unroll
        for (int i4 = 0; i4 < 32; ++i4) {
            float4 w = *(const float4*)&scur[i4 * 4];
            acc += p[4 * i4] * w.x + p[4 * i4 + 1] * w.y + p[4 * i4 + 2] * w.z + p[4 * i4 + 3] * w.w;
        }
        __syncthreads();
        scur[r] = acc;
        __syncthreads();
    }
}

// F3: per (b, chunk j): recurrence with true initial state, write outputs
__global__ __launch_bounds__(64, 1) void k_chunk_final(const float* __restrict__ deltas,
                                                       const float* __restrict__ m_y,
                                                       const float* __restrict__ sstate,
                                                       float* __restrict__ out) {
    const int b = blockIdx.x >> 6, j = blockIdx.x & 63;
    const int o = threadIdx.x;
    __shared__ __align__(16) float y1s[64];
    __shared__ __align__(16) float y2s[64];
    float a1r[64], a2r[64];
#pragma unroll
    for (int i4 = 0; i4 < 16; ++i4) {
        float4 v1 = *(const float4*)&m_y[o * 128 + i4 * 4];
        float4 v2 = *(const float4*)&m_y[o * 128 + 64 + i4 * 4];
        a1r[4 * i4] = v1.x; a1r[4 * i4 + 1] = v1.y; a1r[4 * i4 + 2] = v1.z; a1r[4 * i4 + 3] = v1.w;
        a2r[4 * i4] = v2.x; a2r[4 * i4 + 1] = v2.y; a2r[4 * i4 + 2] = v2.z; a2r[4 * i4 + 3] = v2.w;
    }
    y1s[o] = sstate[((size_t)b * 64 + j) * 128 + o];
    y2s[o] = sstate[((size_t)b * 64 + j) * 128 + 64 + o];
    __syncthreads();
    const size_t base = (((size_t)b * LL) + j * 64) * DD + o;
    for (int t = 0; t < 64; ++t) {
        float acc = deltas[base + (size_t)t * DD];
#pragma unroll
        for (int i4 = 0; i4 < 16; ++i4) {
            float4 w1 = *(const float4*)&y1s[i4 * 4];
            float4 w2 = *(const float4*)&y2s[i4 * 4];
            acc += a1r[4 * i4] * w1.x + a1r[4 * i4 + 1] * w1.y + a1r[4 * i4 + 2] * w1.z + a1r[4 * i4 + 3] * w1.w
                 + a2r[4 * i4] * w2.x + a2r[4 * i4 + 1] * w2.y + a2r[4 * i4 + 2] * w2.z + a2r[4 * i4 + 3] * w2.w;
        }
        out[base + (size_t)t * DD] = acc;
        __syncthreads();
        y2s[o] = y1s[o];
        y1s[o] = acc;
        __syncthreads();
    }
}

extern "C" void kernel_launch(void* const* d_in, const int* in_sizes, int n_in,
                              void* d_out, int out_size, void* d_ws, size_t ws_size,
                              hipStream_t stream) {
    const float* x        = (const float*)d_in[0];
    const float* m_y      = (const float*)d_in[1];
    const float* m_u      = (const float*)d_in[2];
    const float* m_phi    = (const float*)d_in[3];
    const float* eig_vals = (const float*)d_in[4];
    const float* eig_vecs = (const float*)d_in[5];
    float* out = (float*)d_out;

    char* ws = (char*)d_ws;
    size_t off = 0;
    auto alloc = [&](size_t bytes) -> void* {
        void* p = ws + off;
        off += (bytes + 255) & ~(size_t)255;
        return p;
    };
    float2* Vb          = (float2*)alloc((size_t)NN * KK * sizeof(float2));        // 1.5 MB
    float2* Ub          = (float2*)alloc((size_t)BB * NN * DD * sizeof(float2));   // 33.5 MB
    float*  deltas      = (float*)alloc((size_t)BB * LL * DD * sizeof(float));     // 8.4 MB
    unsigned short* mphib = (unsigned short*)alloc((size_t)KK * 64 * 64 * sizeof(unsigned short));
    float*  mats        = (float*)alloc((size_t)3 * 128 * 128 * sizeof(float));
    float*  term        = (float*)alloc((size_t)BB * 64 * 128 * sizeof(float));
    float*  sst         = (float*)alloc((size_t)BB * 64 * 128 * sizeof(float));
    float2* Sb = Ub;  // modulate is safely in-place per frequency

    k_tobf16<<<dim3(384), dim3(256), 0, stream>>>(m_phi, mphib, KK * 64 * 64);
    k_fft_filters<<<dim3(24), dim3(256), 0, stream>>>(eig_vals, eig_vecs, Vb);
    k_fft_x<<<dim3(512), dim3(256), 0, stream>>>(x, Ub);

    k_companion<<<dim3(64), dim3(256), 0, stream>>>(m_y, mats);
    float* Am = mats;
    float* Bm = mats + 16384;
    float* Cm = mats + 32768;
    k_matsq<<<dim3(64), dim3(256), 0, stream>>>(Am, Bm);  // M^2
    k_matsq<<<dim3(64), dim3(256), 0, stream>>>(Bm, Cm);  // M^4
    k_matsq<<<dim3(64), dim3(256), 0, stream>>>(Cm, Bm);  // M^8
    k_matsq<<<dim3(64), dim3(256), 0, stream>>>(Bm, Cm);  // M^16
    k_matsq<<<dim3(64), dim3(256), 0, stream>>>(Cm, Bm);  // M^32
    k_matsq<<<dim3(64), dim3(256), 0, stream>>>(Bm, Cm);  // M^64 -> Cm

    k_modulate<<<dim3(NN / FT), dim3(256), 0, stream>>>(Vb, Ub, mphib, Sb);
    k_ifft<<<dim3(512), dim3(256), 0, stream>>>(Sb, deltas);
    k_aru<<<dim3(1024), dim3(256), 0, stream>>>(x, m_u, deltas);

    k_chunk_local<<<dim3(512), dim3(64), 0, stream>>>(deltas, m_y, term);
    k_boundary<<<dim3(8), dim3(128), 0, stream>>>(Cm, term, sst);
    k_chunk_final<<<dim3(512), dim3(64), 0, stream>>>(deltas, m_y, sst, out);
}

// Round 3
// 590.151 us; speedup vs baseline: 5.6885x; 5.6885x over previous
//
#include <hip/hip_runtime.h>
#include <math.h>

#define BB 8
#define LL 4096
#define DD 64
#define KK 24
#define NN 8192
#define LOGN 13

typedef unsigned int uint;

__device__ __forceinline__ float bfl(uint u) {            // low bf16 -> float
    union { uint u; float f; } v; v.u = u << 16; return v.f;
}
__device__ __forceinline__ float bfh(uint u) {            // high bf16 -> float
    union { uint u; float f; } v; v.u = u & 0xFFFF0000u; return v.f;
}
__device__ __forceinline__ uint pk(float x) {             // float -> bf16 (rne), low bits
    union { float f; uint u; } v; v.f = x;
    return (v.u + 0x7FFFu + ((v.u >> 16) & 1u)) >> 16;
}
__device__ __forceinline__ float2 unpk2(uint u) {
    return make_float2(bfl(u), bfh(u));
}

// ---------------- FFT primitives (in-LDS, 256 threads, N=8192) ----------------
__device__ __forceinline__ void fft_dif(float2* a) {
    const int tid = threadIdx.x;
    for (int lh = LOGN - 1; lh >= 0; --lh) {
        const int half = 1 << lh;
        const float tw = -6.28318530717958647692f / (float)(2 << lh);
#pragma unroll
        for (int bb = 0; bb < NN / 2 / 256; ++bb) {
            int t = tid + (bb << 8);
            int j = t & (half - 1);
            int i0 = ((t >> lh) << (lh + 1)) + j;
            float2 u = a[i0], v = a[i0 + half];
            float sn, cs;
            __sincosf(tw * (float)j, &sn, &cs);
            float dx = u.x - v.x, dy = u.y - v.y;
            a[i0] = make_float2(u.x + v.x, u.y + v.y);
            a[i0 + half] = make_float2(dx * cs - dy * sn, dx * sn + dy * cs);
        }
        __syncthreads();
    }
}

__device__ __forceinline__ void fft_dit(float2* a) {
    const int tid = threadIdx.x;
    for (int lh = 0; lh < LOGN; ++lh) {
        const int half = 1 << lh;
        const float tw = 6.28318530717958647692f / (float)(2 << lh);
#pragma unroll
        for (int bb = 0; bb < NN / 2 / 256; ++bb) {
            int t = tid + (bb << 8);
            int j = t & (half - 1);
            int i0 = ((t >> lh) << (lh + 1)) + j;
            float2 u = a[i0], v = a[i0 + half];
            float sn, cs;
            __sincosf(tw * (float)j, &sn, &cs);
            float wx = v.x * cs - v.y * sn;
            float wy = v.x * sn + v.y * cs;
            a[i0] = make_float2(u.x + wx, u.y + wy);
            a[i0 + half] = make_float2(u.x - wx, u.y - wy);
        }
        __syncthreads();
    }
}

// ---------------- kernels ----------------

// Pack m_phi into per-pass, k3-major bf16x4 table:
// mp[p*12288 + k3*4096 + (c*64+o)] = uint2{ pk(k=kb)|pk(kb+1)<<16, pk(kb+2)|pk(kb+3)<<16 }, kb=p*12+4*k3
__global__ __launch_bounds__(256) void k_pack(const float* __restrict__ mphi,
                                              uint2* __restrict__ mp) {
    int idx = blockIdx.x * 256 + threadIdx.x;
    if (idx >= 24576) return;
    int p = idx / 12288;
    int rem = idx - p * 12288;
    int k3 = rem >> 12;
    int e = rem & 4095;
    int c = e >> 6, o = e & 63;
    int kb = p * 12 + k3 * 4;
    uint x = pk(mphi[((kb + 0) * 64 + c) * 64 + o]) | (pk(mphi[((kb + 1) * 64 + c) * 64 + o]) << 16);
    uint y = pk(mphi[((kb + 2) * 64 + c) * 64 + o]) | (pk(mphi[((kb + 3) * 64 + c) * 64 + o]) << 16);
    mp[idx] = make_uint2(x, y);
}

// V[f,k] = FFT(eig_vecs[:,k] * lambda_k^0.25 / N), bit-reversed bins, fp32
__global__ __launch_bounds__(256) void k_fft_filters(const float* __restrict__ eig_vals,
                                                     const float* __restrict__ eig_vecs,
                                                     float2* __restrict__ Vb) {
    __shared__ float2 a[NN];
    const int k = blockIdx.x, tid = threadIdx.x;
    const float alpha = powf(eig_vals[k], 0.25f) * (1.0f / (float)NN);
    for (int t = tid; t < LL; t += 256)
        a[t] = make_float2(eig_vecs[t * KK + k] * alpha, 0.f);
    for (int t = LL + tid; t < NN; t += 256)
        a[t] = make_float2(0.f, 0.f);
    __syncthreads();
    fft_dif(a);
    for (int r = tid; r < NN; r += 256)
        Vb[(size_t)r * KK + k] = a[r];
}

// U[b,f,c] = FFT(x[b,:,c]), stored as packed complex-bf16 uint
__global__ __launch_bounds__(256) void k_fft_x(const float* __restrict__ x,
                                               uint* __restrict__ Ub) {
    __shared__ float2 a[NN];
    const int b = blockIdx.x >> 6, c = blockIdx.x & 63;
    const int tid = threadIdx.x;
    for (int l = tid; l < LL; l += 256)
        a[l] = make_float2(x[((size_t)b * LL + l) * DD + c], 0.f);
    for (int l = LL + tid; l < NN; l += 256)
        a[l] = make_float2(0.f, 0.f);
    __syncthreads();
    fft_dif(a);
    for (int r = tid; r < NN; r += 256)
        Ub[((size_t)b * NN + r) * DD + c] = pk(a[r].x) | (pk(a[r].y) << 16);
}

// Per-pass modulate: G[c,o] = sum_{k in pass} V[f,k]*mphi[k,c,o]; S[b,f,o] (+)= sum_c U[b,f,c]*G[c,o]
// 256 blocks x 512 threads; 32 freqs per block; mphi half (96KB) LDS-resident.
#define FT2 32
__global__ __launch_bounds__(512) void k_modulate2(const float2* __restrict__ Vb,
                                                   const uint* __restrict__ Ub,
                                                   const uint2* __restrict__ mp,
                                                   uint* __restrict__ Sb,
                                                   const int p) {
    __shared__ __align__(16) uint2 mp_s[3 * 4096];     // 96 KB
    __shared__ __align__(16) float2 Gs[4096];          // 32 KB
    __shared__ __align__(16) float2 Us[512];           // 4 KB
    __shared__ float2 Vt[FT2 * 12];                    // 3 KB
    const int tid = threadIdx.x;
    const int f0 = blockIdx.x * FT2;

    // stage mphi half: 12288 uint2 = 6144 uint4
    {
        const uint4* src = (const uint4*)(mp + (size_t)p * 12288);
        uint4* dst = (uint4*)mp_s;
        for (int i = tid; i < 6144; i += 512) dst[i] = src[i];
    }
    // stage V for this f-tile and pass
    for (int i = tid; i < FT2 * 12; i += 512) {
        int fi = i / 12, j = i - fi * 12;
        Vt[i] = Vb[(size_t)(f0 + fi) * KK + p * 12 + j];
    }
    __syncthreads();

    const int o2 = tid & 31;          // o-pair
    const int ch = (tid >> 5) & 1;    // c-half
    const int b  = tid >> 6;          // wave index == batch
    const size_t ub0 = (size_t)b * NN * DD + (tid & 63);
    const uint2* SbV = (const uint2*)Sb;
    const size_t sp0 = (size_t)b * NN * 32 + o2;

    uint ucur = Ub[ub0 + (size_t)f0 * DD];
    uint2 scur = make_uint2(0, 0);
    if (p) scur = SbV[sp0 + (size_t)f0 * 32];

    for (int fi = 0; fi < FT2; ++fi) {
        const int f = f0 + fi;
        Us[tid] = unpk2(ucur);
        // prefetch next-f operands (latency hides under G-build + S-apply)
        uint unext = 0; uint2 snext = make_uint2(0, 0);
        if (fi + 1 < FT2) {
            unext = Ub[ub0 + (size_t)(f + 1) * DD];
            if (p) snext = SbV[sp0 + (size_t)(f + 1) * 32];
        }
        // V registers
        float2 v[12];
#pragma unroll
        for (int j = 0; j < 12; ++j) v[j] = Vt[fi * 12 + j];
        // G build
        for (int e = tid; e < 4096; e += 512) {
            float gx = 0.f, gy = 0.f;
#pragma unroll
            for (int k3 = 0; k3 < 3; ++k3) {
                uint2 m = mp_s[k3 * 4096 + e];
                float m0 = bfl(m.x), m1 = bfh(m.x), m2 = bfl(m.y), m3 = bfh(m.y);
                gx += v[4 * k3].x * m0 + v[4 * k3 + 1].x * m1 + v[4 * k3 + 2].x * m2 + v[4 * k3 + 3].x * m3;
                gy += v[4 * k3].y * m0 + v[4 * k3 + 1].y * m1 + v[4 * k3 + 2].y * m2 + v[4 * k3 + 3].y * m3;
            }
            Gs[e] = make_float2(gx, gy);
        }
        __syncthreads();
        // S apply: thread covers (b, o-pair, c-half); combine halves via shfl_xor(32)
        {
            float s0x = 0.f, s0y = 0.f, s1x = 0.f, s1y = 0.f;
            const float2* usb = &Us[b * 64 + ch * 32];
            const char* gb = (const char*)&Gs[ch * 32 * 64 + o2 * 2];
#pragma unroll
            for (int cc = 0; cc < 32; ++cc) {
                float2 u = usb[cc];
                float4 g = *(const float4*)(gb + cc * 512);
                s0x += u.x * g.x - u.y * g.y;
                s0y += u.x * g.y + u.y * g.x;
                s1x += u.x * g.z - u.y * g.w;
                s1y += u.x * g.w + u.y * g.z;
            }
            s0x += __shfl_xor(s0x, 32);
            s0y += __shfl_xor(s0y, 32);
            s1x += __shfl_xor(s1x, 32);
            s1y += __shfl_xor(s1y, 32);
            if (ch == 0) {
                if (p) {
                    s0x += bfl(scur.x); s0y += bfh(scur.x);
                    s1x += bfl(scur.y); s1y += bfh(scur.y);
                }
                uint2* sp = (uint2*)&Sb[((size_t)b * NN + f) * DD + o2 * 2];
                *sp = make_uint2(pk(s0x) | (pk(s0y) << 16), pk(s1x) | (pk(s1y) << 16));
            }
        }
        __syncthreads();
        ucur = unext; scur = snext;
    }
}

// delta_phi[b,l,o] = Re(IFFT(S[b,:,o]))[l]
__global__ __launch_bounds__(256) void k_ifft(const uint* __restrict__ Sb,
                                              float* __restrict__ deltas) {
    __shared__ float2 a[NN];
    const int b = blockIdx.x >> 6, o = blockIdx.x & 63;
    const int tid = threadIdx.x;
    for (int r = tid; r < NN; r += 256)
        a[r] = unpk2(Sb[((size_t)b * NN + r) * DD + o]);
    __syncthreads();
    fft_dit(a);
    for (int l = tid; l < LL; l += 256)
        deltas[((size_t)b * LL + l) * DD + o] = a[l].x;
}

// deltas += AR-U
__global__ __launch_bounds__(256) void k_aru(const float* __restrict__ x,
                                             const float* __restrict__ m_u,
                                             float* __restrict__ deltas) {
    __shared__ float mu_s[64 * 193];
    __shared__ float xs[34 * 64];
    const int tid = threadIdx.x;
    const int b = blockIdx.x >> 7;
    const int l0 = (blockIdx.x & 127) * 32;
    for (int idx = tid; idx < 64 * 192; idx += 256) {
        int o = idx / 192;
        int rem = idx - o * 192;
        mu_s[o * 193 + rem] = m_u[idx];
    }
    for (int idx = tid; idx < 34 * 64; idx += 256) {
        int rr = idx >> 6, i = idx & 63;
        int gl = l0 - 2 + rr;
        xs[idx] = (gl >= 0) ? x[((size_t)b * LL + gl) * DD + i] : 0.f;
    }
    __syncthreads();
    const int o = tid & 63, lsub = tid >> 6;
    for (int lb = 0; lb < 8; ++lb) {
        int ll = lsub * 8 + lb;
        int r = ll + 2;
        float acc = 0.f;
#pragma unroll
        for (int i = 0; i < 64; ++i) {
            int mb = o * 193 + i * 3;
            acc += mu_s[mb]     * xs[r * 64 + i]
                 + mu_s[mb + 1] * xs[(r - 1) * 64 + i]
                 + mu_s[mb + 2] * xs[(r - 2) * 64 + i];
        }
        deltas[((size_t)b * LL + l0 + ll) * DD + o] += acc;
    }
}

__global__ __launch_bounds__(256) void k_companion(const float* __restrict__ m_y,
                                                   float* __restrict__ M) {
    int idx = blockIdx.x * 256 + threadIdx.x;
    int r = idx >> 7, c = idx & 127;
    M[idx] = (r < 64) ? m_y[r * 128 + c] : ((c == r - 64) ? 1.f : 0.f);
}

__global__ __launch_bounds__(256) void k_matsq(const float* __restrict__ A,
                                               float* __restrict__ C) {
    int idx = blockIdx.x * 256 + threadIdx.x;
    int r = idx >> 7, c = idx & 127;
    float acc = 0.f;
#pragma unroll
    for (int i = 0; i < 128; ++i) acc += A[r * 128 + i] * A[i * 128 + c];
    C[idx] = acc;
}

__global__ __launch_bounds__(64, 1) void k_chunk_local(const float* __restrict__ deltas,
                                                       const float* __restrict__ m_y,
                                                       float* __restrict__ term) {
    const int b = blockIdx.x >> 6, j = blockIdx.x & 63;
    const int o = threadIdx.x;
    __shared__ __align__(16) float y1s[64];
    __shared__ __align__(16) float y2s[64];
    float a1r[64], a2r[64];
#pragma unroll
    for (int i4 = 0; i4 < 16; ++i4) {
        float4 v1 = *(const float4*)&m_y[o * 128 + i4 * 4];
        float4 v2 = *(const float4*)&m_y[o * 128 + 64 + i4 * 4];
        a1r[4 * i4] = v1.x; a1r[4 * i4 + 1] = v1.y; a1r[4 * i4 + 2] = v1.z; a1r[4 * i4 + 3] = v1.w;
        a2r[4 * i4] = v2.x; a2r[4 * i4 + 1] = v2.y; a2r[4 * i4 + 2] = v2.z; a2r[4 * i4 + 3] = v2.w;
    }
    y1s[o] = 0.f; y2s[o] = 0.f;
    __syncthreads();
    const float* dl = &deltas[(((size_t)b * LL) + j * 64) * DD + o];
    for (int t = 0; t < 64; ++t) {
        float acc = dl[t * DD];
#pragma unroll
        for (int i4 = 0; i4 < 16; ++i4) {
            float4 w1 = *(const float4*)&y1s[i4 * 4];
            float4 w2 = *(const float4*)&y2s[i4 * 4];
            acc += a1r[4 * i4] * w1.x + a1r[4 * i4 + 1] * w1.y + a1r[4 * i4 + 2] * w1.z + a1r[4 * i4 + 3] * w1.w
                 + a2r[4 * i4] * w2.x + a2r[4 * i4 + 1] * w2.y + a2r[4 * i4 + 2] * w2.z + a2r[4 * i4 + 3] * w2.w;
        }
        __syncthreads();
        y2s[o] = y1s[o];
        y1s[o] = acc;
        __syncthreads();
    }
    term[((size_t)b * 64 + j) * 128 + o] = y1s[o];
    term[((size_t)b * 64 + j) * 128 + 64 + o] = y2s[o];
}

__global__ __launch_bounds__(128, 1) void k_boundary(const float* __restrict__ P,
                                                     const float* __restrict__ term,
                                                     float* __restrict__ sstate) {
    const int b = blockIdx.x;
    const int r = threadIdx.x;
    __shared__ __align__(16) float scur[128];
    float p[128];
#pragma unroll
    for (int i4 = 0; i4 < 32; ++i4) {
        float4 v = *(const float4*)&P[r * 128 + i4 * 4];
        p[4 * i4] = v.x; p[4 * i4 + 1] = v.y; p[4 * i4 + 2] = v.z; p[4 * i4 + 3] = v.w;
    }
    scur[r] = 0.f;
    __syncthreads();
    for (int j = 0; j < 64; ++j) {
        sstate[((size_t)b * 64 + j) * 128 + r] = scur[r];
        float acc = term[((size_t)b * 64 + j) * 128 + r];
#pragma unroll
        for (int i4 = 0; i4 < 32; ++i4) {
            float4 w = *(const float4*)&scur[i4 * 4];
            acc += p[4 * i4] * w.x + p[4 * i4 + 1] * w.y + p[4 * i4 + 2] * w.z + p[4 * i4 + 3] * w.w;
        }
        __syncthreads();
        scur[r] = acc;
        __syncthreads();
    }
}

__global__ __launch_bounds__(64, 1) void k_chunk_final(const float* __restrict__ deltas,
                                                       const float* __restrict__ m_y,
                                                       const float* __restrict__ sstate,
                                                       float* __restrict__ out) {
    const int b = blockIdx.x >> 6, j = blockIdx.x & 63;
    const int o = threadIdx.x;
    __shared__ __align__(16) float y1s[64];
    __shared__ __align__(16) float y2s[64];
    float a1r[64], a2r[64];
#pragma unroll
    for (int i4 = 0; i4 < 16; ++i4) {
        float4 v1 = *(const float4*)&m_y[o * 128 + i4 * 4];
        float4 v2 = *(const float4*)&m_y[o * 128 + 64 + i4 * 4];
        a1r[4 * i4] = v1.x; a1r[4 * i4 + 1] = v1.y; a1r[4 * i4 + 2] = v1.z; a1r[4 * i4 + 3] = v1.w;
        a2r[4 * i4] = v2.x; a2r[4 * i4 + 1] = v2.y; a2r[4 * i4 + 2] = v2.z; a2r[4 * i4 + 3] = v2.w;
    }
    y1s[o] = sstate[((size_t)b * 64 + j) * 128 + o];
    y2s[o] = sstate[((size_t)b * 64 + j) * 128 + 64 + o];
    __syncthreads();
    const size_t base = (((size_t)b * LL) + j * 64) * DD + o;
    for (int t = 0; t < 64; ++t) {
        float acc = deltas[base + (size_t)t * DD];
#pragma unroll
        for (int i4 = 0; i4 < 16; ++i4) {
            float4 w1 = *(const float4*)&y1s[i4 * 4];
            float4 w2 = *(const float4*)&y2s[i4 * 4];
            acc += a1r[4 * i4] * w1.x + a1r[4 * i4 + 1] * w1.y + a1r[4 * i4 + 2] * w1.z + a1r[4 * i4 + 3] * w1.w
                 + a2r[4 * i4] * w2.x + a2r[4 * i4 + 1] * w2.y + a2r[4 * i4 + 2] * w2.z + a2r[4 * i4 + 3] * w2.w;
        }
        out[base + (size_t)t * DD] = acc;
        __syncthreads();
        y2s[o] = y1s[o];
        y1s[o] = acc;
        __syncthreads();
    }
}

extern "C" void kernel_launch(void* const* d_in, const int* in_sizes, int n_in,
                              void* d_out, int out_size, void* d_ws, size_t ws_size,
                              hipStream_t stream) {
    const float* x        = (const float*)d_in[0];
    const float* m_y      = (const float*)d_in[1];
    const float* m_u      = (const float*)d_in[2];
    const float* m_phi    = (const float*)d_in[3];
    const float* eig_vals = (const float*)d_in[4];
    const float* eig_vecs = (const float*)d_in[5];
    float* out = (float*)d_out;

    char* ws = (char*)d_ws;
    size_t off = 0;
    auto alloc = [&](size_t bytes) -> void* {
        void* p = ws + off;
        off += (bytes + 255) & ~(size_t)255;
        return p;
    };
    float2* Vb   = (float2*)alloc((size_t)NN * KK * sizeof(float2));          // 1.5 MB
    uint*   Ub   = (uint*)alloc((size_t)BB * NN * DD * sizeof(uint));         // 16.8 MB
    uint*   Sb   = (uint*)alloc((size_t)BB * NN * DD * sizeof(uint));         // 16.8 MB
    float*  deltas = (float*)alloc((size_t)BB * LL * DD * sizeof(float));     // 8.4 MB
    uint2*  mp   = (uint2*)alloc((size_t)24576 * sizeof(uint2));              // 0.2 MB
    float*  mats = (float*)alloc((size_t)3 * 128 * 128 * sizeof(float));
    float*  term = (float*)alloc((size_t)BB * 64 * 128 * sizeof(float));
    float*  sst  = (float*)alloc((size_t)BB * 64 * 128 * sizeof(float));

    k_pack<<<dim3(96), dim3(256), 0, stream>>>(m_phi, mp);
    k_fft_filters<<<dim3(24), dim3(256), 0, stream>>>(eig_vals, eig_vecs, Vb);
    k_fft_x<<<dim3(512), dim3(256), 0, stream>>>(x, Ub);

    k_companion<<<dim3(64), dim3(256), 0, stream>>>(m_y, mats);
    float* Am = mats;
    float* Bm = mats + 16384;
    float* Cm = mats + 32768;
    k_matsq<<<dim3(64), dim3(256), 0, stream>>>(Am, Bm);  // M^2
    k_matsq<<<dim3(64), dim3(256), 0, stream>>>(Bm, Cm);  // M^4
    k_matsq<<<dim3(64), dim3(256), 0, stream>>>(Cm, Bm);  // M^8
    k_matsq<<<dim3(64), dim3(256), 0, stream>>>(Bm, Cm);  // M^16
    k_matsq<<<dim3(64), dim3(256), 0, stream>>>(Cm, Bm);  // M^32
    k_matsq<<<dim3(64), dim3(256), 0, stream>>>(Bm, Cm);  // M^64 -> Cm

    k_modulate2<<<dim3(NN / FT2), dim3(512), 0, stream>>>(Vb, Ub, mp, Sb, 0);
    k_modulate2<<<dim3(NN / FT2), dim3(512), 0, stream>>>(Vb, Ub, mp, Sb, 1);
    k_ifft<<<dim3(512), dim3(256), 0, stream>>>(Sb, deltas);
    k_aru<<<dim3(1024), dim3(256), 0, stream>>>(x, m_u, deltas);

    k_chunk_local<<<dim3(512), dim3(64), 0, stream>>>(deltas, m_y, term);
    k_boundary<<<dim3(8), dim3(128), 0, stream>>>(Cm, term, sst);
    k_chunk_final<<<dim3(512), dim3(64), 0, stream>>>(deltas, m_y, sst, out);
}

// Round 4
// 574.370 us; speedup vs baseline: 5.8448x; 1.0275x over previous
//
#include <hip/hip_runtime.h>
#include <math.h>

#define BB 8
#define LL 4096
#define DD 64
#define KK 24
#define NN 8192
#define LOGN 13

typedef unsigned int uint;

__device__ __forceinline__ float bfl(uint u) {            // low bf16 -> float
    union { uint u; float f; } v; v.u = u << 16; return v.f;
}
__device__ __forceinline__ float bfh(uint u) {            // high bf16 -> float
    union { uint u; float f; } v; v.u = u & 0xFFFF0000u; return v.f;
}
__device__ __forceinline__ uint pk(float x) {             // float -> bf16 (rne), low bits
    union { float f; uint u; } v; v.f = x;
    return (v.u + 0x7FFFu + ((v.u >> 16) & 1u)) >> 16;
}
__device__ __forceinline__ float2 unpk2(uint u) {
    return make_float2(bfl(u), bfh(u));
}

// ---------------- FFT primitives (in-LDS, 256 threads, N=8192) ----------------
__device__ __forceinline__ void fft_dif(float2* a) {
    const int tid = threadIdx.x;
    for (int lh = LOGN - 1; lh >= 0; --lh) {
        const int half = 1 << lh;
        const float tw = -6.28318530717958647692f / (float)(2 << lh);
#pragma unroll
        for (int bb = 0; bb < NN / 2 / 256; ++bb) {
            int t = tid + (bb << 8);
            int j = t & (half - 1);
            int i0 = ((t >> lh) << (lh + 1)) + j;
            float2 u = a[i0], v = a[i0 + half];
            float sn, cs;
            __sincosf(tw * (float)j, &sn, &cs);
            float dx = u.x - v.x, dy = u.y - v.y;
            a[i0] = make_float2(u.x + v.x, u.y + v.y);
            a[i0 + half] = make_float2(dx * cs - dy * sn, dx * sn + dy * cs);
        }
        __syncthreads();
    }
}

__device__ __forceinline__ void fft_dit(float2* a) {
    const int tid = threadIdx.x;
    for (int lh = 0; lh < LOGN; ++lh) {
        const int half = 1 << lh;
        const float tw = 6.28318530717958647692f / (float)(2 << lh);
#pragma unroll
        for (int bb = 0; bb < NN / 2 / 256; ++bb) {
            int t = tid + (bb << 8);
            int j = t & (half - 1);
            int i0 = ((t >> lh) << (lh + 1)) + j;
            float2 u = a[i0], v = a[i0 + half];
            float sn, cs;
            __sincosf(tw * (float)j, &sn, &cs);
            float wx = v.x * cs - v.y * sn;
            float wy = v.x * sn + v.y * cs;
            a[i0] = make_float2(u.x + wx, u.y + wy);
            a[i0 + half] = make_float2(u.x - wx, u.y - wy);
        }
        __syncthreads();
    }
}

// ---------------- kernels ----------------

// Pack m_phi into per-pass, k3-major bf16x4 table (3 planes of 4096 uint2 per pass).
__global__ __launch_bounds__(256) void k_pack(const float* __restrict__ mphi,
                                              uint2* __restrict__ mp) {
    int idx = blockIdx.x * 256 + threadIdx.x;
    if (idx >= 24576) return;
    int p = idx / 12288;
    int rem = idx - p * 12288;
    int k3 = rem >> 12;
    int e = rem & 4095;
    int c = e >> 6, o = e & 63;
    int kb = p * 12 + k3 * 4;
    uint x = pk(mphi[((kb + 0) * 64 + c) * 64 + o]) | (pk(mphi[((kb + 1) * 64 + c) * 64 + o]) << 16);
    uint y = pk(mphi[((kb + 2) * 64 + c) * 64 + o]) | (pk(mphi[((kb + 3) * 64 + c) * 64 + o]) << 16);
    mp[idx] = make_uint2(x, y);
}

// V[f,k] = FFT(eig_vecs[:,k] * lambda_k^0.25 / N), bit-reversed bins, fp32
__global__ __launch_bounds__(256) void k_fft_filters(const float* __restrict__ eig_vals,
                                                     const float* __restrict__ eig_vecs,
                                                     float2* __restrict__ Vb) {
    __shared__ float2 a[NN];
    const int k = blockIdx.x, tid = threadIdx.x;
    const float alpha = powf(eig_vals[k], 0.25f) * (1.0f / (float)NN);
    for (int t = tid; t < LL; t += 256)
        a[t] = make_float2(eig_vecs[t * KK + k] * alpha, 0.f);
    for (int t = LL + tid; t < NN; t += 256)
        a[t] = make_float2(0.f, 0.f);
    __syncthreads();
    fft_dif(a);
    for (int r = tid; r < NN; r += 256)
        Vb[(size_t)r * KK + k] = a[r];
}

// U[b,f,c] = FFT(x[b,:,c]), stored as packed complex-bf16 uint
__global__ __launch_bounds__(256) void k_fft_x(const float* __restrict__ x,
                                               uint* __restrict__ Ub) {
    __shared__ float2 a[NN];
    const int b = blockIdx.x >> 6, c = blockIdx.x & 63;
    const int tid = threadIdx.x;
    for (int l = tid; l < LL; l += 256)
        a[l] = make_float2(x[((size_t)b * LL + l) * DD + c], 0.f);
    for (int l = LL + tid; l < NN; l += 256)
        a[l] = make_float2(0.f, 0.f);
    __syncthreads();
    fft_dif(a);
    for (int r = tid; r < NN; r += 256)
        Ub[((size_t)b * NN + r) * DD + c] = pk(a[r].x) | (pk(a[r].y) << 16);
}

// float2 helpers (pairs over the two blocked frequencies -> candidate v_pk_fma_f32)
__device__ __forceinline__ void gacc(float2& gx, float2& gy,
                                     const float2* vx, const float2* vy,
                                     int kb, uint mw) {
    float m0 = bfl(mw), m1 = bfh(mw);
    gx.x += vx[kb].x * m0 + vx[kb + 1].x * m1;
    gx.y += vx[kb].y * m0 + vx[kb + 1].y * m1;
    gy.x += vy[kb].x * m0 + vy[kb + 1].x * m1;
    gy.y += vy[kb].y * m0 + vy[kb + 1].y * m1;
}
__device__ __forceinline__ void cmac2(float2& ax, float2& ay,
                                      float2 ux, float2 uy, float2 gx, float2 gy) {
    ax.x += ux.x * gx.x - uy.x * gy.x;  ax.y += ux.y * gx.y - uy.y * gy.y;
    ay.x += ux.x * gy.x + uy.x * gx.x;  ay.y += ux.y * gy.y + uy.y * gx.y;
}

// Per-pass modulate, 2-frequency register blocking.
// G[c,o] = sum_{k in pass} V[f,k]*mphi[k,c,o]; S[b,f,o] (+)= sum_c U[b,f,c]*G[c,o]
#define FT2 32
__global__ __launch_bounds__(512) void k_modulate3(const float2* __restrict__ Vb,
                                                   const uint* __restrict__ Ub,
                                                   const uint2* __restrict__ mp,
                                                   uint* __restrict__ Sb,
                                                   const int p) {
    __shared__ __align__(16) uint2 mp_s[3 * 4096];     // 96 KB
    __shared__ __align__(16) uint2 Gs2[4096];          // 32 KB: {f0 bf16 cplx, f1 bf16 cplx}
    __shared__ __align__(16) uint2 Us2[512];           // 4 KB:  {f0, f1}
    __shared__ float2 Vt[FT2 * 12];                    // 3 KB
    const int tid = threadIdx.x;
    const int f0g = blockIdx.x * FT2;

    {   // stage mphi half: 12288 uint2 = 6144 uint4
        const uint4* src = (const uint4*)(mp + (size_t)p * 12288);
        uint4* dst = (uint4*)mp_s;
        for (int i = tid; i < 6144; i += 512) dst[i] = src[i];
    }
    for (int i = tid; i < FT2 * 12; i += 512) {
        int fi = i / 12, j = i - fi * 12;
        Vt[i] = Vb[(size_t)(f0g + fi) * KK + p * 12 + j];
    }
    __syncthreads();

    const int o2 = tid & 31;          // o-pair
    const int ch = (tid >> 5) & 1;    // c-half
    const int b  = tid >> 6;          // wave index == batch
    const size_t ub0 = (size_t)b * NN * DD + (tid & 63);
    const uint2* SbV = (const uint2*)Sb;
    const size_t sp0 = (size_t)b * NN * 32 + o2;

    uint u0 = Ub[ub0 + (size_t)f0g * DD];
    uint u1 = Ub[ub0 + (size_t)(f0g + 1) * DD];
    uint2 sc0 = make_uint2(0, 0), sc1 = make_uint2(0, 0);
    if (p && ch == 0) {
        sc0 = SbV[sp0 + (size_t)f0g * 32];
        sc1 = SbV[sp0 + (size_t)(f0g + 1) * 32];
    }

    for (int fi = 0; fi < FT2; fi += 2) {
        const int f = f0g + fi;
        Us2[tid] = make_uint2(u0, u1);
        // prefetch next f-pair (hides under G-build + S-apply)
        uint nu0 = 0, nu1 = 0; uint2 ns0 = make_uint2(0, 0), ns1 = make_uint2(0, 0);
        if (fi + 2 < FT2) {
            nu0 = Ub[ub0 + (size_t)(f + 2) * DD];
            nu1 = Ub[ub0 + (size_t)(f + 3) * DD];
            if (p && ch == 0) {
                ns0 = SbV[sp0 + (size_t)(f + 2) * 32];
                ns1 = SbV[sp0 + (size_t)(f + 3) * 32];
            }
        }
        // V registers as f-pair vectors
        float2 vx[12], vy[12];
#pragma unroll
        for (int j = 0; j < 12; ++j) {
            float2 a = Vt[fi * 12 + j], b2 = Vt[(fi + 1) * 12 + j];
            vx[j] = make_float2(a.x, b2.x);
            vy[j] = make_float2(a.y, b2.y);
        }
        // G build: elem pairs, b128 in / b128 out
#pragma unroll
        for (int i = 0; i < 4; ++i) {
            int e0 = 2 * (tid + i * 512);
            uint4 mA = *(const uint4*)&mp_s[e0];
            uint4 mB = *(const uint4*)&mp_s[4096 + e0];
            uint4 mC = *(const uint4*)&mp_s[8192 + e0];
            float2 gx0 = {0, 0}, gy0 = {0, 0}, gx1 = {0, 0}, gy1 = {0, 0};
            gacc(gx0, gy0, vx, vy, 0, mA.x);  gacc(gx0, gy0, vx, vy, 2, mA.y);
            gacc(gx0, gy0, vx, vy, 4, mB.x);  gacc(gx0, gy0, vx, vy, 6, mB.y);
            gacc(gx0, gy0, vx, vy, 8, mC.x);  gacc(gx0, gy0, vx, vy, 10, mC.y);
            gacc(gx1, gy1, vx, vy, 0, mA.z);  gacc(gx1, gy1, vx, vy, 2, mA.w);
            gacc(gx1, gy1, vx, vy, 4, mB.z);  gacc(gx1, gy1, vx, vy, 6, mB.w);
            gacc(gx1, gy1, vx, vy, 8, mC.z);  gacc(gx1, gy1, vx, vy, 10, mC.w);
            uint4 w;
            w.x = pk(gx0.x) | (pk(gy0.x) << 16);   // elem e0, f0
            w.y = pk(gx0.y) | (pk(gy0.y) << 16);   // elem e0, f1
            w.z = pk(gx1.x) | (pk(gy1.x) << 16);   // elem e0+1, f0
            w.w = pk(gx1.y) | (pk(gy1.y) << 16);   // elem e0+1, f1
            *(uint4*)&Gs2[e0] = w;
        }
        __syncthreads();
        // S apply: (b, o-pair, c-half), c unrolled by 2, all b128 reads
        {
            float2 A0x = {0, 0}, A0y = {0, 0}, A1x = {0, 0}, A1y = {0, 0};
            const int cbase = ch * 32;
#pragma unroll
            for (int cc = 0; cc < 16; ++cc) {
                int c = cbase + cc * 2;
                uint4 uu = *(const uint4*)&Us2[b * 64 + c];
                uint4 g0 = *(const uint4*)&Gs2[c * 64 + o2 * 2];
                uint4 g1 = *(const uint4*)&Gs2[(c + 1) * 64 + o2 * 2];
                float2 ux = make_float2(bfl(uu.x), bfl(uu.y));
                float2 uy = make_float2(bfh(uu.x), bfh(uu.y));
                float2 g0x0 = make_float2(bfl(g0.x), bfl(g0.y));
                float2 g0y0 = make_float2(bfh(g0.x), bfh(g0.y));
                float2 g0x1 = make_float2(bfl(g0.z), bfl(g0.w));
                float2 g0y1 = make_float2(bfh(g0.z), bfh(g0.w));
                cmac2(A0x, A0y, ux, uy, g0x0, g0y0);
                cmac2(A1x, A1y, ux, uy, g0x1, g0y1);
                float2 vx2 = make_float2(bfl(uu.z), bfl(uu.w));
                float2 vy2 = make_float2(bfh(uu.z), bfh(uu.w));
                float2 g1x0 = make_float2(bfl(g1.x), bfl(g1.y));
                float2 g1y0 = make_float2(bfh(g1.x), bfh(g1.y));
                float2 g1x1 = make_float2(bfl(g1.z), bfl(g1.w));
                float2 g1y1 = make_float2(bfh(g1.z), bfh(g1.w));
                cmac2(A0x, A0y, vx2, vy2, g1x0, g1y0);
                cmac2(A1x, A1y, vx2, vy2, g1x1, g1y1);
            }
            A0x.x += __shfl_xor(A0x.x, 32);  A0x.y += __shfl_xor(A0x.y, 32);
            A0y.x += __shfl_xor(A0y.x, 32);  A0y.y += __shfl_xor(A0y.y, 32);
            A1x.x += __shfl_xor(A1x.x, 32);  A1x.y += __shfl_xor(A1x.y, 32);
            A1y.x += __shfl_xor(A1y.x, 32);  A1y.y += __shfl_xor(A1y.y, 32);
            if (ch == 0) {
                float s0x = A0x.x, s0y = A0y.x, s1x = A1x.x, s1y = A1y.x;   // f
                float t0x = A0x.y, t0y = A0y.y, t1x = A1x.y, t1y = A1y.y;   // f+1
                if (p) {
                    s0x += bfl(sc0.x); s0y += bfh(sc0.x); s1x += bfl(sc0.y); s1y += bfh(sc0.y);
                    t0x += bfl(sc1.x); t0y += bfh(sc1.x); t1x += bfl(sc1.y); t1y += bfh(sc1.y);
                }
                *(uint2*)&Sb[((size_t)b * NN + f) * DD + o2 * 2] =
                    make_uint2(pk(s0x) | (pk(s0y) << 16), pk(s1x) | (pk(s1y) << 16));
                *(uint2*)&Sb[((size_t)b * NN + f + 1) * DD + o2 * 2] =
                    make_uint2(pk(t0x) | (pk(t0y) << 16), pk(t1x) | (pk(t1y) << 16));
            }
        }
        __syncthreads();
        u0 = nu0; u1 = nu1; sc0 = ns0; sc1 = ns1;
    }
}

// delta_phi[b,l,o] = Re(IFFT(S[b,:,o]))[l]
__global__ __launch_bounds__(256) void k_ifft(const uint* __restrict__ Sb,
                                              float* __restrict__ deltas) {
    __shared__ float2 a[NN];
    const int b = blockIdx.x >> 6, o = blockIdx.x & 63;
    const int tid = threadIdx.x;
    for (int r = tid; r < NN; r += 256)
        a[r] = unpk2(Sb[((size_t)b * NN + r) * DD + o]);
    __syncthreads();
    fft_dit(a);
    for (int l = tid; l < LL; l += 256)
        deltas[((size_t)b * LL + l) * DD + o] = a[l].x;
}

// deltas += AR-U
__global__ __launch_bounds__(256) void k_aru(const float* __restrict__ x,
                                             const float* __restrict__ m_u,
                                             float* __restrict__ deltas) {
    __shared__ float mu_s[64 * 193];
    __shared__ float xs[34 * 64];
    const int tid = threadIdx.x;
    const int b = blockIdx.x >> 7;
    const int l0 = (blockIdx.x & 127) * 32;
    for (int idx = tid; idx < 64 * 192; idx += 256) {
        int o = idx / 192;
        int rem = idx - o * 192;
        mu_s[o * 193 + rem] = m_u[idx];
    }
    for (int idx = tid; idx < 34 * 64; idx += 256) {
        int rr = idx >> 6, i = idx & 63;
        int gl = l0 - 2 + rr;
        xs[idx] = (gl >= 0) ? x[((size_t)b * LL + gl) * DD + i] : 0.f;
    }
    __syncthreads();
    const int o = tid & 63, lsub = tid >> 6;
    for (int lb = 0; lb < 8; ++lb) {
        int ll = lsub * 8 + lb;
        int r = ll + 2;
        float acc = 0.f;
#pragma unroll
        for (int i = 0; i < 64; ++i) {
            int mb = o * 193 + i * 3;
            acc += mu_s[mb]     * xs[r * 64 + i]
                 + mu_s[mb + 1] * xs[(r - 1) * 64 + i]
                 + mu_s[mb + 2] * xs[(r - 2) * 64 + i];
        }
        deltas[((size_t)b * LL + l0 + ll) * DD + o] += acc;
    }
}

// First squaring with companion matrix built on the fly from m_y:
// M = [[A1|A2],[I|0]];  (M^2)[r][c] = r<64 ? sum_{i<64} my[r,i] my[i,c] + (c<64 ? my[r,c+64] : 0)
//                                   : my[r-64][c]
__global__ __launch_bounds__(256) void k_matsq1(const float* __restrict__ m_y,
                                                float* __restrict__ C) {
    int idx = blockIdx.x * 256 + threadIdx.x;
    int r = idx >> 7, c = idx & 127;
    if (r >= 64) { C[idx] = m_y[(r - 64) * 128 + c]; return; }
    float acc = (c < 64) ? m_y[r * 128 + 64 + c] : 0.f;
#pragma unroll
    for (int i = 0; i < 64; ++i) acc += m_y[r * 128 + i] * m_y[i * 128 + c];
    C[idx] = acc;
}

__global__ __launch_bounds__(256) void k_matsq(const float* __restrict__ A,
                                               float* __restrict__ C) {
    int idx = blockIdx.x * 256 + threadIdx.x;
    int r = idx >> 7, c = idx & 127;
    float acc = 0.f;
#pragma unroll
    for (int i = 0; i < 128; ++i) acc += A[r * 128 + i] * A[i * 128 + c];
    C[idx] = acc;
}

__global__ __launch_bounds__(64, 1) void k_chunk_local(const float* __restrict__ deltas,
                                                       const float* __restrict__ m_y,
                                                       float* __restrict__ term) {
    const int b = blockIdx.x >> 6, j = blockIdx.x & 63;
    const int o = threadIdx.x;
    __shared__ __align__(16) float y1s[64];
    __shared__ __align__(16) float y2s[64];
    float a1r[64], a2r[64];
#pragma unroll
    for (int i4 = 0; i4 < 16; ++i4) {
        float4 v1 = *(const float4*)&m_y[o * 128 + i4 * 4];
        float4 v2 = *(const float4*)&m_y[o * 128 + 64 + i4 * 4];
        a1r[4 * i4] = v1.x; a1r[4 * i4 + 1] = v1.y; a1r[4 * i4 + 2] = v1.z; a1r[4 * i4 + 3] = v1.w;
        a2r[4 * i4] = v2.x; a2r[4 * i4 + 1] = v2.y; a2r[4 * i4 + 2] = v2.z; a2r[4 * i4 + 3] = v2.w;
    }
    y1s[o] = 0.f; y2s[o] = 0.f;
    __syncthreads();
    const float* dl = &deltas[(((size_t)b * LL) + j * 64) * DD + o];
    for (int t = 0; t < 64; ++t) {
        float acc = dl[t * DD];
#pragma unroll
        for (int i4 = 0; i4 < 16; ++i4) {
            float4 w1 = *(const float4*)&y1s[i4 * 4];
            float4 w2 = *(const float4*)&y2s[i4 * 4];
            acc += a1r[4 * i4] * w1.x + a1r[4 * i4 + 1] * w1.y + a1r[4 * i4 + 2] * w1.z + a1r[4 * i4 + 3] * w1.w
                 + a2r[4 * i4] * w2.x + a2r[4 * i4 + 1] * w2.y + a2r[4 * i4 + 2] * w2.z + a2r[4 * i4 + 3] * w2.w;
        }
        __syncthreads();
        y2s[o] = y1s[o];
        y1s[o] = acc;
        __syncthreads();
    }
    term[((size_t)b * 64 + j) * 128 + o] = y1s[o];
    term[((size_t)b * 64 + j) * 128 + 64 + o] = y2s[o];
}

__global__ __launch_bounds__(128, 1) void k_boundary(const float* __restrict__ P,
                                                     const float* __restrict__ term,
                                                     float* __restrict__ sstate) {
    const int b = blockIdx.x;
    const int r = threadIdx.x;
    __shared__ __align__(16) float scur[128];
    float p[128];
#pragma unroll
    for (int i4 = 0; i4 < 32; ++i4) {
        float4 v = *(const float4*)&P[r * 128 + i4 * 4];
        p[4 * i4] = v.x; p[4 * i4 + 1] = v.y; p[4 * i4 + 2] = v.z; p[4 * i4 + 3] = v.w;
    }
    scur[r] = 0.f;
    __syncthreads();
    for (int j = 0; j < 64; ++j) {
        sstate[((size_t)b * 64 + j) * 128 + r] = scur[r];
        float acc = term[((size_t)b * 64 + j) * 128 + r];
#pragma unroll
        for (int i4 = 0; i4 < 32; ++i4) {
            float4 w = *(const float4*)&scur[i4 * 4];
            acc += p[4 * i4] * w.x + p[4 * i4 + 1] * w.y + p[4 * i4 + 2] * w.z + p[4 * i4 + 3] * w.w;
        }
        __syncthreads();
        scur[r] = acc;
        __syncthreads();
    }
}

__global__ __launch_bounds__(64, 1) void k_chunk_final(const float* __restrict__ deltas,
                                                       const float* __restrict__ m_y,
                                                       const float* __restrict__ sstate,
                                                       float* __restrict__ out) {
    const int b = blockIdx.x >> 6, j = blockIdx.x & 63;
    const int o = threadIdx.x;
    __shared__ __align__(16) float y1s[64];
    __shared__ __align__(16) float y2s[64];
    float a1r[64], a2r[64];
#pragma unroll
    for (int i4 = 0; i4 < 16; ++i4) {
        float4 v1 = *(const float4*)&m_y[o * 128 + i4 * 4];
        float4 v2 = *(const float4*)&m_y[o * 128 + 64 + i4 * 4];
        a1r[4 * i4] = v1.x; a1r[4 * i4 + 1] = v1.y; a1r[4 * i4 + 2] = v1.z; a1r[4 * i4 + 3] = v1.w;
        a2r[4 * i4] = v2.x; a2r[4 * i4 + 1] = v2.y; a2r[4 * i4 + 2] = v2.z; a2r[4 * i4 + 3] = v2.w;
    }
    y1s[o] = sstate[((size_t)b * 64 + j) * 128 + o];
    y2s[o] = sstate[((size_t)b * 64 + j) * 128 + 64 + o];
    __syncthreads();
    const size_t base = (((size_t)b * LL) + j * 64) * DD + o;
    for (int t = 0; t < 64; ++t) {
        float acc = deltas[base + (size_t)t * DD];
#pragma unroll
        for (int i4 = 0; i4 < 16; ++i4) {
            float4 w1 = *(const float4*)&y1s[i4 * 4];
            float4 w2 = *(const float4*)&y2s[i4 * 4];
            acc += a1r[4 * i4] * w1.x + a1r[4 * i4 + 1] * w1.y + a1r[4 * i4 + 2] * w1.z + a1r[4 * i4 + 3] * w1.w
                 + a2r[4 * i4] * w2.x + a2r[4 * i4 + 1] * w2.y + a2r[4 * i4 + 2] * w2.z + a2r[4 * i4 + 3] * w2.w;
        }
        out[base + (size_t)t * DD] = acc;
        __syncthreads();
        y2s[o] = y1s[o];
        y1s[o] = acc;
        __syncthreads();
    }
}

extern "C" void kernel_launch(void* const* d_in, const int* in_sizes, int n_in,
                              void* d_out, int out_size, void* d_ws, size_t ws_size,
                              hipStream_t stream) {
    const float* x        = (const float*)d_in[0];
    const float* m_y      = (const float*)d_in[1];
    const float* m_u      = (const float*)d_in[2];
    const float* m_phi    = (const float*)d_in[3];
    const float* eig_vals = (const float*)d_in[4];
    const float* eig_vecs = (const float*)d_in[5];
    float* out = (float*)d_out;

    char* ws = (char*)d_ws;
    size_t off = 0;
    auto alloc = [&](size_t bytes) -> void* {
        void* p = ws + off;
        off += (bytes + 255) & ~(size_t)255;
        return p;
    };
    float2* Vb   = (float2*)alloc((size_t)NN * KK * sizeof(float2));          // 1.5 MB
    uint*   Ub   = (uint*)alloc((size_t)BB * NN * DD * sizeof(uint));         // 16.8 MB
    uint*   Sb   = (uint*)alloc((size_t)BB * NN * DD * sizeof(uint));         // 16.8 MB
    float*  deltas = (float*)alloc((size_t)BB * LL * DD * sizeof(float));     // 8.4 MB
    uint2*  mp   = (uint2*)alloc((size_t)24576 * sizeof(uint2));              // 0.2 MB
    float*  mats = (float*)alloc((size_t)3 * 128 * 128 * sizeof(float));
    float*  term = (float*)alloc((size_t)BB * 64 * 128 * sizeof(float));
    float*  sst  = (float*)alloc((size_t)BB * 64 * 128 * sizeof(float));

    k_pack<<<dim3(96), dim3(256), 0, stream>>>(m_phi, mp);
    k_fft_filters<<<dim3(24), dim3(256), 0, stream>>>(eig_vals, eig_vecs, Vb);
    k_fft_x<<<dim3(512), dim3(256), 0, stream>>>(x, Ub);

    float* Bm = mats + 16384;
    float* Cm = mats + 32768;
    k_matsq1<<<dim3(64), dim3(256), 0, stream>>>(m_y, Bm);  // M^2
    k_matsq<<<dim3(64), dim3(256), 0, stream>>>(Bm, Cm);    // M^4
    k_matsq<<<dim3(64), dim3(256), 0, stream>>>(Cm, Bm);    // M^8
    k_matsq<<<dim3(64), dim3(256), 0, stream>>>(Bm, Cm);    // M^16
    k_matsq<<<dim3(64), dim3(256), 0, stream>>>(Cm, Bm);    // M^32
    k_matsq<<<dim3(64), dim3(256), 0, stream>>>(Bm, Cm);    // M^64 -> Cm

    k_modulate3<<<dim3(NN / FT2), dim3(512), 0, stream>>>(Vb, Ub, mp, Sb, 0);
    k_modulate3<<<dim3(NN / FT2), dim3(512), 0, stream>>>(Vb, Ub, mp, Sb, 1);
    k_ifft<<<dim3(512), dim3(256), 0, stream>>>(Sb, deltas);
    k_aru<<<dim3(1024), dim3(256), 0, stream>>>(x, m_u, deltas);

    k_chunk_local<<<dim3(512), dim3(64), 0, stream>>>(deltas, m_y, term);
    k_boundary<<<dim3(8), dim3(128), 0, stream>>>(Cm, term, sst);
    k_chunk_final<<<dim3(512), dim3(64), 0, stream>>>(deltas, m_y, sst, out);
}

// Round 5
// 462.725 us; speedup vs baseline: 7.2550x; 1.2413x over previous
//
#include <hip/hip_runtime.h>
#include <math.h>

#define BB 8
#define LL 4096
#define DD 64
#define KK 24
#define NN 8192
#define LOGN 13

typedef unsigned int uint;

__device__ __forceinline__ float bfl(uint u) {            // low bf16 -> float
    union { uint u; float f; } v; v.u = u << 16; return v.f;
}
__device__ __forceinline__ float bfh(uint u) {            // high bf16 -> float
    union { uint u; float f; } v; v.u = u & 0xFFFF0000u; return v.f;
}
__device__ __forceinline__ uint pk(float x) {             // float -> bf16 (rne), low bits
    union { float f; uint u; } v; v.f = x;
    return (v.u + 0x7FFFu + ((v.u >> 16) & 1u)) >> 16;
}
__device__ __forceinline__ float2 unpk2(uint u) {
    return make_float2(bfl(u), bfh(u));
}
__device__ __forceinline__ int br13(int v) { return (int)(__brev((uint)v) >> 19); }

// ---------------- FFT primitives (in-LDS, NT threads, N=8192) ----------------
template<int NT>
__device__ __forceinline__ void fft_dif(float2* a) {
    const int tid = threadIdx.x;
    for (int lh = LOGN - 1; lh >= 0; --lh) {
        const int half = 1 << lh;
        const float tw = -6.28318530717958647692f / (float)(2 << lh);
#pragma unroll
        for (int bb = 0; bb < NN / 2 / NT; ++bb) {
            int t = tid + bb * NT;
            int j = t & (half - 1);
            int i0 = ((t >> lh) << (lh + 1)) + j;
            float2 u = a[i0], v = a[i0 + half];
            float sn, cs;
            __sincosf(tw * (float)j, &sn, &cs);
            float dx = u.x - v.x, dy = u.y - v.y;
            a[i0] = make_float2(u.x + v.x, u.y + v.y);
            a[i0 + half] = make_float2(dx * cs - dy * sn, dx * sn + dy * cs);
        }
        __syncthreads();
    }
}

template<int NT>
__device__ __forceinline__ void fft_dit(float2* a) {
    const int tid = threadIdx.x;
    for (int lh = 0; lh < LOGN; ++lh) {
        const int half = 1 << lh;
        const float tw = 6.28318530717958647692f / (float)(2 << lh);
#pragma unroll
        for (int bb = 0; bb < NN / 2 / NT; ++bb) {
            int t = tid + bb * NT;
            int j = t & (half - 1);
            int i0 = ((t >> lh) << (lh + 1)) + j;
            float2 u = a[i0], v = a[i0 + half];
            float sn, cs;
            __sincosf(tw * (float)j, &sn, &cs);
            float wx = v.x * cs - v.y * sn;
            float wy = v.x * sn + v.y * cs;
            a[i0] = make_float2(u.x + wx, u.y + wy);
            a[i0 + half] = make_float2(u.x - wx, u.y - wy);
        }
        __syncthreads();
    }
}

// ---------------- kernels ----------------

// Pack m_phi into per-pass, k3-major bf16x4 table (3 planes of 4096 uint2 per pass).
__global__ __launch_bounds__(256) void k_pack(const float* __restrict__ mphi,
                                              uint2* __restrict__ mp) {
    int idx = blockIdx.x * 256 + threadIdx.x;
    if (idx >= 24576) return;
    int p = idx / 12288;
    int rem = idx - p * 12288;
    int k3 = rem >> 12;
    int e = rem & 4095;
    int c = e >> 6, o = e & 63;
    int kb = p * 12 + k3 * 4;
    uint x = pk(mphi[((kb + 0) * 64 + c) * 64 + o]) | (pk(mphi[((kb + 1) * 64 + c) * 64 + o]) << 16);
    uint y = pk(mphi[((kb + 2) * 64 + c) * 64 + o]) | (pk(mphi[((kb + 3) * 64 + c) * 64 + o]) << 16);
    mp[idx] = make_uint2(x, y);
}

// V[f,k] = FFT(eig_vecs[:,k] * lambda_k^0.25 / N), bit-reversed bins, fp32
__global__ __launch_bounds__(256) void k_fft_filters(const float* __restrict__ eig_vals,
                                                     const float* __restrict__ eig_vecs,
                                                     float2* __restrict__ Vb) {
    __shared__ float2 a[NN];
    const int k = blockIdx.x, tid = threadIdx.x;
    const float alpha = powf(eig_vals[k], 0.25f) * (1.0f / (float)NN);
    for (int t = tid; t < LL; t += 256)
        a[t] = make_float2(eig_vecs[t * KK + k] * alpha, 0.f);
    for (int t = LL + tid; t < NN; t += 256)
        a[t] = make_float2(0.f, 0.f);
    __syncthreads();
    fft_dif<256>(a);
    for (int r = tid; r < NN; r += 256)
        Vb[(size_t)r * KK + k] = a[r];
}

// Two real channels per complex FFT: z = x[:,c] + i x[:,c+1].
// Writes U only at Hermitian-half positions (even r, plus r=1 <-> f=4096).
__global__ __launch_bounds__(512) void k_fft_x2(const float* __restrict__ x,
                                                uint* __restrict__ Ub) {
    __shared__ float2 a[NN];
    const int b = blockIdx.x >> 5, cp = blockIdx.x & 31;
    const int tid = threadIdx.x;
    for (int l = tid; l < LL; l += 512)
        a[l] = *(const float2*)&x[((size_t)b * LL + l) * DD + 2 * cp];
    for (int l = LL + tid; l < NN; l += 512)
        a[l] = make_float2(0.f, 0.f);
    __syncthreads();
    fft_dif<512>(a);
    for (int idx = tid; idx < 4097; idx += 512) {
        int r = (idx == 4096) ? 1 : 2 * idx;
        int fn = br13(r);
        int q = br13((8192 - fn) & 8191);
        float2 Z = a[r], W = a[q];
        float ucx = 0.5f * (Z.x + W.x), ucy = 0.5f * (Z.y - W.y);
        float upx = 0.5f * (Z.y + W.y), upy = 0.5f * (W.x - Z.x);
        *(uint2*)&Ub[((size_t)b * NN + r) * DD + 2 * cp] =
            make_uint2(pk(ucx) | (pk(ucy) << 16), pk(upx) | (pk(upy) << 16));
    }
}

// float2 helpers (pairs over the two blocked positions -> candidate v_pk_fma_f32)
__device__ __forceinline__ void gacc(float2& gx, float2& gy,
                                     const float2* vx, const float2* vy,
                                     int kb, uint mw) {
    float m0 = bfl(mw), m1 = bfh(mw);
    gx.x += vx[kb].x * m0 + vx[kb + 1].x * m1;
    gx.y += vx[kb].y * m0 + vx[kb + 1].y * m1;
    gy.x += vy[kb].x * m0 + vy[kb + 1].x * m1;
    gy.y += vy[kb].y * m0 + vy[kb + 1].y * m1;
}
__device__ __forceinline__ void cmac2(float2& ax, float2& ay,
                                      float2 ux, float2 uy, float2 gx, float2 gy) {
    ax.x += ux.x * gx.x - uy.x * gy.x;  ax.y += ux.y * gx.y - uy.y * gy.y;
    ay.x += ux.x * gy.x + uy.x * gx.x;  ay.y += ux.y * gy.y + uy.y * gx.y;
}

// Per-pass modulate over Hermitian half only: 16 even positions per block
// (blocks 0..255), block 256 handles r=1 (f=4096). 2-position register blocking.
#define FE 16
__global__ __launch_bounds__(512) void k_modulate4(const float2* __restrict__ Vb,
                                                   const uint* __restrict__ Ub,
                                                   const uint2* __restrict__ mp,
                                                   uint* __restrict__ Sb,
                                                   const int p) {
    __shared__ __align__(16) uint2 mp_s[3 * 4096];     // 96 KB
    __shared__ __align__(16) uint2 Gs2[4096];          // 32 KB: {f0 bf16 cplx, f1 bf16 cplx}
    __shared__ __align__(16) uint2 Us2[512];           // 4 KB:  {f0, f1}
    __shared__ float2 Vt[FE * 12];                     // 1.5 KB
    const int tid = threadIdx.x;
    const int bx = blockIdx.x;
    const bool tail = (bx == 256);
    const int npairs = tail ? 1 : 8;

    {   // stage mphi half: 12288 uint2 = 6144 uint4
        const uint4* src = (const uint4*)(mp + (size_t)p * 12288);
        uint4* dst = (uint4*)mp_s;
        for (int i = tid; i < 6144; i += 512) dst[i] = src[i];
    }
    for (int i = tid; i < FE * 12; i += 512) {
        int fi = i / 12, j = i - fi * 12;
        int pos = tail ? 1 : bx * 32 + 2 * fi;
        Vt[i] = Vb[(size_t)pos * KK + p * 12 + j];
    }
    __syncthreads();

    const int o2 = tid & 31;          // o-pair
    const int ch = (tid >> 5) & 1;    // c-half
    const int b  = tid >> 6;          // wave index == batch
    const size_t ub0 = (size_t)b * NN * DD + (tid & 63);
    const uint2* SbV = (const uint2*)Sb;
    const size_t sp0 = (size_t)b * NN * 32 + o2;

    auto posf = [&](int pi, int h) { return tail ? 1 : bx * 32 + 4 * pi + 2 * h; };

    uint u0 = Ub[ub0 + (size_t)posf(0, 0) * DD];
    uint u1 = Ub[ub0 + (size_t)posf(0, 1) * DD];
    uint2 sc0 = make_uint2(0, 0), sc1 = make_uint2(0, 0);
    if (p && ch == 0) {
        sc0 = SbV[sp0 + (size_t)posf(0, 0) * 32];
        sc1 = SbV[sp0 + (size_t)posf(0, 1) * 32];
    }

    for (int pi = 0; pi < npairs; ++pi) {
        const int p0 = posf(pi, 0), p1 = posf(pi, 1);
        Us2[tid] = make_uint2(u0, u1);
        // prefetch next position-pair (hides under G-build + S-apply)
        uint nu0 = 0, nu1 = 0; uint2 ns0 = make_uint2(0, 0), ns1 = make_uint2(0, 0);
        if (pi + 1 < npairs) {
            nu0 = Ub[ub0 + (size_t)posf(pi + 1, 0) * DD];
            nu1 = Ub[ub0 + (size_t)posf(pi + 1, 1) * DD];
            if (p && ch == 0) {
                ns0 = SbV[sp0 + (size_t)posf(pi + 1, 0) * 32];
                ns1 = SbV[sp0 + (size_t)posf(pi + 1, 1) * 32];
            }
        }
        // V registers as position-pair vectors
        float2 vx[12], vy[12];
#pragma unroll
        for (int j = 0; j < 12; ++j) {
            float2 a = Vt[(2 * pi) * 12 + j], b2 = Vt[(2 * pi + 1) * 12 + j];
            vx[j] = make_float2(a.x, b2.x);
            vy[j] = make_float2(a.y, b2.y);
        }
        // G build: elem pairs, b128 in / b128 out
#pragma unroll
        for (int i = 0; i < 4; ++i) {
            int e0 = 2 * (tid + i * 512);
            uint4 mA = *(const uint4*)&mp_s[e0];
            uint4 mB = *(const uint4*)&mp_s[4096 + e0];
            uint4 mC = *(const uint4*)&mp_s[8192 + e0];
            float2 gx0 = {0, 0}, gy0 = {0, 0}, gx1 = {0, 0}, gy1 = {0, 0};
            gacc(gx0, gy0, vx, vy, 0, mA.x);  gacc(gx0, gy0, vx, vy, 2, mA.y);
            gacc(gx0, gy0, vx, vy, 4, mB.x);  gacc(gx0, gy0, vx, vy, 6, mB.y);
            gacc(gx0, gy0, vx, vy, 8, mC.x);  gacc(gx0, gy0, vx, vy, 10, mC.y);
            gacc(gx1, gy1, vx, vy, 0, mA.z);  gacc(gx1, gy1, vx, vy, 2, mA.w);
            gacc(gx1, gy1, vx, vy, 4, mB.z);  gacc(gx1, gy1, vx, vy, 6, mB.w);
            gacc(gx1, gy1, vx, vy, 8, mC.z);  gacc(gx1, gy1, vx, vy, 10, mC.w);
            uint4 w;
            w.x = pk(gx0.x) | (pk(gy0.x) << 16);
            w.y = pk(gx0.y) | (pk(gy0.y) << 16);
            w.z = pk(gx1.x) | (pk(gy1.x) << 16);
            w.w = pk(gx1.y) | (pk(gy1.y) << 16);
            *(uint4*)&Gs2[e0] = w;
        }
        __syncthreads();
        // S apply: (b, o-pair, c-half), c unrolled by 2, all b128 reads
        {
            float2 A0x = {0, 0}, A0y = {0, 0}, A1x = {0, 0}, A1y = {0, 0};
            const int cbase = ch * 32;
#pragma unroll
            for (int cc = 0; cc < 16; ++cc) {
                int c = cbase + cc * 2;
                uint4 uu = *(const uint4*)&Us2[b * 64 + c];
                uint4 g0 = *(const uint4*)&Gs2[c * 64 + o2 * 2];
                uint4 g1 = *(const uint4*)&Gs2[(c + 1) * 64 + o2 * 2];
                float2 ux = make_float2(bfl(uu.x), bfl(uu.y));
                float2 uy = make_float2(bfh(uu.x), bfh(uu.y));
                float2 g0x0 = make_float2(bfl(g0.x), bfl(g0.y));
                float2 g0y0 = make_float2(bfh(g0.x), bfh(g0.y));
                float2 g0x1 = make_float2(bfl(g0.z), bfl(g0.w));
                float2 g0y1 = make_float2(bfh(g0.z), bfh(g0.w));
                cmac2(A0x, A0y, ux, uy, g0x0, g0y0);
                cmac2(A1x, A1y, ux, uy, g0x1, g0y1);
                float2 vx2 = make_float2(bfl(uu.z), bfl(uu.w));
                float2 vy2 = make_float2(bfh(uu.z), bfh(uu.w));
                float2 g1x0 = make_float2(bfl(g1.x), bfl(g1.y));
                float2 g1y0 = make_float2(bfh(g1.x), bfh(g1.y));
                float2 g1x1 = make_float2(bfl(g1.z), bfl(g1.w));
                float2 g1y1 = make_float2(bfh(g1.z), bfh(g1.w));
                cmac2(A0x, A0y, vx2, vy2, g1x0, g1y0);
                cmac2(A1x, A1y, vx2, vy2, g1x1, g1y1);
            }
            A0x.x += __shfl_xor(A0x.x, 32);  A0x.y += __shfl_xor(A0x.y, 32);
            A0y.x += __shfl_xor(A0y.x, 32);  A0y.y += __shfl_xor(A0y.y, 32);
            A1x.x += __shfl_xor(A1x.x, 32);  A1x.y += __shfl_xor(A1x.y, 32);
            A1y.x += __shfl_xor(A1y.x, 32);  A1y.y += __shfl_xor(A1y.y, 32);
            if (ch == 0) {
                float s0x = A0x.x, s0y = A0y.x, s1x = A1x.x, s1y = A1y.x;   // p0
                float t0x = A0x.y, t0y = A0y.y, t1x = A1x.y, t1y = A1y.y;   // p1
                if (p) {
                    s0x += bfl(sc0.x); s0y += bfh(sc0.x); s1x += bfl(sc0.y); s1y += bfh(sc0.y);
                    t0x += bfl(sc1.x); t0y += bfh(sc1.x); t1x += bfl(sc1.y); t1y += bfh(sc1.y);
                }
                *(uint2*)&Sb[((size_t)b * NN + p0) * DD + o2 * 2] =
                    make_uint2(pk(s0x) | (pk(s0y) << 16), pk(s1x) | (pk(s1y) << 16));
                *(uint2*)&Sb[((size_t)b * NN + p1) * DD + o2 * 2] =
                    make_uint2(pk(t0x) | (pk(t0y) << 16), pk(t1x) | (pk(t1y) << 16));
            }
        }
        __syncthreads();
        u0 = nu0; u1 = nu1; sc0 = ns0; sc1 = ns1;
    }
}

// Two output channels per inverse FFT. Stages Hermitian half, reconstructs odd
// positions in LDS: z[q] = conj(S_o[r]) + i conj(S_o'[r]).
__global__ __launch_bounds__(512) void k_ifft2(const uint* __restrict__ Sb,
                                               float* __restrict__ deltas) {
    __shared__ float2 a[NN];
    const int b = blockIdx.x >> 5, op = blockIdx.x & 31;
    const int tid = threadIdx.x;
    for (int idx = tid; idx < 4097; idx += 512) {
        int r = (idx == 4096) ? 1 : 2 * idx;
        uint2 w = *(const uint2*)&Sb[((size_t)b * NN + r) * DD + op * 2];
        float2 A = unpk2(w.x), B = unpk2(w.y);
        a[r] = make_float2(A.x - B.y, A.y + B.x);
        int fn = br13(r);
        int q = br13((8192 - fn) & 8191);
        if (q != r) a[q] = make_float2(A.x + B.y, B.x - A.y);
    }
    __syncthreads();
    fft_dit<512>(a);
    for (int l = tid; l < LL; l += 512)
        *(float2*)&deltas[((size_t)b * LL + l) * DD + op * 2] = make_float2(a[l].x, a[l].y);
}

// deltas += AR-U
__global__ __launch_bounds__(256) void k_aru(const float* __restrict__ x,
                                             const float* __restrict__ m_u,
                                             float* __restrict__ deltas) {
    __shared__ float mu_s[64 * 193];
    __shared__ float xs[34 * 64];
    const int tid = threadIdx.x;
    const int b = blockIdx.x >> 7;
    const int l0 = (blockIdx.x & 127) * 32;
    for (int idx = tid; idx < 64 * 192; idx += 256) {
        int o = idx / 192;
        int rem = idx - o * 192;
        mu_s[o * 193 + rem] = m_u[idx];
    }
    for (int idx = tid; idx < 34 * 64; idx += 256) {
        int rr = idx >> 6, i = idx & 63;
        int gl = l0 - 2 + rr;
        xs[idx] = (gl >= 0) ? x[((size_t)b * LL + gl) * DD + i] : 0.f;
    }
    __syncthreads();
    const int o = tid & 63, lsub = tid >> 6;
    for (int lb = 0; lb < 8; ++lb) {
        int ll = lsub * 8 + lb;
        int r = ll + 2;
        float acc = 0.f;
#pragma unroll
        for (int i = 0; i < 64; ++i) {
            int mb = o * 193 + i * 3;
            acc += mu_s[mb]     * xs[r * 64 + i]
                 + mu_s[mb + 1] * xs[(r - 1) * 64 + i]
                 + mu_s[mb + 2] * xs[(r - 2) * 64 + i];
        }
        deltas[((size_t)b * LL + l0 + ll) * DD + o] += acc;
    }
}

// First squaring with companion matrix built on the fly from m_y.
__global__ __launch_bounds__(256) void k_matsq1(const float* __restrict__ m_y,
                                                float* __restrict__ C) {
    int idx = blockIdx.x * 256 + threadIdx.x;
    int r = idx >> 7, c = idx & 127;
    if (r >= 64) { C[idx] = m_y[(r - 64) * 128 + c]; return; }
    float acc = (c < 64) ? m_y[r * 128 + 64 + c] : 0.f;
#pragma unroll
    for (int i = 0; i < 64; ++i) acc += m_y[r * 128 + i] * m_y[i * 128 + c];
    C[idx] = acc;
}

__global__ __launch_bounds__(256) void k_matsq(const float* __restrict__ A,
                                               float* __restrict__ C) {
    int idx = blockIdx.x * 256 + threadIdx.x;
    int r = idx >> 7, c = idx & 127;
    float acc = 0.f;
#pragma unroll
    for (int i = 0; i < 128; ++i) acc += A[r * 128 + i] * A[i * 128 + c];
    C[idx] = acc;
}

__global__ __launch_bounds__(64, 1) void k_chunk_local(const float* __restrict__ deltas,
                                                       const float* __restrict__ m_y,
                                                       float* __restrict__ term) {
    const int b = blockIdx.x >> 6, j = blockIdx.x & 63;
    const int o = threadIdx.x;
    __shared__ __align__(16) float y1s[64];
    __shared__ __align__(16) float y2s[64];
    float a1r[64], a2r[64];
#pragma unroll
    for (int i4 = 0; i4 < 16; ++i4) {
        float4 v1 = *(const float4*)&m_y[o * 128 + i4 * 4];
        float4 v2 = *(const float4*)&m_y[o * 128 + 64 + i4 * 4];
        a1r[4 * i4] = v1.x; a1r[4 * i4 + 1] = v1.y; a1r[4 * i4 + 2] = v1.z; a1r[4 * i4 + 3] = v1.w;
        a2r[4 * i4] = v2.x; a2r[4 * i4 + 1] = v2.y; a2r[4 * i4 + 2] = v2.z; a2r[4 * i4 + 3] = v2.w;
    }
    y1s[o] = 0.f; y2s[o] = 0.f;
    __syncthreads();
    const float* dl = &deltas[(((size_t)b * LL) + j * 64) * DD + o];
    for (int t = 0; t < 64; ++t) {
        float acc = dl[t * DD];
#pragma unroll
        for (int i4 = 0; i4 < 16; ++i4) {
            float4 w1 = *(const float4*)&y1s[i4 * 4];
            float4 w2 = *(const float4*)&y2s[i4 * 4];
            acc += a1r[4 * i4] * w1.x + a1r[4 * i4 + 1] * w1.y + a1r[4 * i4 + 2] * w1.z + a1r[4 * i4 + 3] * w1.w
                 + a2r[4 * i4] * w2.x + a2r[4 * i4 + 1] * w2.y + a2r[4 * i4 + 2] * w2.z + a2r[4 * i4 + 3] * w2.w;
        }
        __syncthreads();
        y2s[o] = y1s[o];
        y1s[o] = acc;
        __syncthreads();
    }
    term[((size_t)b * 64 + j) * 128 + o] = y1s[o];
    term[((size_t)b * 64 + j) * 128 + 64 + o] = y2s[o];
}

__global__ __launch_bounds__(128, 1) void k_boundary(const float* __restrict__ P,
                                                     const float* __restrict__ term,
                                                     float* __restrict__ sstate) {
    const int b = blockIdx.x;
    const int r = threadIdx.x;
    __shared__ __align__(16) float scur[128];
    float p[128];
#pragma unroll
    for (int i4 = 0; i4 < 32; ++i4) {
        float4 v = *(const float4*)&P[r * 128 + i4 * 4];
        p[4 * i4] = v.x; p[4 * i4 + 1] = v.y; p[4 * i4 + 2] = v.z; p[4 * i4 + 3] = v.w;
    }
    scur[r] = 0.f;
    __syncthreads();
    for (int j = 0; j < 64; ++j) {
        sstate[((size_t)b * 64 + j) * 128 + r] = scur[r];
        float acc = term[((size_t)b * 64 + j) * 128 + r];
#pragma unroll
        for (int i4 = 0; i4 < 32; ++i4) {
            float4 w = *(const float4*)&scur[i4 * 4];
            acc += p[4 * i4] * w.x + p[4 * i4 + 1] * w.y + p[4 * i4 + 2] * w.z + p[4 * i4 + 3] * w.w;
        }
        __syncthreads();
        scur[r] = acc;
        __syncthreads();
    }
}

__global__ __launch_bounds__(64, 1) void k_chunk_final(const float* __restrict__ deltas,
                                                       const float* __restrict__ m_y,
                                                       const float* __restrict__ sstate,
                                                       float* __restrict__ out) {
    const int b = blockIdx.x >> 6, j = blockIdx.x & 63;
    const int o = threadIdx.x;
    __shared__ __align__(16) float y1s[64];
    __shared__ __align__(16) float y2s[64];
    float a1r[64], a2r[64];
#pragma unroll
    for (int i4 = 0; i4 < 16; ++i4) {
        float4 v1 = *(const float4*)&m_y[o * 128 + i4 * 4];
        float4 v2 = *(const float4*)&m_y[o * 128 + 64 + i4 * 4];
        a1r[4 * i4] = v1.x; a1r[4 * i4 + 1] = v1.y; a1r[4 * i4 + 2] = v1.z; a1r[4 * i4 + 3] = v1.w;
        a2r[4 * i4] = v2.x; a2r[4 * i4 + 1] = v2.y; a2r[4 * i4 + 2] = v2.z; a2r[4 * i4 + 3] = v2.w;
    }
    y1s[o] = sstate[((size_t)b * 64 + j) * 128 + o];
    y2s[o] = sstate[((size_t)b * 64 + j) * 128 + 64 + o];
    __syncthreads();
    const size_t base = (((size_t)b * LL) + j * 64) * DD + o;
    for (int t = 0; t < 64; ++t) {
        float acc = deltas[base + (size_t)t * DD];
#pragma unroll
        for (int i4 = 0; i4 < 16; ++i4) {
            float4 w1 = *(const float4*)&y1s[i4 * 4];
            float4 w2 = *(const float4*)&y2s[i4 * 4];
            acc += a1r[4 * i4] * w1.x + a1r[4 * i4 + 1] * w1.y + a1r[4 * i4 + 2] * w1.z + a1r[4 * i4 + 3] * w1.w
                 + a2r[4 * i4] * w2.x + a2r[4 * i4 + 1] * w2.y + a2r[4 * i4 + 2] * w2.z + a2r[4 * i4 + 3] * w2.w;
        }
        out[base + (size_t)t * DD] = acc;
        __syncthreads();
        y2s[o] = y1s[o];
        y1s[o] = acc;
        __syncthreads();
    }
}

extern "C" void kernel_launch(void* const* d_in, const int* in_sizes, int n_in,
                              void* d_out, int out_size, void* d_ws, size_t ws_size,
                              hipStream_t stream) {
    const float* x        = (const float*)d_in[0];
    const float* m_y      = (const float*)d_in[1];
    const float* m_u      = (const float*)d_in[2];
    const float* m_phi    = (const float*)d_in[3];
    const float* eig_vals = (const float*)d_in[4];
    const float* eig_vecs = (const float*)d_in[5];
    float* out = (float*)d_out;

    char* ws = (char*)d_ws;
    size_t off = 0;
    auto alloc = [&](size_t bytes) -> void* {
        void* p = ws + off;
        off += (bytes + 255) & ~(size_t)255;
        return p;
    };
    float2* Vb   = (float2*)alloc((size_t)NN * KK * sizeof(float2));          // 1.5 MB
    uint*   Ub   = (uint*)alloc((size_t)BB * NN * DD * sizeof(uint));         // 16.8 MB
    uint*   Sb   = (uint*)alloc((size_t)BB * NN * DD * sizeof(uint));         // 16.8 MB
    float*  deltas = (float*)alloc((size_t)BB * LL * DD * sizeof(float));     // 8.4 MB
    uint2*  mp   = (uint2*)alloc((size_t)24576 * sizeof(uint2));              // 0.2 MB
    float*  mats = (float*)alloc((size_t)3 * 128 * 128 * sizeof(float));
    float*  term = (float*)alloc((size_t)BB * 64 * 128 * sizeof(float));
    float*  sst  = (float*)alloc((size_t)BB * 64 * 128 * sizeof(float));

    k_pack<<<dim3(96), dim3(256), 0, stream>>>(m_phi, mp);
    k_fft_filters<<<dim3(24), dim3(256), 0, stream>>>(eig_vals, eig_vecs, Vb);
    k_fft_x2<<<dim3(256), dim3(512), 0, stream>>>(x, Ub);

    float* Bm = mats + 16384;
    float* Cm = mats + 32768;
    k_matsq1<<<dim3(64), dim3(256), 0, stream>>>(m_y, Bm);  // M^2
    k_matsq<<<dim3(64), dim3(256), 0, stream>>>(Bm, Cm);    // M^4
    k_matsq<<<dim3(64), dim3(256), 0, stream>>>(Cm, Bm);    // M^8
    k_matsq<<<dim3(64), dim3(256), 0, stream>>>(Bm, Cm);    // M^16
    k_matsq<<<dim3(64), dim3(256), 0, stream>>>(Cm, Bm);    // M^32
    k_matsq<<<dim3(64), dim3(256), 0, stream>>>(Bm, Cm);    // M^64 -> Cm

    k_modulate4<<<dim3(257), dim3(512), 0, stream>>>(Vb, Ub, mp, Sb, 0);
    k_modulate4<<<dim3(257), dim3(512), 0, stream>>>(Vb, Ub, mp, Sb, 1);
    k_ifft2<<<dim3(256), dim3(512), 0, stream>>>(Sb, deltas);
    k_aru<<<dim3(1024), dim3(256), 0, stream>>>(x, m_u, deltas);

    k_chunk_local<<<dim3(512), dim3(64), 0, stream>>>(deltas, m_y, term);
    k_boundary<<<dim3(8), dim3(128), 0, stream>>>(Cm, term, sst);
    k_chunk_final<<<dim3(512), dim3(64), 0, stream>>>(deltas, m_y, sst, out);
}

// Round 6
// 415.133 us; speedup vs baseline: 8.0868x; 1.1146x over previous
//
#include <hip/hip_runtime.h>
#include <math.h>

#define BB 8
#define LL 4096
#define DD 64
#define KK 24
#define NN 8192
#define LOGN 13

typedef unsigned int uint;

__device__ __forceinline__ float bfl(uint u) {            // low bf16 -> float
    union { uint u; float f; } v; v.u = u << 16; return v.f;
}
__device__ __forceinline__ float bfh(uint u) {            // high bf16 -> float
    union { uint u; float f; } v; v.u = u & 0xFFFF0000u; return v.f;
}
__device__ __forceinline__ uint pk(float x) {             // float -> bf16 (rne), low bits
    union { float f; uint u; } v; v.f = x;
    return (v.u + 0x7FFFu + ((v.u >> 16) & 1u)) >> 16;
}
__device__ __forceinline__ float2 unpk2(uint u) {
    return make_float2(bfl(u), bfh(u));
}
__device__ __forceinline__ int br13(int v) { return (int)(__brev((uint)v) >> 19); }

// ---------------- FFT primitives (in-LDS, NT threads, N=8192) ----------------
template<int NT>
__device__ __forceinline__ void fft_dif(float2* a) {
    const int tid = threadIdx.x;
    for (int lh = LOGN - 1; lh >= 0; --lh) {
        const int half = 1 << lh;
        const float tw = -6.28318530717958647692f / (float)(2 << lh);
#pragma unroll
        for (int bb = 0; bb < NN / 2 / NT; ++bb) {
            int t = tid + bb * NT;
            int j = t & (half - 1);
            int i0 = ((t >> lh) << (lh + 1)) + j;
            float2 u = a[i0], v = a[i0 + half];
            float sn, cs;
            __sincosf(tw * (float)j, &sn, &cs);
            float dx = u.x - v.x, dy = u.y - v.y;
            a[i0] = make_float2(u.x + v.x, u.y + v.y);
            a[i0 + half] = make_float2(dx * cs - dy * sn, dx * sn + dy * cs);
        }
        __syncthreads();
    }
}

template<int NT>
__device__ __forceinline__ void fft_dit(float2* a) {
    const int tid = threadIdx.x;
    for (int lh = 0; lh < LOGN; ++lh) {
        const int half = 1 << lh;
        const float tw = 6.28318530717958647692f / (float)(2 << lh);
#pragma unroll
        for (int bb = 0; bb < NN / 2 / NT; ++bb) {
            int t = tid + bb * NT;
            int j = t & (half - 1);
            int i0 = ((t >> lh) << (lh + 1)) + j;
            float2 u = a[i0], v = a[i0 + half];
            float sn, cs;
            __sincosf(tw * (float)j, &sn, &cs);
            float wx = v.x * cs - v.y * sn;
            float wy = v.x * sn + v.y * cs;
            a[i0] = make_float2(u.x + wx, u.y + wy);
            a[i0 + half] = make_float2(u.x - wx, u.y - wy);
        }
        __syncthreads();
    }
}

// ---------------- kernels ----------------

// Pack m_phi into per-pass, k3-major bf16x4 table (3 planes of 4096 uint2 per pass).
__global__ __launch_bounds__(256) void k_pack(const float* __restrict__ mphi,
                                              uint2* __restrict__ mp) {
    int idx = blockIdx.x * 256 + threadIdx.x;
    if (idx >= 24576) return;
    int p = idx / 12288;
    int rem = idx - p * 12288;
    int k3 = rem >> 12;
    int e = rem & 4095;
    int c = e >> 6, o = e & 63;
    int kb = p * 12 + k3 * 4;
    uint x = pk(mphi[((kb + 0) * 64 + c) * 64 + o]) | (pk(mphi[((kb + 1) * 64 + c) * 64 + o]) << 16);
    uint y = pk(mphi[((kb + 2) * 64 + c) * 64 + o]) | (pk(mphi[((kb + 3) * 64 + c) * 64 + o]) << 16);
    mp[idx] = make_uint2(x, y);
}

// V[f,k] = FFT(eig_vecs[:,k] * lambda_k^0.25 / N), bit-reversed bins, fp32
__global__ __launch_bounds__(256) void k_fft_filters(const float* __restrict__ eig_vals,
                                                     const float* __restrict__ eig_vecs,
                                                     float2* __restrict__ Vb) {
    __shared__ float2 a[NN];
    const int k = blockIdx.x, tid = threadIdx.x;
    const float alpha = powf(eig_vals[k], 0.25f) * (1.0f / (float)NN);
    for (int t = tid; t < LL; t += 256)
        a[t] = make_float2(eig_vecs[t * KK + k] * alpha, 0.f);
    for (int t = LL + tid; t < NN; t += 256)
        a[t] = make_float2(0.f, 0.f);
    __syncthreads();
    fft_dif<256>(a);
    for (int r = tid; r < NN; r += 256)
        Vb[(size_t)r * KK + k] = a[r];
}

// Two real channels per complex FFT: z = x[:,c] + i x[:,c+1].
// Writes U only at Hermitian-half positions (even r, plus r=1 <-> f=4096).
__global__ __launch_bounds__(512) void k_fft_x2(const float* __restrict__ x,
                                                uint* __restrict__ Ub) {
    __shared__ float2 a[NN];
    const int b = blockIdx.x >> 5, cp = blockIdx.x & 31;
    const int tid = threadIdx.x;
    for (int l = tid; l < LL; l += 512)
        a[l] = *(const float2*)&x[((size_t)b * LL + l) * DD + 2 * cp];
    for (int l = LL + tid; l < NN; l += 512)
        a[l] = make_float2(0.f, 0.f);
    __syncthreads();
    fft_dif<512>(a);
    for (int idx = tid; idx < 4097; idx += 512) {
        int r = (idx == 4096) ? 1 : 2 * idx;
        int fn = br13(r);
        int q = br13((8192 - fn) & 8191);
        float2 Z = a[r], W = a[q];
        float ucx = 0.5f * (Z.x + W.x), ucy = 0.5f * (Z.y - W.y);
        float upx = 0.5f * (Z.y + W.y), upy = 0.5f * (W.x - Z.x);
        *(uint2*)&Ub[((size_t)b * NN + r) * DD + 2 * cp] =
            make_uint2(pk(ucx) | (pk(ucy) << 16), pk(upx) | (pk(upy) << 16));
    }
}

// float2 helpers (pairs over the two blocked positions -> candidate v_pk_fma_f32)
__device__ __forceinline__ void gacc(float2& gx, float2& gy,
                                     const float2* vx, const float2* vy,
                                     int kb, uint mw) {
    float m0 = bfl(mw), m1 = bfh(mw);
    gx.x += vx[kb].x * m0 + vx[kb + 1].x * m1;
    gx.y += vx[kb].y * m0 + vx[kb + 1].y * m1;
    gy.x += vy[kb].x * m0 + vy[kb + 1].x * m1;
    gy.y += vy[kb].y * m0 + vy[kb + 1].y * m1;
}
__device__ __forceinline__ void cmac2(float2& ax, float2& ay,
                                      float2 ux, float2 uy, float2 gx, float2 gy) {
    ax.x += ux.x * gx.x - uy.x * gy.x;  ax.y += ux.y * gx.y - uy.y * gy.y;
    ay.x += ux.x * gy.x + uy.x * gx.x;  ay.y += ux.y * gy.y + uy.y * gx.y;
}

// Per-pass modulate over Hermitian half only: 16 even positions per block
// (blocks 0..255), block 256 handles r=1 (f=4096). 2-position register blocking.
#define FE 16
__global__ __launch_bounds__(512) void k_modulate4(const float2* __restrict__ Vb,
                                                   const uint* __restrict__ Ub,
                                                   const uint2* __restrict__ mp,
                                                   uint* __restrict__ Sb,
                                                   const int p) {
    __shared__ __align__(16) uint2 mp_s[3 * 4096];     // 96 KB
    __shared__ __align__(16) uint2 Gs2[4096];          // 32 KB: {f0 bf16 cplx, f1 bf16 cplx}
    __shared__ __align__(16) uint2 Us2[512];           // 4 KB:  {f0, f1}
    __shared__ float2 Vt[FE * 12];                     // 1.5 KB
    const int tid = threadIdx.x;
    const int bx = blockIdx.x;
    const bool tail = (bx == 256);
    const int npairs = tail ? 1 : 8;

    {   // stage mphi half: 12288 uint2 = 6144 uint4
        const uint4* src = (const uint4*)(mp + (size_t)p * 12288);
        uint4* dst = (uint4*)mp_s;
        for (int i = tid; i < 6144; i += 512) dst[i] = src[i];
    }
    for (int i = tid; i < FE * 12; i += 512) {
        int fi = i / 12, j = i - fi * 12;
        int pos = tail ? 1 : bx * 32 + 2 * fi;
        Vt[i] = Vb[(size_t)pos * KK + p * 12 + j];
    }
    __syncthreads();

    const int o2 = tid & 31;          // o-pair
    const int ch = (tid >> 5) & 1;    // c-half
    const int b  = tid >> 6;          // wave index == batch
    const size_t ub0 = (size_t)b * NN * DD + (tid & 63);
    const uint2* SbV = (const uint2*)Sb;
    const size_t sp0 = (size_t)b * NN * 32 + o2;

    auto posf = [&](int pi, int h) { return tail ? 1 : bx * 32 + 4 * pi + 2 * h; };

    uint u0 = Ub[ub0 + (size_t)posf(0, 0) * DD];
    uint u1 = Ub[ub0 + (size_t)posf(0, 1) * DD];
    uint2 sc0 = make_uint2(0, 0), sc1 = make_uint2(0, 0);
    if (p && ch == 0) {
        sc0 = SbV[sp0 + (size_t)posf(0, 0) * 32];
        sc1 = SbV[sp0 + (size_t)posf(0, 1) * 32];
    }

    for (int pi = 0; pi < npairs; ++pi) {
        const int p0 = posf(pi, 0), p1 = posf(pi, 1);
        Us2[tid] = make_uint2(u0, u1);
        // prefetch next position-pair (hides under G-build + S-apply)
        uint nu0 = 0, nu1 = 0; uint2 ns0 = make_uint2(0, 0), ns1 = make_uint2(0, 0);
        if (pi + 1 < npairs) {
            nu0 = Ub[ub0 + (size_t)posf(pi + 1, 0) * DD];
            nu1 = Ub[ub0 + (size_t)posf(pi + 1, 1) * DD];
            if (p && ch == 0) {
                ns0 = SbV[sp0 + (size_t)posf(pi + 1, 0) * 32];
                ns1 = SbV[sp0 + (size_t)posf(pi + 1, 1) * 32];
            }
        }
        // V registers as position-pair vectors
        float2 vx[12], vy[12];
#pragma unroll
        for (int j = 0; j < 12; ++j) {
            float2 a = Vt[(2 * pi) * 12 + j], b2 = Vt[(2 * pi + 1) * 12 + j];
            vx[j] = make_float2(a.x, b2.x);
            vy[j] = make_float2(a.y, b2.y);
        }
        // G build: elem pairs, b128 in / b128 out
#pragma unroll
        for (int i = 0; i < 4; ++i) {
            int e0 = 2 * (tid + i * 512);
            uint4 mA = *(const uint4*)&mp_s[e0];
            uint4 mB = *(const uint4*)&mp_s[4096 + e0];
            uint4 mC = *(const uint4*)&mp_s[8192 + e0];
            float2 gx0 = {0, 0}, gy0 = {0, 0}, gx1 = {0, 0}, gy1 = {0, 0};
            gacc(gx0, gy0, vx, vy, 0, mA.x);  gacc(gx0, gy0, vx, vy, 2, mA.y);
            gacc(gx0, gy0, vx, vy, 4, mB.x);  gacc(gx0, gy0, vx, vy, 6, mB.y);
            gacc(gx0, gy0, vx, vy, 8, mC.x);  gacc(gx0, gy0, vx, vy, 10, mC.y);
            gacc(gx1, gy1, vx, vy, 0, mA.z);  gacc(gx1, gy1, vx, vy, 2, mA.w);
            gacc(gx1, gy1, vx, vy, 4, mB.z);  gacc(gx1, gy1, vx, vy, 6, mB.w);
            gacc(gx1, gy1, vx, vy, 8, mC.z);  gacc(gx1, gy1, vx, vy, 10, mC.w);
            uint4 w;
            w.x = pk(gx0.x) | (pk(gy0.x) << 16);
            w.y = pk(gx0.y) | (pk(gy0.y) << 16);
            w.z = pk(gx1.x) | (pk(gy1.x) << 16);
            w.w = pk(gx1.y) | (pk(gy1.y) << 16);
            *(uint4*)&Gs2[e0] = w;
        }
        __syncthreads();
        // S apply: (b, o-pair, c-half), c unrolled by 2, all b128 reads
        {
            float2 A0x = {0, 0}, A0y = {0, 0}, A1x = {0, 0}, A1y = {0, 0};
            const int cbase = ch * 32;
#pragma unroll
            for (int cc = 0; cc < 16; ++cc) {
                int c = cbase + cc * 2;
                uint4 uu = *(const uint4*)&Us2[b * 64 + c];
                uint4 g0 = *(const uint4*)&Gs2[c * 64 + o2 * 2];
                uint4 g1 = *(const uint4*)&Gs2[(c + 1) * 64 + o2 * 2];
                float2 ux = make_float2(bfl(uu.x), bfl(uu.y));
                float2 uy = make_float2(bfh(uu.x), bfh(uu.y));
                float2 g0x0 = make_float2(bfl(g0.x), bfl(g0.y));
                float2 g0y0 = make_float2(bfh(g0.x), bfh(g0.y));
                float2 g0x1 = make_float2(bfl(g0.z), bfl(g0.w));
                float2 g0y1 = make_float2(bfh(g0.z), bfh(g0.w));
                cmac2(A0x, A0y, ux, uy, g0x0, g0y0);
                cmac2(A1x, A1y, ux, uy, g0x1, g0y1);
                float2 vx2 = make_float2(bfl(uu.z), bfl(uu.w));
                float2 vy2 = make_float2(bfh(uu.z), bfh(uu.w));
                float2 g1x0 = make_float2(bfl(g1.x), bfl(g1.y));
                float2 g1y0 = make_float2(bfh(g1.x), bfh(g1.y));
                float2 g1x1 = make_float2(bfl(g1.z), bfl(g1.w));
                float2 g1y1 = make_float2(bfh(g1.z), bfh(g1.w));
                cmac2(A0x, A0y, vx2, vy2, g1x0, g1y0);
                cmac2(A1x, A1y, vx2, vy2, g1x1, g1y1);
            }
            A0x.x += __shfl_xor(A0x.x, 32);  A0x.y += __shfl_xor(A0x.y, 32);
            A0y.x += __shfl_xor(A0y.x, 32);  A0y.y += __shfl_xor(A0y.y, 32);
            A1x.x += __shfl_xor(A1x.x, 32);  A1x.y += __shfl_xor(A1x.y, 32);
            A1y.x += __shfl_xor(A1y.x, 32);  A1y.y += __shfl_xor(A1y.y, 32);
            if (ch == 0) {
                float s0x = A0x.x, s0y = A0y.x, s1x = A1x.x, s1y = A1y.x;   // p0
                float t0x = A0x.y, t0y = A0y.y, t1x = A1x.y, t1y = A1y.y;   // p1
                if (p) {
                    s0x += bfl(sc0.x); s0y += bfh(sc0.x); s1x += bfl(sc0.y); s1y += bfh(sc0.y);
                    t0x += bfl(sc1.x); t0y += bfh(sc1.x); t1x += bfl(sc1.y); t1y += bfh(sc1.y);
                }
                *(uint2*)&Sb[((size_t)b * NN + p0) * DD + o2 * 2] =
                    make_uint2(pk(s0x) | (pk(s0y) << 16), pk(s1x) | (pk(s1y) << 16));
                *(uint2*)&Sb[((size_t)b * NN + p1) * DD + o2 * 2] =
                    make_uint2(pk(t0x) | (pk(t0y) << 16), pk(t1x) | (pk(t1y) << 16));
            }
        }
        __syncthreads();
        u0 = nu0; u1 = nu1; sc0 = ns0; sc1 = ns1;
    }
}

// Two output channels per inverse FFT. Stages Hermitian half, reconstructs odd
// positions in LDS: z[q] = conj(S_o[r]) + i conj(S_o'[r]).
__global__ __launch_bounds__(512) void k_ifft2(const uint* __restrict__ Sb,
                                               float* __restrict__ deltas) {
    __shared__ float2 a[NN];
    const int b = blockIdx.x >> 5, op = blockIdx.x & 31;
    const int tid = threadIdx.x;
    for (int idx = tid; idx < 4097; idx += 512) {
        int r = (idx == 4096) ? 1 : 2 * idx;
        uint2 w = *(const uint2*)&Sb[((size_t)b * NN + r) * DD + op * 2];
        float2 A = unpk2(w.x), B = unpk2(w.y);
        a[r] = make_float2(A.x - B.y, A.y + B.x);
        int fn = br13(r);
        int q = br13((8192 - fn) & 8191);
        if (q != r) a[q] = make_float2(A.x + B.y, B.x - A.y);
    }
    __syncthreads();
    fft_dit<512>(a);
    for (int l = tid; l < LL; l += 512)
        *(float2*)&deltas[((size_t)b * LL + l) * DD + op * 2] = make_float2(a[l].x, a[l].y);
}

// deltas += AR-U
__global__ __launch_bounds__(256) void k_aru(const float* __restrict__ x,
                                             const float* __restrict__ m_u,
                                             float* __restrict__ deltas) {
    __shared__ float mu_s[64 * 193];
    __shared__ float xs[34 * 64];
    const int tid = threadIdx.x;
    const int b = blockIdx.x >> 7;
    const int l0 = (blockIdx.x & 127) * 32;
    for (int idx = tid; idx < 64 * 192; idx += 256) {
        int o = idx / 192;
        int rem = idx - o * 192;
        mu_s[o * 193 + rem] = m_u[idx];
    }
    for (int idx = tid; idx < 34 * 64; idx += 256) {
        int rr = idx >> 6, i = idx & 63;
        int gl = l0 - 2 + rr;
        xs[idx] = (gl >= 0) ? x[((size_t)b * LL + gl) * DD + i] : 0.f;
    }
    __syncthreads();
    const int o = tid & 63, lsub = tid >> 6;
    for (int lb = 0; lb < 8; ++lb) {
        int ll = lsub * 8 + lb;
        int r = ll + 2;
        float acc = 0.f;
#pragma unroll
        for (int i = 0; i < 64; ++i) {
            int mb = o * 193 + i * 3;
            acc += mu_s[mb]     * xs[r * 64 + i]
                 + mu_s[mb + 1] * xs[(r - 1) * 64 + i]
                 + mu_s[mb + 2] * xs[(r - 2) * 64 + i];
        }
        deltas[((size_t)b * LL + l0 + ll) * DD + o] += acc;
    }
}

// First squaring with companion matrix built on the fly from m_y.
__global__ __launch_bounds__(256) void k_matsq1(const float* __restrict__ m_y,
                                                float* __restrict__ C) {
    int idx = blockIdx.x * 256 + threadIdx.x;
    int r = idx >> 7, c = idx & 127;
    if (r >= 64) { C[idx] = m_y[(r - 64) * 128 + c]; return; }
    float acc = (c < 64) ? m_y[r * 128 + 64 + c] : 0.f;
#pragma unroll
    for (int i = 0; i < 64; ++i) acc += m_y[r * 128 + i] * m_y[i * 128 + c];
    C[idx] = acc;
}

__global__ __launch_bounds__(256) void k_matsq(const float* __restrict__ A,
                                               float* __restrict__ C) {
    int idx = blockIdx.x * 256 + threadIdx.x;
    int r = idx >> 7, c = idx & 127;
    float acc = 0.f;
#pragma unroll
    for (int i = 0; i < 128; ++i) acc += A[r * 128 + i] * A[i * 128 + c];
    C[idx] = acc;
}

// ---- hierarchical boundary-scan helpers (row-half in 64 regs, no spill) ----
__device__ __forceinline__ void load_rowhalf(const float* __restrict__ P, int r, int h,
                                             float* __restrict__ p) {
#pragma unroll
    for (int i4 = 0; i4 < 16; ++i4) {
        float4 v = *(const float4*)&P[r * 128 + h * 64 + i4 * 4];
        p[4 * i4] = v.x; p[4 * i4 + 1] = v.y; p[4 * i4 + 2] = v.z; p[4 * i4 + 3] = v.w;
    }
}
__device__ __forceinline__ float dot64(const float* __restrict__ p, const float* s) {
    float a0 = 0.f, a1 = 0.f, a2 = 0.f, a3 = 0.f;
#pragma unroll
    for (int i4 = 0; i4 < 16; ++i4) {
        float4 w = *(const float4*)&s[i4 * 4];
        a0 += p[4 * i4] * w.x;  a1 += p[4 * i4 + 1] * w.y;
        a2 += p[4 * i4 + 2] * w.z;  a3 += p[4 * i4 + 3] * w.w;
    }
    return (a0 + a1) + (a2 + a3);
}

// Level 2: per (b,g): zero-init partial scan over the 8 chunks of group g.
// q[b][8g+k] = partial state before chunk k (group-local); Qg[b][g] = terminal.
__global__ __launch_bounds__(256, 1) void k_grp_scan(const float* __restrict__ P,
                                                     const float* __restrict__ term,
                                                     float* __restrict__ q,
                                                     float* __restrict__ Qg) {
    const int b = blockIdx.x >> 3, g = blockIdx.x & 7;
    const int tid = threadIdx.x;
    const int r = tid & 127, h = tid >> 7;
    __shared__ __align__(16) float scur[128];
    __shared__ float pacc[256];
    float p[64];
    load_rowhalf(P, r, h, p);
    if (tid < 128) scur[tid] = 0.f;
    __syncthreads();
    for (int k = 0; k < 8; ++k) {
        const size_t j = (size_t)(b * 64 + g * 8 + k) * 128;
        if (tid < 128) q[j + tid] = scur[tid];
        pacc[tid] = dot64(p, &scur[h * 64]);
        __syncthreads();
        if (tid < 128) scur[tid] = pacc[tid] + pacc[tid + 128] + term[j + tid];
        __syncthreads();
    }
    if (tid < 128) Qg[(b * 8 + g) * 128 + tid] = scur[tid];
}

// Level 3: per batch: scan over 8 group boundaries with P8 = M^512.
__global__ __launch_bounds__(256, 1) void k_bnd8(const float* __restrict__ P8,
                                                 const float* __restrict__ Qg,
                                                 float* __restrict__ Sg) {
    const int b = blockIdx.x;
    const int tid = threadIdx.x;
    const int r = tid & 127, h = tid >> 7;
    __shared__ __align__(16) float scur[128];
    __shared__ float pacc[256];
    float p[64];
    load_rowhalf(P8, r, h, p);
    if (tid < 128) scur[tid] = 0.f;
    __syncthreads();
    for (int g = 0; g < 8; ++g) {
        if (tid < 128) Sg[(b * 8 + g) * 128 + tid] = scur[tid];
        pacc[tid] = dot64(p, &scur[h * 64]);
        __syncthreads();
        if (tid < 128) scur[tid] = pacc[tid] + pacc[tid + 128] + Qg[(b * 8 + g) * 128 + tid];
        __syncthreads();
    }
}

// Level 4: per (b,g): s[8g+k] = P^k * Sg + q[8g+k], 8 serial P-multiplies.
__global__ __launch_bounds__(256, 1) void k_fixup(const float* __restrict__ P,
                                                  const float* __restrict__ Sg,
                                                  const float* __restrict__ q,
                                                  float* __restrict__ sst) {
    const int b = blockIdx.x >> 3, g = blockIdx.x & 7;
    const int tid = threadIdx.x;
    const int r = tid & 127, h = tid >> 7;
    __shared__ __align__(16) float scur[128];
    __shared__ float pacc[256];
    float p[64];
    load_rowhalf(P, r, h, p);
    if (tid < 128) scur[tid] = Sg[(b * 8 + g) * 128 + tid];
    __syncthreads();
    for (int k = 0; k < 8; ++k) {
        const size_t j = (size_t)(b * 64 + g * 8 + k) * 128;
        if (tid < 128) sst[j + tid] = scur[tid] + q[j + tid];
        if (k == 7) break;
        pacc[tid] = dot64(p, &scur[h * 64]);
        __syncthreads();
        if (tid < 128) scur[tid] = pacc[tid] + pacc[tid + 128];
        __syncthreads();
    }
}

__global__ __launch_bounds__(64, 1) void k_chunk_local(const float* __restrict__ deltas,
                                                       const float* __restrict__ m_y,
                                                       float* __restrict__ term) {
    const int b = blockIdx.x >> 6, j = blockIdx.x & 63;
    const int o = threadIdx.x;
    __shared__ __align__(16) float y1s[64];
    __shared__ __align__(16) float y2s[64];
    float a1r[64], a2r[64];
#pragma unroll
    for (int i4 = 0; i4 < 16; ++i4) {
        float4 v1 = *(const float4*)&m_y[o * 128 + i4 * 4];
        float4 v2 = *(const float4*)&m_y[o * 128 + 64 + i4 * 4];
        a1r[4 * i4] = v1.x; a1r[4 * i4 + 1] = v1.y; a1r[4 * i4 + 2] = v1.z; a1r[4 * i4 + 3] = v1.w;
        a2r[4 * i4] = v2.x; a2r[4 * i4 + 1] = v2.y; a2r[4 * i4 + 2] = v2.z; a2r[4 * i4 + 3] = v2.w;
    }
    y1s[o] = 0.f; y2s[o] = 0.f;
    __syncthreads();
    const float* dl = &deltas[(((size_t)b * LL) + j * 64) * DD + o];
    for (int t = 0; t < 64; ++t) {
        float acc = dl[t * DD];
#pragma unroll
        for (int i4 = 0; i4 < 16; ++i4) {
            float4 w1 = *(const float4*)&y1s[i4 * 4];
            float4 w2 = *(const float4*)&y2s[i4 * 4];
            acc += a1r[4 * i4] * w1.x + a1r[4 * i4 + 1] * w1.y + a1r[4 * i4 + 2] * w1.z + a1r[4 * i4 + 3] * w1.w
                 + a2r[4 * i4] * w2.x + a2r[4 * i4 + 1] * w2.y + a2r[4 * i4 + 2] * w2.z + a2r[4 * i4 + 3] * w2.w;
        }
        __syncthreads();
        y2s[o] = y1s[o];
        y1s[o] = acc;
        __syncthreads();
    }
    term[((size_t)b * 64 + j) * 128 + o] = y1s[o];
    term[((size_t)b * 64 + j) * 128 + 64 + o] = y2s[o];
}

__global__ __launch_bounds__(64, 1) void k_chunk_final(const float* __restrict__ deltas,
                                                       const float* __restrict__ m_y,
                                                       const float* __restrict__ sstate,
                                                       float* __restrict__ out) {
    const int b = blockIdx.x >> 6, j = blockIdx.x & 63;
    const int o = threadIdx.x;
    __shared__ __align__(16) float y1s[64];
    __shared__ __align__(16) float y2s[64];
    float a1r[64], a2r[64];
#pragma unroll
    for (int i4 = 0; i4 < 16; ++i4) {
        float4 v1 = *(const float4*)&m_y[o * 128 + i4 * 4];
        float4 v2 = *(const float4*)&m_y[o * 128 + 64 + i4 * 4];
        a1r[4 * i4] = v1.x; a1r[4 * i4 + 1] = v1.y; a1r[4 * i4 + 2] = v1.z; a1r[4 * i4 + 3] = v1.w;
        a2r[4 * i4] = v2.x; a2r[4 * i4 + 1] = v2.y; a2r[4 * i4 + 2] = v2.z; a2r[4 * i4 + 3] = v2.w;
    }
    y1s[o] = sstate[((size_t)b * 64 + j) * 128 + o];
    y2s[o] = sstate[((size_t)b * 64 + j) * 128 + 64 + o];
    __syncthreads();
    const size_t base = (((size_t)b * LL) + j * 64) * DD + o;
    for (int t = 0; t < 64; ++t) {
        float acc = deltas[base + (size_t)t * DD];
#pragma unroll
        for (int i4 = 0; i4 < 16; ++i4) {
            float4 w1 = *(const float4*)&y1s[i4 * 4];
            float4 w2 = *(const float4*)&y2s[i4 * 4];
            acc += a1r[4 * i4] * w1.x + a1r[4 * i4 + 1] * w1.y + a1r[4 * i4 + 2] * w1.z + a1r[4 * i4 + 3] * w1.w
                 + a2r[4 * i4] * w2.x + a2r[4 * i4 + 1] * w2.y + a2r[4 * i4 + 2] * w2.z + a2r[4 * i4 + 3] * w2.w;
        }
        out[base + (size_t)t * DD] = acc;
        __syncthreads();
        y2s[o] = y1s[o];
        y1s[o] = acc;
        __syncthreads();
    }
}

extern "C" void kernel_launch(void* const* d_in, const int* in_sizes, int n_in,
                              void* d_out, int out_size, void* d_ws, size_t ws_size,
                              hipStream_t stream) {
    const float* x        = (const float*)d_in[0];
    const float* m_y      = (const float*)d_in[1];
    const float* m_u      = (const float*)d_in[2];
    const float* m_phi    = (const float*)d_in[3];
    const float* eig_vals = (const float*)d_in[4];
    const float* eig_vecs = (const float*)d_in[5];
    float* out = (float*)d_out;

    char* ws = (char*)d_ws;
    size_t off = 0;
    auto alloc = [&](size_t bytes) -> void* {
        void* p = ws + off;
        off += (bytes + 255) & ~(size_t)255;
        return p;
    };
    float2* Vb   = (float2*)alloc((size_t)NN * KK * sizeof(float2));          // 1.5 MB
    uint*   Ub   = (uint*)alloc((size_t)BB * NN * DD * sizeof(uint));         // 16.8 MB
    uint*   Sb   = (uint*)alloc((size_t)BB * NN * DD * sizeof(uint));         // 16.8 MB
    float*  deltas = (float*)alloc((size_t)BB * LL * DD * sizeof(float));     // 8.4 MB
    uint2*  mp   = (uint2*)alloc((size_t)24576 * sizeof(uint2));              // 0.2 MB
    float*  mats = (float*)alloc((size_t)3 * 128 * 128 * sizeof(float));
    float*  term = (float*)alloc((size_t)BB * 64 * 128 * sizeof(float));
    float*  sst  = (float*)alloc((size_t)BB * 64 * 128 * sizeof(float));
    float*  qbuf = (float*)alloc((size_t)BB * 64 * 128 * sizeof(float));
    float*  Qg   = (float*)alloc((size_t)BB * 8 * 128 * sizeof(float));
    float*  Sgb  = (float*)alloc((size_t)BB * 8 * 128 * sizeof(float));

    k_pack<<<dim3(96), dim3(256), 0, stream>>>(m_phi, mp);
    k_fft_filters<<<dim3(24), dim3(256), 0, stream>>>(eig_vals, eig_vecs, Vb);
    k_fft_x2<<<dim3(256), dim3(512), 0, stream>>>(x, Ub);

    float* Am = mats;
    float* Bm = mats + 16384;
    float* Cm = mats + 32768;
    k_matsq1<<<dim3(64), dim3(256), 0, stream>>>(m_y, Bm);  // M^2
    k_matsq<<<dim3(64), dim3(256), 0, stream>>>(Bm, Cm);    // M^4
    k_matsq<<<dim3(64), dim3(256), 0, stream>>>(Cm, Bm);    // M^8
    k_matsq<<<dim3(64), dim3(256), 0, stream>>>(Bm, Cm);    // M^16
    k_matsq<<<dim3(64), dim3(256), 0, stream>>>(Cm, Bm);    // M^32
    k_matsq<<<dim3(64), dim3(256), 0, stream>>>(Bm, Cm);    // M^64  -> Cm (P)
    k_matsq<<<dim3(64), dim3(256), 0, stream>>>(Cm, Am);    // M^128
    k_matsq<<<dim3(64), dim3(256), 0, stream>>>(Am, Bm);    // M^256
    k_matsq<<<dim3(64), dim3(256), 0, stream>>>(Bm, Am);    // M^512 -> Am (P8)

    k_modulate4<<<dim3(257), dim3(512), 0, stream>>>(Vb, Ub, mp, Sb, 0);
    k_modulate4<<<dim3(257), dim3(512), 0, stream>>>(Vb, Ub, mp, Sb, 1);
    k_ifft2<<<dim3(256), dim3(512), 0, stream>>>(Sb, deltas);
    k_aru<<<dim3(1024), dim3(256), 0, stream>>>(x, m_u, deltas);

    k_chunk_local<<<dim3(512), dim3(64), 0, stream>>>(deltas, m_y, term);
    k_grp_scan<<<dim3(64), dim3(256), 0, stream>>>(Cm, term, qbuf, Qg);
    k_bnd8<<<dim3(8), dim3(256), 0, stream>>>(Am, Qg, Sgb);
    k_fixup<<<dim3(64), dim3(256), 0, stream>>>(Cm, Sgb, qbuf, sst);
    k_chunk_final<<<dim3(512), dim3(64), 0, stream>>>(deltas, m_y, sst, out);
}

// Round 7
// 388.900 us; speedup vs baseline: 8.6323x; 1.0675x over previous
//
#include <hip/hip_runtime.h>
#include <math.h>

#define BB 8
#define LL 4096
#define DD 64
#define KK 24
#define NN 8192
#define LOGN 13

typedef unsigned int uint;

__device__ __forceinline__ float bfl(uint u) {            // low bf16 -> float
    union { uint u; float f; } v; v.u = u << 16; return v.f;
}
__device__ __forceinline__ float bfh(uint u) {            // high bf16 -> float
    union { uint u; float f; } v; v.u = u & 0xFFFF0000u; return v.f;
}
__device__ __forceinline__ uint pk(float x) {             // float -> bf16 (rne), low bits
    union { float f; uint u; } v; v.f = x;
    return (v.u + 0x7FFFu + ((v.u >> 16) & 1u)) >> 16;
}
__device__ __forceinline__ float2 unpk2(uint u) {
    return make_float2(bfl(u), bfh(u));
}
__device__ __forceinline__ int br13(int v) { return (int)(__brev((uint)v) >> 19); }

// ---------------- FFT primitives (in-LDS, NT threads, N=8192) ----------------
template<int NT>
__device__ __forceinline__ void fft_dif(float2* a) {
    const int tid = threadIdx.x;
    for (int lh = LOGN - 1; lh >= 0; --lh) {
        const int half = 1 << lh;
        const float tw = -6.28318530717958647692f / (float)(2 << lh);
#pragma unroll
        for (int bb = 0; bb < NN / 2 / NT; ++bb) {
            int t = tid + bb * NT;
            int j = t & (half - 1);
            int i0 = ((t >> lh) << (lh + 1)) + j;
            float2 u = a[i0], v = a[i0 + half];
            float sn, cs;
            __sincosf(tw * (float)j, &sn, &cs);
            float dx = u.x - v.x, dy = u.y - v.y;
            a[i0] = make_float2(u.x + v.x, u.y + v.y);
            a[i0 + half] = make_float2(dx * cs - dy * sn, dx * sn + dy * cs);
        }
        __syncthreads();
    }
}

template<int NT>
__device__ __forceinline__ void fft_dit(float2* a) {
    const int tid = threadIdx.x;
    for (int lh = 0; lh < LOGN; ++lh) {
        const int half = 1 << lh;
        const float tw = 6.28318530717958647692f / (float)(2 << lh);
#pragma unroll
        for (int bb = 0; bb < NN / 2 / NT; ++bb) {
            int t = tid + bb * NT;
            int j = t & (half - 1);
            int i0 = ((t >> lh) << (lh + 1)) + j;
            float2 u = a[i0], v = a[i0 + half];
            float sn, cs;
            __sincosf(tw * (float)j, &sn, &cs);
            float wx = v.x * cs - v.y * sn;
            float wy = v.x * sn + v.y * cs;
            a[i0] = make_float2(u.x + wx, u.y + wy);
            a[i0 + half] = make_float2(u.x - wx, u.y - wy);
        }
        __syncthreads();
    }
}

// ---------------- kernels ----------------

// Pack m_phi into per-pass, k3-major bf16x4 table (3 planes of 4096 uint2 per pass).
__global__ __launch_bounds__(256) void k_pack(const float* __restrict__ mphi,
                                              uint2* __restrict__ mp) {
    int idx = blockIdx.x * 256 + threadIdx.x;
    if (idx >= 24576) return;
    int p = idx / 12288;
    int rem = idx - p * 12288;
    int k3 = rem >> 12;
    int e = rem & 4095;
    int c = e >> 6, o = e & 63;
    int kb = p * 12 + k3 * 4;
    uint x = pk(mphi[((kb + 0) * 64 + c) * 64 + o]) | (pk(mphi[((kb + 1) * 64 + c) * 64 + o]) << 16);
    uint y = pk(mphi[((kb + 2) * 64 + c) * 64 + o]) | (pk(mphi[((kb + 3) * 64 + c) * 64 + o]) << 16);
    mp[idx] = make_uint2(x, y);
}

// V[f,k] = FFT(eig_vecs[:,k] * lambda_k^0.25 / N), bit-reversed bins, fp32
__global__ __launch_bounds__(256) void k_fft_filters(const float* __restrict__ eig_vals,
                                                     const float* __restrict__ eig_vecs,
                                                     float2* __restrict__ Vb) {
    __shared__ float2 a[NN];
    const int k = blockIdx.x, tid = threadIdx.x;
    const float alpha = powf(eig_vals[k], 0.25f) * (1.0f / (float)NN);
    for (int t = tid; t < LL; t += 256)
        a[t] = make_float2(eig_vecs[t * KK + k] * alpha, 0.f);
    for (int t = LL + tid; t < NN; t += 256)
        a[t] = make_float2(0.f, 0.f);
    __syncthreads();
    fft_dif<256>(a);
    for (int r = tid; r < NN; r += 256)
        Vb[(size_t)r * KK + k] = a[r];
}

// Two real channels per complex FFT: z = x[:,c] + i x[:,c+1].
// Writes U only at Hermitian-half positions (even r, plus r=1 <-> f=4096).
__global__ __launch_bounds__(512) void k_fft_x2(const float* __restrict__ x,
                                                uint* __restrict__ Ub) {
    __shared__ float2 a[NN];
    const int b = blockIdx.x >> 5, cp = blockIdx.x & 31;
    const int tid = threadIdx.x;
    for (int l = tid; l < LL; l += 512)
        a[l] = *(const float2*)&x[((size_t)b * LL + l) * DD + 2 * cp];
    for (int l = LL + tid; l < NN; l += 512)
        a[l] = make_float2(0.f, 0.f);
    __syncthreads();
    fft_dif<512>(a);
    for (int idx = tid; idx < 4097; idx += 512) {
        int r = (idx == 4096) ? 1 : 2 * idx;
        int fn = br13(r);
        int q = br13((8192 - fn) & 8191);
        float2 Z = a[r], W = a[q];
        float ucx = 0.5f * (Z.x + W.x), ucy = 0.5f * (Z.y - W.y);
        float upx = 0.5f * (Z.y + W.y), upy = 0.5f * (W.x - Z.x);
        *(uint2*)&Ub[((size_t)b * NN + r) * DD + 2 * cp] =
            make_uint2(pk(ucx) | (pk(ucy) << 16), pk(upx) | (pk(upy) << 16));
    }
}

// float2 helpers (pairs over the two blocked positions -> candidate v_pk_fma_f32)
__device__ __forceinline__ void gacc(float2& gx, float2& gy,
                                     const float2* vx, const float2* vy,
                                     int kb, uint mw) {
    float m0 = bfl(mw), m1 = bfh(mw);
    gx.x += vx[kb].x * m0 + vx[kb + 1].x * m1;
    gx.y += vx[kb].y * m0 + vx[kb + 1].y * m1;
    gy.x += vy[kb].x * m0 + vy[kb + 1].x * m1;
    gy.y += vy[kb].y * m0 + vy[kb + 1].y * m1;
}
__device__ __forceinline__ void cmac2(float2& ax, float2& ay,
                                      float2 ux, float2 uy, float2 gx, float2 gy) {
    ax.x += ux.x * gx.x - uy.x * gy.x;  ax.y += ux.y * gx.y - uy.y * gy.y;
    ay.x += ux.x * gy.x + uy.x * gx.x;  ay.y += ux.y * gy.y + uy.y * gx.y;
}

// Per-pass modulate over Hermitian half only: 16 even positions per block
// (blocks 0..255), block 256 handles r=1 (f=4096). 2-position register blocking.
#define FE 16
__global__ __launch_bounds__(512) void k_modulate4(const float2* __restrict__ Vb,
                                                   const uint* __restrict__ Ub,
                                                   const uint2* __restrict__ mp,
                                                   uint* __restrict__ Sb,
                                                   const int p) {
    __shared__ __align__(16) uint2 mp_s[3 * 4096];     // 96 KB
    __shared__ __align__(16) uint2 Gs2[4096];          // 32 KB: {f0 bf16 cplx, f1 bf16 cplx}
    __shared__ __align__(16) uint2 Us2[512];           // 4 KB:  {f0, f1}
    __shared__ float2 Vt[FE * 12];                     // 1.5 KB
    const int tid = threadIdx.x;
    const int bx = blockIdx.x;
    const bool tail = (bx == 256);
    const int npairs = tail ? 1 : 8;

    {   // stage mphi half: 12288 uint2 = 6144 uint4
        const uint4* src = (const uint4*)(mp + (size_t)p * 12288);
        uint4* dst = (uint4*)mp_s;
        for (int i = tid; i < 6144; i += 512) dst[i] = src[i];
    }
    for (int i = tid; i < FE * 12; i += 512) {
        int fi = i / 12, j = i - fi * 12;
        int pos = tail ? 1 : bx * 32 + 2 * fi;
        Vt[i] = Vb[(size_t)pos * KK + p * 12 + j];
    }
    __syncthreads();

    const int o2 = tid & 31;          // o-pair
    const int ch = (tid >> 5) & 1;    // c-half
    const int b  = tid >> 6;          // wave index == batch
    const size_t ub0 = (size_t)b * NN * DD + (tid & 63);
    const uint2* SbV = (const uint2*)Sb;
    const size_t sp0 = (size_t)b * NN * 32 + o2;

    auto posf = [&](int pi, int h) { return tail ? 1 : bx * 32 + 4 * pi + 2 * h; };

    uint u0 = Ub[ub0 + (size_t)posf(0, 0) * DD];
    uint u1 = Ub[ub0 + (size_t)posf(0, 1) * DD];
    uint2 sc0 = make_uint2(0, 0), sc1 = make_uint2(0, 0);
    if (p && ch == 0) {
        sc0 = SbV[sp0 + (size_t)posf(0, 0) * 32];
        sc1 = SbV[sp0 + (size_t)posf(0, 1) * 32];
    }

    for (int pi = 0; pi < npairs; ++pi) {
        const int p0 = posf(pi, 0), p1 = posf(pi, 1);
        Us2[tid] = make_uint2(u0, u1);
        // prefetch next position-pair (hides under G-build + S-apply)
        uint nu0 = 0, nu1 = 0; uint2 ns0 = make_uint2(0, 0), ns1 = make_uint2(0, 0);
        if (pi + 1 < npairs) {
            nu0 = Ub[ub0 + (size_t)posf(pi + 1, 0) * DD];
            nu1 = Ub[ub0 + (size_t)posf(pi + 1, 1) * DD];
            if (p && ch == 0) {
                ns0 = SbV[sp0 + (size_t)posf(pi + 1, 0) * 32];
                ns1 = SbV[sp0 + (size_t)posf(pi + 1, 1) * 32];
            }
        }
        // V registers as position-pair vectors
        float2 vx[12], vy[12];
#pragma unroll
        for (int j = 0; j < 12; ++j) {
            float2 a = Vt[(2 * pi) * 12 + j], b2 = Vt[(2 * pi + 1) * 12 + j];
            vx[j] = make_float2(a.x, b2.x);
            vy[j] = make_float2(a.y, b2.y);
        }
        // G build: elem pairs, b128 in / b128 out
#pragma unroll
        for (int i = 0; i < 4; ++i) {
            int e0 = 2 * (tid + i * 512);
            uint4 mA = *(const uint4*)&mp_s[e0];
            uint4 mB = *(const uint4*)&mp_s[4096 + e0];
            uint4 mC = *(const uint4*)&mp_s[8192 + e0];
            float2 gx0 = {0, 0}, gy0 = {0, 0}, gx1 = {0, 0}, gy1 = {0, 0};
            gacc(gx0, gy0, vx, vy, 0, mA.x);  gacc(gx0, gy0, vx, vy, 2, mA.y);
            gacc(gx0, gy0, vx, vy, 4, mB.x);  gacc(gx0, gy0, vx, vy, 6, mB.y);
            gacc(gx0, gy0, vx, vy, 8, mC.x);  gacc(gx0, gy0, vx, vy, 10, mC.y);
            gacc(gx1, gy1, vx, vy, 0, mA.z);  gacc(gx1, gy1, vx, vy, 2, mA.w);
            gacc(gx1, gy1, vx, vy, 4, mB.z);  gacc(gx1, gy1, vx, vy, 6, mB.w);
            gacc(gx1, gy1, vx, vy, 8, mC.z);  gacc(gx1, gy1, vx, vy, 10, mC.w);
            uint4 w;
            w.x = pk(gx0.x) | (pk(gy0.x) << 16);
            w.y = pk(gx0.y) | (pk(gy0.y) << 16);
            w.z = pk(gx1.x) | (pk(gy1.x) << 16);
            w.w = pk(gx1.y) | (pk(gy1.y) << 16);
            *(uint4*)&Gs2[e0] = w;
        }
        __syncthreads();
        // S apply: (b, o-pair, c-half), c unrolled by 2, all b128 reads
        {
            float2 A0x = {0, 0}, A0y = {0, 0}, A1x = {0, 0}, A1y = {0, 0};
            const int cbase = ch * 32;
#pragma unroll
            for (int cc = 0; cc < 16; ++cc) {
                int c = cbase + cc * 2;
                uint4 uu = *(const uint4*)&Us2[b * 64 + c];
                uint4 g0 = *(const uint4*)&Gs2[c * 64 + o2 * 2];
                uint4 g1 = *(const uint4*)&Gs2[(c + 1) * 64 + o2 * 2];
                float2 ux = make_float2(bfl(uu.x), bfl(uu.y));
                float2 uy = make_float2(bfh(uu.x), bfh(uu.y));
                float2 g0x0 = make_float2(bfl(g0.x), bfl(g0.y));
                float2 g0y0 = make_float2(bfh(g0.x), bfh(g0.y));
                float2 g0x1 = make_float2(bfl(g0.z), bfl(g0.w));
                float2 g0y1 = make_float2(bfh(g0.z), bfh(g0.w));
                cmac2(A0x, A0y, ux, uy, g0x0, g0y0);
                cmac2(A1x, A1y, ux, uy, g0x1, g0y1);
                float2 vx2 = make_float2(bfl(uu.z), bfl(uu.w));
                float2 vy2 = make_float2(bfh(uu.z), bfh(uu.w));
                float2 g1x0 = make_float2(bfl(g1.x), bfl(g1.y));
                float2 g1y0 = make_float2(bfh(g1.x), bfh(g1.y));
                float2 g1x1 = make_float2(bfl(g1.z), bfl(g1.w));
                float2 g1y1 = make_float2(bfh(g1.z), bfh(g1.w));
                cmac2(A0x, A0y, vx2, vy2, g1x0, g1y0);
                cmac2(A1x, A1y, vx2, vy2, g1x1, g1y1);
            }
            A0x.x += __shfl_xor(A0x.x, 32);  A0x.y += __shfl_xor(A0x.y, 32);
            A0y.x += __shfl_xor(A0y.x, 32);  A0y.y += __shfl_xor(A0y.y, 32);
            A1x.x += __shfl_xor(A1x.x, 32);  A1x.y += __shfl_xor(A1x.y, 32);
            A1y.x += __shfl_xor(A1y.x, 32);  A1y.y += __shfl_xor(A1y.y, 32);
            if (ch == 0) {
                float s0x = A0x.x, s0y = A0y.x, s1x = A1x.x, s1y = A1y.x;   // p0
                float t0x = A0x.y, t0y = A0y.y, t1x = A1x.y, t1y = A1y.y;   // p1
                if (p) {
                    s0x += bfl(sc0.x); s0y += bfh(sc0.x); s1x += bfl(sc0.y); s1y += bfh(sc0.y);
                    t0x += bfl(sc1.x); t0y += bfh(sc1.x); t1x += bfl(sc1.y); t1y += bfh(sc1.y);
                }
                *(uint2*)&Sb[((size_t)b * NN + p0) * DD + o2 * 2] =
                    make_uint2(pk(s0x) | (pk(s0y) << 16), pk(s1x) | (pk(s1y) << 16));
                *(uint2*)&Sb[((size_t)b * NN + p1) * DD + o2 * 2] =
                    make_uint2(pk(t0x) | (pk(t0y) << 16), pk(t1x) | (pk(t1y) << 16));
            }
        }
        __syncthreads();
        u0 = nu0; u1 = nu1; sc0 = ns0; sc1 = ns1;
    }
}

// Two output channels per inverse FFT. Stages Hermitian half, reconstructs odd
// positions in LDS: z[q] = conj(S_o[r]) + i conj(S_o'[r]).
__global__ __launch_bounds__(512) void k_ifft2(const uint* __restrict__ Sb,
                                               float* __restrict__ deltas) {
    __shared__ float2 a[NN];
    const int b = blockIdx.x >> 5, op = blockIdx.x & 31;
    const int tid = threadIdx.x;
    for (int idx = tid; idx < 4097; idx += 512) {
        int r = (idx == 4096) ? 1 : 2 * idx;
        uint2 w = *(const uint2*)&Sb[((size_t)b * NN + r) * DD + op * 2];
        float2 A = unpk2(w.x), B = unpk2(w.y);
        a[r] = make_float2(A.x - B.y, A.y + B.x);
        int fn = br13(r);
        int q = br13((8192 - fn) & 8191);
        if (q != r) a[q] = make_float2(A.x + B.y, B.x - A.y);
    }
    __syncthreads();
    fft_dit<512>(a);
    for (int l = tid; l < LL; l += 512)
        *(float2*)&deltas[((size_t)b * LL + l) * DD + op * 2] = make_float2(a[l].x, a[l].y);
}

// deltas += AR-U
__global__ __launch_bounds__(256) void k_aru(const float* __restrict__ x,
                                             const float* __restrict__ m_u,
                                             float* __restrict__ deltas) {
    __shared__ float mu_s[64 * 193];
    __shared__ float xs[34 * 64];
    const int tid = threadIdx.x;
    const int b = blockIdx.x >> 7;
    const int l0 = (blockIdx.x & 127) * 32;
    for (int idx = tid; idx < 64 * 192; idx += 256) {
        int o = idx / 192;
        int rem = idx - o * 192;
        mu_s[o * 193 + rem] = m_u[idx];
    }
    for (int idx = tid; idx < 34 * 64; idx += 256) {
        int rr = idx >> 6, i = idx & 63;
        int gl = l0 - 2 + rr;
        xs[idx] = (gl >= 0) ? x[((size_t)b * LL + gl) * DD + i] : 0.f;
    }
    __syncthreads();
    const int o = tid & 63, lsub = tid >> 6;
    for (int lb = 0; lb < 8; ++lb) {
        int ll = lsub * 8 + lb;
        int r = ll + 2;
        float acc = 0.f;
#pragma unroll
        for (int i = 0; i < 64; ++i) {
            int mb = o * 193 + i * 3;
            acc += mu_s[mb]     * xs[r * 64 + i]
                 + mu_s[mb + 1] * xs[(r - 1) * 64 + i]
                 + mu_s[mb + 2] * xs[(r - 2) * 64 + i];
        }
        deltas[((size_t)b * LL + l0 + ll) * DD + o] += acc;
    }
}

// First squaring with companion matrix built on the fly from m_y.
__global__ __launch_bounds__(256) void k_matsq1(const float* __restrict__ m_y,
                                                float* __restrict__ C) {
    int idx = blockIdx.x * 256 + threadIdx.x;
    int r = idx >> 7, c = idx & 127;
    if (r >= 64) { C[idx] = m_y[(r - 64) * 128 + c]; return; }
    float acc = (c < 64) ? m_y[r * 128 + 64 + c] : 0.f;
#pragma unroll
    for (int i = 0; i < 64; ++i) acc += m_y[r * 128 + i] * m_y[i * 128 + c];
    C[idx] = acc;
}

__global__ __launch_bounds__(256) void k_matsq(const float* __restrict__ A,
                                               float* __restrict__ C) {
    int idx = blockIdx.x * 256 + threadIdx.x;
    int r = idx >> 7, c = idx & 127;
    float acc = 0.f;
#pragma unroll
    for (int i = 0; i < 128; ++i) acc += A[r * 128 + i] * A[i * 128 + c];
    C[idx] = acc;
}

// ---- hierarchical boundary-scan helpers (row-half in 64 regs, no spill) ----
__device__ __forceinline__ void load_rowhalf(const float* __restrict__ P, int r, int h,
                                             float* __restrict__ p) {
#pragma unroll
    for (int i4 = 0; i4 < 16; ++i4) {
        float4 v = *(const float4*)&P[r * 128 + h * 64 + i4 * 4];
        p[4 * i4] = v.x; p[4 * i4 + 1] = v.y; p[4 * i4 + 2] = v.z; p[4 * i4 + 3] = v.w;
    }
}
__device__ __forceinline__ float dot64(const float* __restrict__ p, const float* s) {
    float a0 = 0.f, a1 = 0.f, a2 = 0.f, a3 = 0.f;
#pragma unroll
    for (int i4 = 0; i4 < 16; ++i4) {
        float4 w = *(const float4*)&s[i4 * 4];
        a0 += p[4 * i4] * w.x;  a1 += p[4 * i4 + 1] * w.y;
        a2 += p[4 * i4 + 2] * w.z;  a3 += p[4 * i4 + 3] * w.w;
    }
    return (a0 + a1) + (a2 + a3);
}

// Level 2: per (b,g): zero-init partial scan over the 8 chunks of group g.
__global__ __launch_bounds__(256, 1) void k_grp_scan(const float* __restrict__ P,
                                                     const float* __restrict__ term,
                                                     float* __restrict__ q,
                                                     float* __restrict__ Qg) {
    const int b = blockIdx.x >> 3, g = blockIdx.x & 7;
    const int tid = threadIdx.x;
    const int r = tid & 127, h = tid >> 7;
    __shared__ __align__(16) float scur[128];
    __shared__ float pacc[256];
    float p[64];
    load_rowhalf(P, r, h, p);
    if (tid < 128) scur[tid] = 0.f;
    __syncthreads();
    for (int k = 0; k < 8; ++k) {
        const size_t j = (size_t)(b * 64 + g * 8 + k) * 128;
        if (tid < 128) q[j + tid] = scur[tid];
        pacc[tid] = dot64(p, &scur[h * 64]);
        __syncthreads();
        if (tid < 128) scur[tid] = pacc[tid] + pacc[tid + 128] + term[j + tid];
        __syncthreads();
    }
    if (tid < 128) Qg[(b * 8 + g) * 128 + tid] = scur[tid];
}

// Level 3: per batch: scan over 8 group boundaries with P8 = M^512.
__global__ __launch_bounds__(256, 1) void k_bnd8(const float* __restrict__ P8,
                                                 const float* __restrict__ Qg,
                                                 float* __restrict__ Sg) {
    const int b = blockIdx.x;
    const int tid = threadIdx.x;
    const int r = tid & 127, h = tid >> 7;
    __shared__ __align__(16) float scur[128];
    __shared__ float pacc[256];
    float p[64];
    load_rowhalf(P8, r, h, p);
    if (tid < 128) scur[tid] = 0.f;
    __syncthreads();
    for (int g = 0; g < 8; ++g) {
        if (tid < 128) Sg[(b * 8 + g) * 128 + tid] = scur[tid];
        pacc[tid] = dot64(p, &scur[h * 64]);
        __syncthreads();
        if (tid < 128) scur[tid] = pacc[tid] + pacc[tid + 128] + Qg[(b * 8 + g) * 128 + tid];
        __syncthreads();
    }
}

// Level 4: per (b,g): s[8g+k] = P^k * Sg + q[8g+k], 8 serial P-multiplies.
__global__ __launch_bounds__(256, 1) void k_fixup(const float* __restrict__ P,
                                                  const float* __restrict__ Sg,
                                                  const float* __restrict__ q,
                                                  float* __restrict__ sst) {
    const int b = blockIdx.x >> 3, g = blockIdx.x & 7;
    const int tid = threadIdx.x;
    const int r = tid & 127, h = tid >> 7;
    __shared__ __align__(16) float scur[128];
    __shared__ float pacc[256];
    float p[64];
    load_rowhalf(P, r, h, p);
    if (tid < 128) scur[tid] = Sg[(b * 8 + g) * 128 + tid];
    __syncthreads();
    for (int k = 0; k < 8; ++k) {
        const size_t j = (size_t)(b * 64 + g * 8 + k) * 128;
        if (tid < 128) sst[j + tid] = scur[tid] + q[j + tid];
        if (k == 7) break;
        pacc[tid] = dot64(p, &scur[h * 64]);
        __syncthreads();
        if (tid < 128) scur[tid] = pacc[tid] + pacc[tid + 128];
        __syncthreads();
    }
}

// Per-chunk local recurrence, 2-wave split: thread (o,h) holds quarter-rows
// A1[o][32h..32h+32), A2[o][32h..32h+32) in 64 VGPRs (no spill). State in LDS.
__global__ __launch_bounds__(128, 1) void k_chunk_local(const float* __restrict__ deltas,
                                                        const float* __restrict__ m_y,
                                                        float* __restrict__ term) {
    const int b = blockIdx.x >> 6, j = blockIdx.x & 63;
    const int tid = threadIdx.x;
    const int o = tid & 63, h = tid >> 6;
    __shared__ __align__(16) float y1s[64];
    __shared__ __align__(16) float y2s[64];
    __shared__ float pacc[128];
    float m1[32], m2[32];
#pragma unroll
    for (int i4 = 0; i4 < 8; ++i4) {
        float4 v1 = *(const float4*)&m_y[o * 128 + h * 32 + i4 * 4];
        float4 v2 = *(const float4*)&m_y[o * 128 + 64 + h * 32 + i4 * 4];
        m1[4 * i4] = v1.x; m1[4 * i4 + 1] = v1.y; m1[4 * i4 + 2] = v1.z; m1[4 * i4 + 3] = v1.w;
        m2[4 * i4] = v2.x; m2[4 * i4 + 1] = v2.y; m2[4 * i4 + 2] = v2.z; m2[4 * i4 + 3] = v2.w;
    }
    if (tid < 64) { y1s[tid] = 0.f; y2s[tid] = 0.f; }
    __syncthreads();
    const float* dl = &deltas[(((size_t)b * LL) + j * 64) * DD + o];
    for (int t = 0; t < 64; ++t) {
        float a0 = 0.f, a1 = 0.f, a2 = 0.f, a3 = 0.f;
#pragma unroll
        for (int i4 = 0; i4 < 8; ++i4) {
            float4 w1 = *(const float4*)&y1s[h * 32 + i4 * 4];
            float4 w2 = *(const float4*)&y2s[h * 32 + i4 * 4];
            a0 += m1[4 * i4] * w1.x + m2[4 * i4] * w2.x;
            a1 += m1[4 * i4 + 1] * w1.y + m2[4 * i4 + 1] * w2.y;
            a2 += m1[4 * i4 + 2] * w1.z + m2[4 * i4 + 2] * w2.z;
            a3 += m1[4 * i4 + 3] * w1.w + m2[4 * i4 + 3] * w2.w;
        }
        pacc[tid] = (a0 + a1) + (a2 + a3);
        __syncthreads();
        if (h == 0) {
            float outv = pacc[o] + pacc[o + 64] + dl[t * DD];
            y2s[o] = y1s[o];
            y1s[o] = outv;
        }
        __syncthreads();
    }
    if (tid < 64) {
        term[((size_t)b * 64 + j) * 128 + o] = y1s[o];
        term[((size_t)b * 64 + j) * 128 + 64 + o] = y2s[o];
    }
}

// Per-chunk final recurrence with true initial states; writes outputs.
__global__ __launch_bounds__(128, 1) void k_chunk_final(const float* __restrict__ deltas,
                                                        const float* __restrict__ m_y,
                                                        const float* __restrict__ sstate,
                                                        float* __restrict__ out) {
    const int b = blockIdx.x >> 6, j = blockIdx.x & 63;
    const int tid = threadIdx.x;
    const int o = tid & 63, h = tid >> 6;
    __shared__ __align__(16) float y1s[64];
    __shared__ __align__(16) float y2s[64];
    __shared__ float pacc[128];
    float m1[32], m2[32];
#pragma unroll
    for (int i4 = 0; i4 < 8; ++i4) {
        float4 v1 = *(const float4*)&m_y[o * 128 + h * 32 + i4 * 4];
        float4 v2 = *(const float4*)&m_y[o * 128 + 64 + h * 32 + i4 * 4];
        m1[4 * i4] = v1.x; m1[4 * i4 + 1] = v1.y; m1[4 * i4 + 2] = v1.z; m1[4 * i4 + 3] = v1.w;
        m2[4 * i4] = v2.x; m2[4 * i4 + 1] = v2.y; m2[4 * i4 + 2] = v2.z; m2[4 * i4 + 3] = v2.w;
    }
    if (tid < 64) {
        y1s[tid] = sstate[((size_t)b * 64 + j) * 128 + tid];
        y2s[tid] = sstate[((size_t)b * 64 + j) * 128 + 64 + tid];
    }
    __syncthreads();
    const size_t base = (((size_t)b * LL) + j * 64) * DD + o;
    for (int t = 0; t < 64; ++t) {
        float a0 = 0.f, a1 = 0.f, a2 = 0.f, a3 = 0.f;
#pragma unroll
        for (int i4 = 0; i4 < 8; ++i4) {
            float4 w1 = *(const float4*)&y1s[h * 32 + i4 * 4];
            float4 w2 = *(const float4*)&y2s[h * 32 + i4 * 4];
            a0 += m1[4 * i4] * w1.x + m2[4 * i4] * w2.x;
            a1 += m1[4 * i4 + 1] * w1.y + m2[4 * i4 + 1] * w2.y;
            a2 += m1[4 * i4 + 2] * w1.z + m2[4 * i4 + 2] * w2.z;
            a3 += m1[4 * i4 + 3] * w1.w + m2[4 * i4 + 3] * w2.w;
        }
        pacc[tid] = (a0 + a1) + (a2 + a3);
        __syncthreads();
        if (h == 0) {
            float outv = pacc[o] + pacc[o + 64] + deltas[base + (size_t)t * DD];
            out[base + (size_t)t * DD] = outv;
            y2s[o] = y1s[o];
            y1s[o] = outv;
        }
        __syncthreads();
    }
}

extern "C" void kernel_launch(void* const* d_in, const int* in_sizes, int n_in,
                              void* d_out, int out_size, void* d_ws, size_t ws_size,
                              hipStream_t stream) {
    const float* x        = (const float*)d_in[0];
    const float* m_y      = (const float*)d_in[1];
    const float* m_u      = (const float*)d_in[2];
    const float* m_phi    = (const float*)d_in[3];
    const float* eig_vals = (const float*)d_in[4];
    const float* eig_vecs = (const float*)d_in[5];
    float* out = (float*)d_out;

    char* ws = (char*)d_ws;
    size_t off = 0;
    auto alloc = [&](size_t bytes) -> void* {
        void* p = ws + off;
        off += (bytes + 255) & ~(size_t)255;
        return p;
    };
    float2* Vb   = (float2*)alloc((size_t)NN * KK * sizeof(float2));          // 1.5 MB
    uint*   Ub   = (uint*)alloc((size_t)BB * NN * DD * sizeof(uint));         // 16.8 MB
    uint*   Sb   = (uint*)alloc((size_t)BB * NN * DD * sizeof(uint));         // 16.8 MB
    float*  deltas = (float*)alloc((size_t)BB * LL * DD * sizeof(float));     // 8.4 MB
    uint2*  mp   = (uint2*)alloc((size_t)24576 * sizeof(uint2));              // 0.2 MB
    float*  mats = (float*)alloc((size_t)3 * 128 * 128 * sizeof(float));
    float*  term = (float*)alloc((size_t)BB * 64 * 128 * sizeof(float));
    float*  sst  = (float*)alloc((size_t)BB * 64 * 128 * sizeof(float));
    float*  qbuf = (float*)alloc((size_t)BB * 64 * 128 * sizeof(float));
    float*  Qg   = (float*)alloc((size_t)BB * 8 * 128 * sizeof(float));
    float*  Sgb  = (float*)alloc((size_t)BB * 8 * 128 * sizeof(float));

    k_pack<<<dim3(96), dim3(256), 0, stream>>>(m_phi, mp);
    k_fft_filters<<<dim3(24), dim3(256), 0, stream>>>(eig_vals, eig_vecs, Vb);
    k_fft_x2<<<dim3(256), dim3(512), 0, stream>>>(x, Ub);

    float* Am = mats;
    float* Bm = mats + 16384;
    float* Cm = mats + 32768;
    k_matsq1<<<dim3(64), dim3(256), 0, stream>>>(m_y, Bm);  // M^2
    k_matsq<<<dim3(64), dim3(256), 0, stream>>>(Bm, Cm);    // M^4
    k_matsq<<<dim3(64), dim3(256), 0, stream>>>(Cm, Bm);    // M^8
    k_matsq<<<dim3(64), dim3(256), 0, stream>>>(Bm, Cm);    // M^16
    k_matsq<<<dim3(64), dim3(256), 0, stream>>>(Cm, Bm);    // M^32
    k_matsq<<<dim3(64), dim3(256), 0, stream>>>(Bm, Cm);    // M^64  -> Cm (P)
    k_matsq<<<dim3(64), dim3(256), 0, stream>>>(Cm, Am);    // M^128
    k_matsq<<<dim3(64), dim3(256), 0, stream>>>(Am, Bm);    // M^256
    k_matsq<<<dim3(64), dim3(256), 0, stream>>>(Bm, Am);    // M^512 -> Am (P8)

    k_modulate4<<<dim3(257), dim3(512), 0, stream>>>(Vb, Ub, mp, Sb, 0);
    k_modulate4<<<dim3(257), dim3(512), 0, stream>>>(Vb, Ub, mp, Sb, 1);
    k_ifft2<<<dim3(256), dim3(512), 0, stream>>>(Sb, deltas);
    k_aru<<<dim3(1024), dim3(256), 0, stream>>>(x, m_u, deltas);

    k_chunk_local<<<dim3(512), dim3(128), 0, stream>>>(deltas, m_y, term);
    k_grp_scan<<<dim3(64), dim3(256), 0, stream>>>(Cm, term, qbuf, Qg);
    k_bnd8<<<dim3(8), dim3(256), 0, stream>>>(Am, Qg, Sgb);
    k_fixup<<<dim3(64), dim3(256), 0, stream>>>(Cm, Sgb, qbuf, sst);
    k_chunk_final<<<dim3(512), dim3(128), 0, stream>>>(deltas, m_y, sst, out);
}

// Round 9
// 314.998 us; speedup vs baseline: 10.6575x; 1.2346x over previous
//
#include <hip/hip_runtime.h>
#include <math.h>

#define BB 8
#define LL 4096
#define DD 64
#define KK 24
#define NN 8192
#define LOGN 13
#define NP 4128     // padded half-spectrum rows per batch (129 tiles * 32)

typedef unsigned int uint;
typedef unsigned short u16;
typedef __attribute__((ext_vector_type(8))) short bf16x8;
typedef __attribute__((ext_vector_type(4))) float f32x4;

__device__ __forceinline__ float bfl(uint u) {            // low bf16 -> float
    union { uint u; float f; } v; v.u = u << 16; return v.f;
}
__device__ __forceinline__ float bfh(uint u) {            // high bf16 -> float
    union { uint u; float f; } v; v.u = u & 0xFFFF0000u; return v.f;
}
__device__ __forceinline__ uint pk(float x) {             // float -> bf16 (rne), low bits
    union { float f; uint u; } v; v.f = x;
    return (v.u + 0x7FFFu + ((v.u >> 16) & 1u)) >> 16;
}
__device__ __forceinline__ float2 unpk2(uint u) {
    return make_float2(bfl(u), bfh(u));
}
__device__ __forceinline__ int br13(int v) { return (int)(__brev((uint)v) >> 19); }

// ---------------- FFT primitives (in-LDS, NT threads, N=8192) ----------------
template<int NT>
__device__ __forceinline__ void fft_dif(float2* a) {
    const int tid = threadIdx.x;
    for (int lh = LOGN - 1; lh >= 0; --lh) {
        const int half = 1 << lh;
        const float tw = -6.28318530717958647692f / (float)(2 << lh);
#pragma unroll
        for (int bb = 0; bb < NN / 2 / NT; ++bb) {
            int t = tid + bb * NT;
            int j = t & (half - 1);
            int i0 = ((t >> lh) << (lh + 1)) + j;
            float2 u = a[i0], v = a[i0 + half];
            float sn, cs;
            __sincosf(tw * (float)j, &sn, &cs);
            float dx = u.x - v.x, dy = u.y - v.y;
            a[i0] = make_float2(u.x + v.x, u.y + v.y);
            a[i0 + half] = make_float2(dx * cs - dy * sn, dx * sn + dy * cs);
        }
        __syncthreads();
    }
}

template<int NT>
__device__ __forceinline__ void fft_dit(float2* a) {
    const int tid = threadIdx.x;
    for (int lh = 0; lh < LOGN; ++lh) {
        const int half = 1 << lh;
        const float tw = 6.28318530717958647692f / (float)(2 << lh);
#pragma unroll
        for (int bb = 0; bb < NN / 2 / NT; ++bb) {
            int t = tid + bb * NT;
            int j = t & (half - 1);
            int i0 = ((t >> lh) << (lh + 1)) + j;
            float2 u = a[i0], v = a[i0 + half];
            float sn, cs;
            __sincosf(tw * (float)j, &sn, &cs);
            float wx = v.x * cs - v.y * sn;
            float wy = v.x * sn + v.y * cs;
            a[i0] = make_float2(u.x + wx, u.y + wy);
            a[i0 + half] = make_float2(u.x - wx, u.y - wy);
        }
        __syncthreads();
    }
}

// ---------------- kernels ----------------

// Pack m_phi into o-major bf16 c-pair table: mp2[k][o][cpair] (for MFMA B-frags).
__global__ __launch_bounds__(256) void k_pack(const float* __restrict__ mphi,
                                              uint* __restrict__ mp2) {
    int idx = blockIdx.x * 256 + threadIdx.x;
    if (idx >= KK * 64 * 32) return;
    int k = idx >> 11;
    int rem = idx & 2047;
    int o = rem >> 5, cp = rem & 31;
    int c = cp * 2;
    uint v = pk(mphi[(k * 64 + c) * 64 + o]) | (pk(mphi[(k * 64 + c + 1) * 64 + o]) << 16);
    mp2[idx] = v;
}

// V[f,k] = FFT(eig_vecs[:,k] * lambda_k^0.25 / N), bit-reversed bins, fp32
__global__ __launch_bounds__(256) void k_fft_filters(const float* __restrict__ eig_vals,
                                                     const float* __restrict__ eig_vecs,
                                                     float2* __restrict__ Vb) {
    __shared__ float2 a[NN];
    const int k = blockIdx.x, tid = threadIdx.x;
    const float alpha = powf(eig_vals[k], 0.25f) * (1.0f / (float)NN);
    for (int t = tid; t < LL; t += 256)
        a[t] = make_float2(eig_vecs[t * KK + k] * alpha, 0.f);
    for (int t = LL + tid; t < NN; t += 256)
        a[t] = make_float2(0.f, 0.f);
    __syncthreads();
    fft_dif<256>(a);
    for (int r = tid; r < NN; r += 256)
        Vb[(size_t)r * KK + k] = a[r];
}

// Two real channels per complex FFT: z = x[:,c] + i x[:,c+1].
// Writes Hermitian-half U as separate x/y bf16 planes [b][NP][64] (MFMA A layout).
__global__ __launch_bounds__(512) void k_fft_x2(const float* __restrict__ x,
                                                u16* __restrict__ Uxp,
                                                u16* __restrict__ Uyp) {
    __shared__ float2 a[NN];
    const int b = blockIdx.x >> 5, cp = blockIdx.x & 31;
    const int tid = threadIdx.x;
    for (int l = tid; l < LL; l += 512)
        a[l] = *(const float2*)&x[((size_t)b * LL + l) * DD + 2 * cp];
    for (int l = LL + tid; l < NN; l += 512)
        a[l] = make_float2(0.f, 0.f);
    __syncthreads();
    fft_dif<512>(a);
    for (int idx = tid; idx < 4097; idx += 512) {
        int r = (idx == 4096) ? 1 : 2 * idx;
        int fn = br13(r);
        int q = br13((8192 - fn) & 8191);
        float2 Z = a[r], W = a[q];
        float ucx = 0.5f * (Z.x + W.x), ucy = 0.5f * (Z.y - W.y);
        float upx = 0.5f * (Z.y + W.y), upy = 0.5f * (W.x - Z.x);
        size_t R = (size_t)b * NP + idx;
        *(uint*)&Uxp[R * 64 + 2 * cp] = pk(ucx) | (pk(upx) << 16);
        *(uint*)&Uyp[R * 64 + 2 * cp] = pk(ucy) | (pk(upy) << 16);
    }
}

// MFMA modulate, single pass over all 24 filters:
//   per k: W = U_tile x mphi_k  (2 real 16x16x32 bf16 MFMA chains per quadrant)
//   S += V[pos,k] * W           (complex scale-accumulate, fp32)
// Block = 32 rows (consecutive half-spectrum positions of one batch) x 64 outputs.
// 4 waves: w&1 = row-tile (16), w>>1 = o-half (32). mphi double-buffered in LDS.
__global__ __launch_bounds__(256) void k_modulate5(const float2* __restrict__ Vb,
                                                   const u16* __restrict__ Uxp,
                                                   const u16* __restrict__ Uyp,
                                                   const uint* __restrict__ mp2,
                                                   uint* __restrict__ Sb2) {
    __shared__ u16 Uxs[32][72];
    __shared__ u16 Uys[32][72];
    __shared__ u16 mpT[2][64][72];
    __shared__ float2 Vt[32][24];
    const int tid = threadIdx.x;
    const int pt = blockIdx.x;      // 0..128 position tiles
    const int b  = blockIdx.y;      // batch
    const int p0 = pt * 32;
    const size_t Rb = (size_t)b * NP + p0;

    {   // stage U tile (32 rows x 64 ch, both planes), padded rows for conflict-free reads
        int row = tid >> 3, seg = tid & 7;
        uint4 vx = *(const uint4*)&Uxp[(Rb + row) * 64 + seg * 8];
        uint4 vy = *(const uint4*)&Uyp[(Rb + row) * 64 + seg * 8];
        *(uint4*)&Uxs[row][seg * 8] = vx;
        *(uint4*)&Uys[row][seg * 8] = vy;
    }
    {   // stage mphi k=0: 64 o x 64 c = 512 uint4; 256 threads x 2 uint4
        int o = tid >> 2, seg = tid & 3;
        const uint4* src = (const uint4*)&mp2[(size_t)o * 32 + seg * 8];
        uint4 m0 = src[0], m1 = src[1];
        *(uint4*)&mpT[0][o][seg * 16] = m0;
        *(uint4*)&mpT[0][o][seg * 16 + 8] = m1;
    }
    for (int i = tid; i < 768; i += 256) {   // stage V (32 pos x 24 k)
        int pi = i / 24, kk = i - pi * 24;
        int pidx = p0 + pi; if (pidx > 4096) pidx = 4096;
        int r = (pidx == 4096) ? 1 : 2 * pidx;
        Vt[pi][kk] = Vb[(size_t)r * KK + kk];
    }
    __syncthreads();

    const int lane = tid & 63, w = tid >> 6;
    const int rt = w & 1, chalf = w >> 1;
    const int lrow = lane & 15, lk = lane >> 4;
    const u16* axp = &Uxs[rt * 16 + lrow][lk * 8];
    const u16* ayp = &Uys[rt * 16 + lrow][lk * 8];

    float Sx0[4] = {0.f, 0.f, 0.f, 0.f}, Sy0[4] = {0.f, 0.f, 0.f, 0.f};
    float Sx1[4] = {0.f, 0.f, 0.f, 0.f}, Sy1[4] = {0.f, 0.f, 0.f, 0.f};

    for (int k = 0; k < KK; ++k) {
        const int cur = k & 1;
        bf16x8 ax0 = *(const bf16x8*)(axp);
        bf16x8 ax1 = *(const bf16x8*)(axp + 32);
        bf16x8 ay0 = *(const bf16x8*)(ayp);
        bf16x8 ay1 = *(const bf16x8*)(ayp + 32);
        const u16* bp0 = &mpT[cur][chalf * 32 + lrow][lk * 8];
        const u16* bp1 = &mpT[cur][chalf * 32 + 16 + lrow][lk * 8];
        bf16x8 b00 = *(const bf16x8*)(bp0);
        bf16x8 b01 = *(const bf16x8*)(bp0 + 32);
        bf16x8 b10 = *(const bf16x8*)(bp1);
        bf16x8 b11 = *(const bf16x8*)(bp1 + 32);
        float2 v0 = Vt[rt * 16 + lk * 4 + 0][k];
        float2 v1 = Vt[rt * 16 + lk * 4 + 1][k];
        float2 v2 = Vt[rt * 16 + lk * 4 + 2][k];
        float2 v3 = Vt[rt * 16 + lk * 4 + 3][k];
        if (k + 1 < KK) {   // prefetch next mphi into other buffer (full c-range)
            int o = tid >> 2, seg = tid & 3;
            const uint4* src = (const uint4*)&mp2[((size_t)(k + 1) * 64 + o) * 32 + seg * 8];
            uint4 m0 = src[0], m1 = src[1];
            *(uint4*)&mpT[cur ^ 1][o][seg * 16] = m0;
            *(uint4*)&mpT[cur ^ 1][o][seg * 16 + 8] = m1;
        }
        f32x4 z = {0.f, 0.f, 0.f, 0.f};
        f32x4 Wx0 = __builtin_amdgcn_mfma_f32_16x16x32_bf16(ax0, b00, z, 0, 0, 0);
        Wx0 = __builtin_amdgcn_mfma_f32_16x16x32_bf16(ax1, b01, Wx0, 0, 0, 0);
        f32x4 Wy0 = __builtin_amdgcn_mfma_f32_16x16x32_bf16(ay0, b00, z, 0, 0, 0);
        Wy0 = __builtin_amdgcn_mfma_f32_16x16x32_bf16(ay1, b01, Wy0, 0, 0, 0);
        f32x4 Wx1 = __builtin_amdgcn_mfma_f32_16x16x32_bf16(ax0, b10, z, 0, 0, 0);
        Wx1 = __builtin_amdgcn_mfma_f32_16x16x32_bf16(ax1, b11, Wx1, 0, 0, 0);
        f32x4 Wy1 = __builtin_amdgcn_mfma_f32_16x16x32_bf16(ay0, b10, z, 0, 0, 0);
        Wy1 = __builtin_amdgcn_mfma_f32_16x16x32_bf16(ay1, b11, Wy1, 0, 0, 0);
        Sx0[0] += v0.x * Wx0[0] - v0.y * Wy0[0];  Sy0[0] += v0.x * Wy0[0] + v0.y * Wx0[0];
        Sx0[1] += v1.x * Wx0[1] - v1.y * Wy0[1];  Sy0[1] += v1.x * Wy0[1] + v1.y * Wx0[1];
        Sx0[2] += v2.x * Wx0[2] - v2.y * Wy0[2];  Sy0[2] += v2.x * Wy0[2] + v2.y * Wx0[2];
        Sx0[3] += v3.x * Wx0[3] - v3.y * Wy0[3];  Sy0[3] += v3.x * Wy0[3] + v3.y * Wx0[3];
        Sx1[0] += v0.x * Wx1[0] - v0.y * Wy1[0];  Sy1[0] += v0.x * Wy1[0] + v0.y * Wx1[0];
        Sx1[1] += v1.x * Wx1[1] - v1.y * Wy1[1];  Sy1[1] += v1.x * Wy1[1] + v1.y * Wx1[1];
        Sx1[2] += v2.x * Wx1[2] - v2.y * Wy1[2];  Sy1[2] += v2.x * Wy1[2] + v2.y * Wx1[2];
        Sx1[3] += v3.x * Wx1[3] - v3.y * Wy1[3];  Sy1[3] += v3.x * Wy1[3] + v3.y * Wx1[3];
        __syncthreads();
    }
    // store: C/D layout col=lane&15, row=(lane>>4)*4+reg  [verified m89]
    const int rbase = rt * 16 + lk * 4;
    const int o0 = chalf * 32 + lrow;
#pragma unroll
    for (int j = 0; j < 4; ++j) {
        Sb2[(Rb + rbase + j) * 64 + o0]      = pk(Sx0[j]) | (pk(Sy0[j]) << 16);
        Sb2[(Rb + rbase + j) * 64 + o0 + 16] = pk(Sx1[j]) | (pk(Sy1[j]) << 16);
    }
}

// Two output channels per inverse FFT. Stages Hermitian half from Sb2 (row-plane
// layout), reconstructs odd positions: z[q] = conj(S_o) + i conj(S_o').
__global__ __launch_bounds__(512) void k_ifft2(const uint* __restrict__ Sb2,
                                               float* __restrict__ deltas) {
    __shared__ float2 a[NN];
    const int b = blockIdx.x >> 5, op = blockIdx.x & 31;
    const int tid = threadIdx.x;
    for (int idx = tid; idx < 4097; idx += 512) {
        int r = (idx == 4096) ? 1 : 2 * idx;
        uint2 w = *(const uint2*)&Sb2[((size_t)b * NP + idx) * 64 + op * 2];
        float2 A = unpk2(w.x), B = unpk2(w.y);
        a[r] = make_float2(A.x - B.y, A.y + B.x);
        int fn = br13(r);
        int q = br13((8192 - fn) & 8191);
        if (q != r) a[q] = make_float2(A.x + B.y, B.x - A.y);
    }
    __syncthreads();
    fft_dit<512>(a);
    for (int l = tid; l < LL; l += 512)
        *(float2*)&deltas[((size_t)b * LL + l) * DD + op * 2] = make_float2(a[l].x, a[l].y);
}

// deltas += AR-U
__global__ __launch_bounds__(256) void k_aru(const float* __restrict__ x,
                                             const float* __restrict__ m_u,
                                             float* __restrict__ deltas) {
    __shared__ float mu_s[64 * 193];
    __shared__ float xs[34 * 64];
    const int tid = threadIdx.x;
    const int b = blockIdx.x >> 7;
    const int l0 = (blockIdx.x & 127) * 32;
    for (int idx = tid; idx < 64 * 192; idx += 256) {
        int o = idx / 192;
        int rem = idx - o * 192;
        mu_s[o * 193 + rem] = m_u[idx];
    }
    for (int idx = tid; idx < 34 * 64; idx += 256) {
        int rr = idx >> 6, i = idx & 63;
        int gl = l0 - 2 + rr;
        xs[idx] = (gl >= 0) ? x[((size_t)b * LL + gl) * DD + i] : 0.f;
    }
    __syncthreads();
    const int o = tid & 63, lsub = tid >> 6;
    for (int lb = 0; lb < 8; ++lb) {
        int ll = lsub * 8 + lb;
        int r = ll + 2;
        float acc = 0.f;
#pragma unroll
        for (int i = 0; i < 64; ++i) {
            int mb = o * 193 + i * 3;
            acc += mu_s[mb]     * xs[r * 64 + i]
                 + mu_s[mb + 1] * xs[(r - 1) * 64 + i]
                 + mu_s[mb + 2] * xs[(r - 2) * 64 + i];
        }
        deltas[((size_t)b * LL + l0 + ll) * DD + o] += acc;
    }
}

// First squaring with companion matrix built on the fly from m_y.
__global__ __launch_bounds__(256) void k_matsq1(const float* __restrict__ m_y,
                                                float* __restrict__ C) {
    int idx = blockIdx.x * 256 + threadIdx.x;
    int r = idx >> 7, c = idx & 127;
    if (r >= 64) { C[idx] = m_y[(r - 64) * 128 + c]; return; }
    float acc = (c < 64) ? m_y[r * 128 + 64 + c] : 0.f;
#pragma unroll
    for (int i = 0; i < 64; ++i) acc += m_y[r * 128 + i] * m_y[i * 128 + c];
    C[idx] = acc;
}

__global__ __launch_bounds__(256) void k_matsq(const float* __restrict__ A,
                                               float* __restrict__ C) {
    int idx = blockIdx.x * 256 + threadIdx.x;
    int r = idx >> 7, c = idx & 127;
    float acc = 0.f;
#pragma unroll
    for (int i = 0; i < 128; ++i) acc += A[r * 128 + i] * A[i * 128 + c];
    C[idx] = acc;
}

// ---- hierarchical boundary-scan helpers (row-half in 64 regs, no spill) ----
__device__ __forceinline__ void load_rowhalf(const float* __restrict__ P, int r, int h,
                                             float* __restrict__ p) {
#pragma unroll
    for (int i4 = 0; i4 < 16; ++i4) {
        float4 v = *(const float4*)&P[r * 128 + h * 64 + i4 * 4];
        p[4 * i4] = v.x; p[4 * i4 + 1] = v.y; p[4 * i4 + 2] = v.z; p[4 * i4 + 3] = v.w;
    }
}
__device__ __forceinline__ float dot64(const float* __restrict__ p, const float* s) {
    float a0 = 0.f, a1 = 0.f, a2 = 0.f, a3 = 0.f;
#pragma unroll
    for (int i4 = 0; i4 < 16; ++i4) {
        float4 w = *(const float4*)&s[i4 * 4];
        a0 += p[4 * i4] * w.x;  a1 += p[4 * i4 + 1] * w.y;
        a2 += p[4 * i4 + 2] * w.z;  a3 += p[4 * i4 + 3] * w.w;
    }
    return (a0 + a1) + (a2 + a3);
}

// Level 2: per (b,g): zero-init partial scan over the 8 chunks of group g.
__global__ __launch_bounds__(256, 1) void k_grp_scan(const float* __restrict__ P,
                                                     const float* __restrict__ term,
                                                     float* __restrict__ q,
                                                     float* __restrict__ Qg) {
    const int b = blockIdx.x >> 3, g = blockIdx.x & 7;
    const int tid = threadIdx.x;
    const int r = tid & 127, h = tid >> 7;
    __shared__ __align__(16) float scur[128];
    __shared__ float pacc[256];
    float p[64];
    load_rowhalf(P, r, h, p);
    if (tid < 128) scur[tid] = 0.f;
    __syncthreads();
    for (int k = 0; k < 8; ++k) {
        const size_t j = (size_t)(b * 64 + g * 8 + k) * 128;
        if (tid < 128) q[j + tid] = scur[tid];
        pacc[tid] = dot64(p, &scur[h * 64]);
        __syncthreads();
        if (tid < 128) scur[tid] = pacc[tid] + pacc[tid + 128] + term[j + tid];
        __syncthreads();
    }
    if (tid < 128) Qg[(b * 8 + g) * 128 + tid] = scur[tid];
}

// Level 3: per batch: scan over 8 group boundaries with P8 = M^512.
__global__ __launch_bounds__(256, 1) void k_bnd8(const float* __restrict__ P8,
                                                 const float* __restrict__ Qg,
                                                 float* __restrict__ Sg) {
    const int b = blockIdx.x;
    const int tid = threadIdx.x;
    const int r = tid & 127, h = tid >> 7;
    __shared__ __align__(16) float scur[128];
    __shared__ float pacc[256];
    float p[64];
    load_rowhalf(P8, r, h, p);
    if (tid < 128) scur[tid] = 0.f;
    __syncthreads();
    for (int g = 0; g < 8; ++g) {
        if (tid < 128) Sg[(b * 8 + g) * 128 + tid] = scur[tid];
        pacc[tid] = dot64(p, &scur[h * 64]);
        __syncthreads();
        if (tid < 128) scur[tid] = pacc[tid] + pacc[tid + 128] + Qg[(b * 8 + g) * 128 + tid];
        __syncthreads();
    }
}

// Level 4: per (b,g): s[8g+k] = P^k * Sg + q[8g+k], 8 serial P-multiplies.
__global__ __launch_bounds__(256, 1) void k_fixup(const float* __restrict__ P,
                                                  const float* __restrict__ Sg,
                                                  const float* __restrict__ q,
                                                  float* __restrict__ sst) {
    const int b = blockIdx.x >> 3, g = blockIdx.x & 7;
    const int tid = threadIdx.x;
    const int r = tid & 127, h = tid >> 7;
    __shared__ __align__(16) float scur[128];
    __shared__ float pacc[256];
    float p[64];
    load_rowhalf(P, r, h, p);
    if (tid < 128) scur[tid] = Sg[(b * 8 + g) * 128 + tid];
    __syncthreads();
    for (int k = 0; k < 8; ++k) {
        const size_t j = (size_t)(b * 64 + g * 8 + k) * 128;
        if (tid < 128) sst[j + tid] = scur[tid] + q[j + tid];
        if (k == 7) break;
        pacc[tid] = dot64(p, &scur[h * 64]);
        __syncthreads();
        if (tid < 128) scur[tid] = pacc[tid] + pacc[tid + 128];
        __syncthreads();
    }
}

// Per-chunk local recurrence, 2-wave split: thread (o,h) holds quarter-rows in
// 64 VGPRs (no spill). State in LDS.
__global__ __launch_bounds__(128, 1) void k_chunk_local(const float* __restrict__ deltas,
                                                        const float* __restrict__ m_y,
                                                        float* __restrict__ term) {
    const int b = blockIdx.x >> 6, j = blockIdx.x & 63;
    const int tid = threadIdx.x;
    const int o = tid & 63, h = tid >> 6;
    __shared__ __align__(16) float y1s[64];
    __shared__ __align__(16) float y2s[64];
    __shared__ float pacc[128];
    float m1[32], m2[32];
#pragma unroll
    for (int i4 = 0; i4 < 8; ++i4) {
        float4 v1 = *(const float4*)&m_y[o * 128 + h * 32 + i4 * 4];
        float4 v2 = *(const float4*)&m_y[o * 128 + 64 + h * 32 + i4 * 4];
        m1[4 * i4] = v1.x; m1[4 * i4 + 1] = v1.y; m1[4 * i4 + 2] = v1.z; m1[4 * i4 + 3] = v1.w;
        m2[4 * i4] = v2.x; m2[4 * i4 + 1] = v2.y; m2[4 * i4 + 2] = v2.z; m2[4 * i4 + 3] = v2.w;
    }
    if (tid < 64) { y1s[tid] = 0.f; y2s[tid] = 0.f; }
    __syncthreads();
    const float* dl = &deltas[(((size_t)b * LL) + j * 64) * DD + o];
    for (int t = 0; t < 64; ++t) {
        float a0 = 0.f, a1 = 0.f, a2 = 0.f, a3 = 0.f;
#pragma unroll
        for (int i4 = 0; i4 < 8; ++i4) {
            float4 w1 = *(const float4*)&y1s[h * 32 + i4 * 4];
            float4 w2 = *(const float4*)&y2s[h * 32 + i4 * 4];
            a0 += m1[4 * i4] * w1.x + m2[4 * i4] * w2.x;
            a1 += m1[4 * i4 + 1] * w1.y + m2[4 * i4 + 1] * w2.y;
            a2 += m1[4 * i4 + 2] * w1.z + m2[4 * i4 + 2] * w2.z;
            a3 += m1[4 * i4 + 3] * w1.w + m2[4 * i4 + 3] * w2.w;
        }
        pacc[tid] = (a0 + a1) + (a2 + a3);
        __syncthreads();
        if (h == 0) {
            float outv = pacc[o] + pacc[o + 64] + dl[t * DD];
            y2s[o] = y1s[o];
            y1s[o] = outv;
        }
        __syncthreads();
    }
    if (tid < 64) {
        term[((size_t)b * 64 + j) * 128 + o] = y1s[o];
        term[((size_t)b * 64 + j) * 128 + 64 + o] = y2s[o];
    }
}

// Per-chunk final recurrence with true initial states; writes outputs.
__global__ __launch_bounds__(128, 1) void k_chunk_final(const float* __restrict__ deltas,
                                                        const float* __restrict__ m_y,
                                                        const float* __restrict__ sstate,
                                                        float* __restrict__ out) {
    const int b = blockIdx.x >> 6, j = blockIdx.x & 63;
    const int tid = threadIdx.x;
    const int o = tid & 63, h = tid >> 6;
    __shared__ __align__(16) float y1s[64];
    __shared__ __align__(16) float y2s[64];
    __shared__ float pacc[128];
    float m1[32], m2[32];
#pragma unroll
    for (int i4 = 0; i4 < 8; ++i4) {
        float4 v1 = *(const float4*)&m_y[o * 128 + h * 32 + i4 * 4];
        float4 v2 = *(const float4*)&m_y[o * 128 + 64 + h * 32 + i4 * 4];
        m1[4 * i4] = v1.x; m1[4 * i4 + 1] = v1.y; m1[4 * i4 + 2] = v1.z; m1[4 * i4 + 3] = v1.w;
        m2[4 * i4] = v2.x; m2[4 * i4 + 1] = v2.y; m2[4 * i4 + 2] = v2.z; m2[4 * i4 + 3] = v2.w;
    }
    if (tid < 64) {
        y1s[tid] = sstate[((size_t)b * 64 + j) * 128 + tid];
        y2s[tid] = sstate[((size_t)b * 64 + j) * 128 + 64 + tid];
    }
    __syncthreads();
    const size_t base = (((size_t)b * LL) + j * 64) * DD + o;
    for (int t = 0; t < 64; ++t) {
        float a0 = 0.f, a1 = 0.f, a2 = 0.f, a3 = 0.f;
#pragma unroll
        for (int i4 = 0; i4 < 8; ++i4) {
            float4 w1 = *(const float4*)&y1s[h * 32 + i4 * 4];
            float4 w2 = *(const float4*)&y2s[h * 32 + i4 * 4];
            a0 += m1[4 * i4] * w1.x + m2[4 * i4] * w2.x;
            a1 += m1[4 * i4 + 1] * w1.y + m2[4 * i4 + 1] * w2.y;
            a2 += m1[4 * i4 + 2] * w1.z + m2[4 * i4 + 2] * w2.z;
            a3 += m1[4 * i4 + 3] * w1.w + m2[4 * i4 + 3] * w2.w;
        }
        pacc[tid] = (a0 + a1) + (a2 + a3);
        __syncthreads();
        if (h == 0) {
            float outv = pacc[o] + pacc[o + 64] + deltas[base + (size_t)t * DD];
            out[base + (size_t)t * DD] = outv;
            y2s[o] = y1s[o];
            y1s[o] = outv;
        }
        __syncthreads();
    }
}

extern "C" void kernel_launch(void* const* d_in, const int* in_sizes, int n_in,
                              void* d_out, int out_size, void* d_ws, size_t ws_size,
                              hipStream_t stream) {
    const float* x        = (const float*)d_in[0];
    const float* m_y      = (const float*)d_in[1];
    const float* m_u      = (const float*)d_in[2];
    const float* m_phi    = (const float*)d_in[3];
    const float* eig_vals = (const float*)d_in[4];
    const float* eig_vecs = (const float*)d_in[5];
    float* out = (float*)d_out;

    char* ws = (char*)d_ws;
    size_t off = 0;
    auto alloc = [&](size_t bytes) -> void* {
        void* p = ws + off;
        off += (bytes + 255) & ~(size_t)255;
        return p;
    };
    float2* Vb   = (float2*)alloc((size_t)NN * KK * sizeof(float2));          // 1.6 MB
    u16*    Uxp  = (u16*)alloc((size_t)BB * NP * 64 * sizeof(u16));           // 4.2 MB
    u16*    Uyp  = (u16*)alloc((size_t)BB * NP * 64 * sizeof(u16));           // 4.2 MB
    uint*   Sb2  = (uint*)alloc((size_t)BB * NP * 64 * sizeof(uint));         // 8.5 MB
    float*  deltas = (float*)alloc((size_t)BB * LL * DD * sizeof(float));     // 8.4 MB
    uint*   mp2  = (uint*)alloc((size_t)KK * 64 * 32 * sizeof(uint));         // 0.2 MB
    float*  mats = (float*)alloc((size_t)3 * 128 * 128 * sizeof(float));
    float*  term = (float*)alloc((size_t)BB * 64 * 128 * sizeof(float));
    float*  sst  = (float*)alloc((size_t)BB * 64 * 128 * sizeof(float));
    float*  qbuf = (float*)alloc((size_t)BB * 64 * 128 * sizeof(float));
    float*  Qg   = (float*)alloc((size_t)BB * 8 * 128 * sizeof(float));
    float*  Sgb  = (float*)alloc((size_t)BB * 8 * 128 * sizeof(float));

    k_pack<<<dim3(192), dim3(256), 0, stream>>>(m_phi, mp2);
    k_fft_filters<<<dim3(24), dim3(256), 0, stream>>>(eig_vals, eig_vecs, Vb);
    k_fft_x2<<<dim3(256), dim3(512), 0, stream>>>(x, Uxp, Uyp);

    float* Am = mats;
    float* Bm = mats + 16384;
    float* Cm = mats + 32768;
    k_matsq1<<<dim3(64), dim3(256), 0, stream>>>(m_y, Bm);  // M^2
    k_matsq<<<dim3(64), dim3(256), 0, stream>>>(Bm, Cm);    // M^4
    k_matsq<<<dim3(64), dim3(256), 0, stream>>>(Cm, Bm);    // M^8
    k_matsq<<<dim3(64), dim3(256), 0, stream>>>(Bm, Cm);    // M^16
    k_matsq<<<dim3(64), dim3(256), 0, stream>>>(Cm, Bm);    // M^32
    k_matsq<<<dim3(64), dim3(256), 0, stream>>>(Bm, Cm);    // M^64  -> Cm (P)
    k_matsq<<<dim3(64), dim3(256), 0, stream>>>(Cm, Am);    // M^128
    k_matsq<<<dim3(64), dim3(256), 0, stream>>>(Am, Bm);    // M^256
    k_matsq<<<dim3(64), dim3(256), 0, stream>>>(Bm, Am);    // M^512 -> Am (P8)

    k_modulate5<<<dim3(129, 8), dim3(256), 0, stream>>>(Vb, Uxp, Uyp, mp2, Sb2);
    k_ifft2<<<dim3(256), dim3(512), 0, stream>>>(Sb2, deltas);
    k_aru<<<dim3(1024), dim3(256), 0, stream>>>(x, m_u, deltas);

    k_chunk_local<<<dim3(512), dim3(128), 0, stream>>>(deltas, m_y, term);
    k_grp_scan<<<dim3(64), dim3(256), 0, stream>>>(Cm, term, qbuf, Qg);
    k_bnd8<<<dim3(8), dim3(256), 0, stream>>>(Am, Qg, Sgb);
    k_fixup<<<dim3(64), dim3(256), 0, stream>>>(Cm, Sgb, qbuf, sst);
    k_chunk_final<<<dim3(512), dim3(128), 0, stream>>>(deltas, m_y, sst, out);
}

// Round 10
// 305.996 us; speedup vs baseline: 10.9710x; 1.0294x over previous
//
#include <hip/hip_runtime.h>
#include <math.h>

#define BB 8
#define LL 4096
#define DD 64
#define KK 24
#define NN 8192
#define LOGN 13
#define NP 4128     // padded half-spectrum rows per batch (129 tiles * 32)
#define NCH 256     // chunks per batch
#define CH 16       // timesteps per chunk

typedef unsigned int uint;
typedef unsigned short u16;
typedef __attribute__((ext_vector_type(8))) short bf16x8;
typedef __attribute__((ext_vector_type(4))) float f32x4;

__device__ __forceinline__ float bfl(uint u) {
    union { uint u; float f; } v; v.u = u << 16; return v.f;
}
__device__ __forceinline__ float bfh(uint u) {
    union { uint u; float f; } v; v.u = u & 0xFFFF0000u; return v.f;
}
__device__ __forceinline__ uint pk(float x) {
    union { float f; uint u; } v; v.f = x;
    return (v.u + 0x7FFFu + ((v.u >> 16) & 1u)) >> 16;
}
__device__ __forceinline__ float2 unpk2(uint u) {
    return make_float2(bfl(u), bfh(u));
}
__device__ __forceinline__ int br13(int v) { return (int)(__brev((uint)v) >> 19); }

// ---------------- FFT primitives with LDS twiddle table ----------------
// twc[2^lh + j] = {cos, sin} of angle -2*pi*j / 2^(lh+1); twc[0] unused-safe.
template<int NT>
__device__ __forceinline__ void build_tw(float2* twc) {
    const int tid = threadIdx.x;
    for (int i = tid; i < 8192; i += NT) {
        if (i == 0) { twc[0] = make_float2(1.f, 0.f); continue; }
        int lh = 31 - __builtin_clz((uint)i);
        int j = i - (1 << lh);
        float ang = -6.28318530717958647692f * (float)j / (float)(2 << lh);
        float sn, cs;
        __sincosf(ang, &sn, &cs);
        twc[i] = make_float2(cs, sn);
    }
}

template<int NT>
__device__ __forceinline__ void fft_dif(float2* a, const float2* __restrict__ twc) {
    const int tid = threadIdx.x;
    for (int lh = LOGN - 1; lh >= 0; --lh) {
        const int half = 1 << lh;
#pragma unroll
        for (int bb = 0; bb < NN / 2 / NT; ++bb) {
            int t = tid + bb * NT;
            int j = t & (half - 1);
            int i0 = ((t >> lh) << (lh + 1)) + j;
            float2 u = a[i0], v = a[i0 + half];
            float2 w = twc[half + j];
            float cs = w.x, sn = w.y;
            float dx = u.x - v.x, dy = u.y - v.y;
            a[i0] = make_float2(u.x + v.x, u.y + v.y);
            a[i0 + half] = make_float2(dx * cs - dy * sn, dx * sn + dy * cs);
        }
        __syncthreads();
    }
}

template<int NT>
__device__ __forceinline__ void fft_dit(float2* a, const float2* __restrict__ twc) {
    const int tid = threadIdx.x;
    for (int lh = 0; lh < LOGN; ++lh) {
        const int half = 1 << lh;
#pragma unroll
        for (int bb = 0; bb < NN / 2 / NT; ++bb) {
            int t = tid + bb * NT;
            int j = t & (half - 1);
            int i0 = ((t >> lh) << (lh + 1)) + j;
            float2 u = a[i0], v = a[i0 + half];
            float2 w = twc[half + j];
            float cs = w.x, sn = -w.y;      // conjugate for inverse
            float wx = v.x * cs - v.y * sn;
            float wy = v.x * sn + v.y * cs;
            a[i0] = make_float2(u.x + wx, u.y + wy);
            a[i0 + half] = make_float2(u.x - wx, u.y - wy);
        }
        __syncthreads();
    }
}

// ---------------- kernels ----------------

// Pack m_phi into o-major bf16 c-pair table: mp2[k][o][cpair] (for MFMA B-frags).
__global__ __launch_bounds__(256) void k_pack(const float* __restrict__ mphi,
                                              uint* __restrict__ mp2) {
    int idx = blockIdx.x * 256 + threadIdx.x;
    if (idx >= KK * 64 * 32) return;
    int k = idx >> 11;
    int rem = idx & 2047;
    int o = rem >> 5, cp = rem & 31;
    int c = cp * 2;
    uint v = pk(mphi[(k * 64 + c) * 64 + o]) | (pk(mphi[(k * 64 + c + 1) * 64 + o]) << 16);
    mp2[idx] = v;
}

// V[f,k] = FFT(eig_vecs[:,k] * lambda_k^0.25 / N), bit-reversed bins, fp32
__global__ __launch_bounds__(256) void k_fft_filters(const float* __restrict__ eig_vals,
                                                     const float* __restrict__ eig_vecs,
                                                     float2* __restrict__ Vb) {
    __shared__ float2 a[NN];
    __shared__ float2 twc[8192];
    const int k = blockIdx.x, tid = threadIdx.x;
    const float alpha = powf(eig_vals[k], 0.25f) * (1.0f / (float)NN);
    for (int t = tid; t < LL; t += 256)
        a[t] = make_float2(eig_vecs[t * KK + k] * alpha, 0.f);
    for (int t = LL + tid; t < NN; t += 256)
        a[t] = make_float2(0.f, 0.f);
    build_tw<256>(twc);
    __syncthreads();
    fft_dif<256>(a, twc);
    for (int r = tid; r < NN; r += 256)
        Vb[(size_t)r * KK + k] = a[r];
}

// Two real channels per complex FFT: z = x[:,c] + i x[:,c+1].
// Writes Hermitian-half U as separate x/y bf16 planes [b][NP][64] (MFMA A layout).
__global__ __launch_bounds__(512) void k_fft_x2(const float* __restrict__ x,
                                                u16* __restrict__ Uxp,
                                                u16* __restrict__ Uyp) {
    __shared__ float2 a[NN];
    __shared__ float2 twc[8192];
    const int b = blockIdx.x >> 5, cp = blockIdx.x & 31;
    const int tid = threadIdx.x;
    for (int l = tid; l < LL; l += 512)
        a[l] = *(const float2*)&x[((size_t)b * LL + l) * DD + 2 * cp];
    for (int l = LL + tid; l < NN; l += 512)
        a[l] = make_float2(0.f, 0.f);
    build_tw<512>(twc);
    __syncthreads();
    fft_dif<512>(a, twc);
    for (int idx = tid; idx < 4097; idx += 512) {
        int r = (idx == 4096) ? 1 : 2 * idx;
        int fn = br13(r);
        int q = br13((8192 - fn) & 8191);
        float2 Z = a[r], W = a[q];
        float ucx = 0.5f * (Z.x + W.x), ucy = 0.5f * (Z.y - W.y);
        float upx = 0.5f * (Z.y + W.y), upy = 0.5f * (W.x - Z.x);
        size_t R = (size_t)b * NP + idx;
        *(uint*)&Uxp[R * 64 + 2 * cp] = pk(ucx) | (pk(upx) << 16);
        *(uint*)&Uyp[R * 64 + 2 * cp] = pk(ucy) | (pk(upy) << 16);
    }
}

// MFMA modulate, single pass over all 24 filters (unchanged from R9).
__global__ __launch_bounds__(256) void k_modulate5(const float2* __restrict__ Vb,
                                                   const u16* __restrict__ Uxp,
                                                   const u16* __restrict__ Uyp,
                                                   const uint* __restrict__ mp2,
                                                   uint* __restrict__ Sb2) {
    __shared__ u16 Uxs[32][72];
    __shared__ u16 Uys[32][72];
    __shared__ u16 mpT[2][64][72];
    __shared__ float2 Vt[32][24];
    const int tid = threadIdx.x;
    const int pt = blockIdx.x;
    const int b  = blockIdx.y;
    const int p0 = pt * 32;
    const size_t Rb = (size_t)b * NP + p0;

    {
        int row = tid >> 3, seg = tid & 7;
        uint4 vx = *(const uint4*)&Uxp[(Rb + row) * 64 + seg * 8];
        uint4 vy = *(const uint4*)&Uyp[(Rb + row) * 64 + seg * 8];
        *(uint4*)&Uxs[row][seg * 8] = vx;
        *(uint4*)&Uys[row][seg * 8] = vy;
    }
    {
        int o = tid >> 2, seg = tid & 3;
        const uint4* src = (const uint4*)&mp2[(size_t)o * 32 + seg * 8];
        uint4 m0 = src[0], m1 = src[1];
        *(uint4*)&mpT[0][o][seg * 16] = m0;
        *(uint4*)&mpT[0][o][seg * 16 + 8] = m1;
    }
    for (int i = tid; i < 768; i += 256) {
        int pi = i / 24, kk = i - pi * 24;
        int pidx = p0 + pi; if (pidx > 4096) pidx = 4096;
        int r = (pidx == 4096) ? 1 : 2 * pidx;
        Vt[pi][kk] = Vb[(size_t)r * KK + kk];
    }
    __syncthreads();

    const int lane = tid & 63, w = tid >> 6;
    const int rt = w & 1, chalf = w >> 1;
    const int lrow = lane & 15, lk = lane >> 4;
    const u16* axp = &Uxs[rt * 16 + lrow][lk * 8];
    const u16* ayp = &Uys[rt * 16 + lrow][lk * 8];

    float Sx0[4] = {0.f, 0.f, 0.f, 0.f}, Sy0[4] = {0.f, 0.f, 0.f, 0.f};
    float Sx1[4] = {0.f, 0.f, 0.f, 0.f}, Sy1[4] = {0.f, 0.f, 0.f, 0.f};

    for (int k = 0; k < KK; ++k) {
        const int cur = k & 1;
        bf16x8 ax0 = *(const bf16x8*)(axp);
        bf16x8 ax1 = *(const bf16x8*)(axp + 32);
        bf16x8 ay0 = *(const bf16x8*)(ayp);
        bf16x8 ay1 = *(const bf16x8*)(ayp + 32);
        const u16* bp0 = &mpT[cur][chalf * 32 + lrow][lk * 8];
        const u16* bp1 = &mpT[cur][chalf * 32 + 16 + lrow][lk * 8];
        bf16x8 b00 = *(const bf16x8*)(bp0);
        bf16x8 b01 = *(const bf16x8*)(bp0 + 32);
        bf16x8 b10 = *(const bf16x8*)(bp1);
        bf16x8 b11 = *(const bf16x8*)(bp1 + 32);
        float2 v0 = Vt[rt * 16 + lk * 4 + 0][k];
        float2 v1 = Vt[rt * 16 + lk * 4 + 1][k];
        float2 v2 = Vt[rt * 16 + lk * 4 + 2][k];
        float2 v3 = Vt[rt * 16 + lk * 4 + 3][k];
        if (k + 1 < KK) {
            int o = tid >> 2, seg = tid & 3;
            const uint4* src = (const uint4*)&mp2[((size_t)(k + 1) * 64 + o) * 32 + seg * 8];
            uint4 m0 = src[0], m1 = src[1];
            *(uint4*)&mpT[cur ^ 1][o][seg * 16] = m0;
            *(uint4*)&mpT[cur ^ 1][o][seg * 16 + 8] = m1;
        }
        f32x4 z = {0.f, 0.f, 0.f, 0.f};
        f32x4 Wx0 = __builtin_amdgcn_mfma_f32_16x16x32_bf16(ax0, b00, z, 0, 0, 0);
        Wx0 = __builtin_amdgcn_mfma_f32_16x16x32_bf16(ax1, b01, Wx0, 0, 0, 0);
        f32x4 Wy0 = __builtin_amdgcn_mfma_f32_16x16x32_bf16(ay0, b00, z, 0, 0, 0);
        Wy0 = __builtin_amdgcn_mfma_f32_16x16x32_bf16(ay1, b01, Wy0, 0, 0, 0);
        f32x4 Wx1 = __builtin_amdgcn_mfma_f32_16x16x32_bf16(ax0, b10, z, 0, 0, 0);
        Wx1 = __builtin_amdgcn_mfma_f32_16x16x32_bf16(ax1, b11, Wx1, 0, 0, 0);
        f32x4 Wy1 = __builtin_amdgcn_mfma_f32_16x16x32_bf16(ay0, b10, z, 0, 0, 0);
        Wy1 = __builtin_amdgcn_mfma_f32_16x16x32_bf16(ay1, b11, Wy1, 0, 0, 0);
        Sx0[0] += v0.x * Wx0[0] - v0.y * Wy0[0];  Sy0[0] += v0.x * Wy0[0] + v0.y * Wx0[0];
        Sx0[1] += v1.x * Wx0[1] - v1.y * Wy0[1];  Sy0[1] += v1.x * Wy0[1] + v1.y * Wx0[1];
        Sx0[2] += v2.x * Wx0[2] - v2.y * Wy0[2];  Sy0[2] += v2.x * Wy0[2] + v2.y * Wx0[2];
        Sx0[3] += v3.x * Wx0[3] - v3.y * Wy0[3];  Sy0[3] += v3.x * Wy0[3] + v3.y * Wx0[3];
        Sx1[0] += v0.x * Wx1[0] - v0.y * Wy1[0];  Sy1[0] += v0.x * Wy1[0] + v0.y * Wx1[0];
        Sx1[1] += v1.x * Wx1[1] - v1.y * Wy1[1];  Sy1[1] += v1.x * Wy1[1] + v1.y * Wx1[1];
        Sx1[2] += v2.x * Wx1[2] - v2.y * Wy1[2];  Sy1[2] += v2.x * Wy1[2] + v2.y * Wx1[2];
        Sx1[3] += v3.x * Wx1[3] - v3.y * Wy1[3];  Sy1[3] += v3.x * Wy1[3] + v3.y * Wx1[3];
        __syncthreads();
    }
    const int rbase = rt * 16 + lk * 4;
    const int o0 = chalf * 32 + lrow;
#pragma unroll
    for (int j = 0; j < 4; ++j) {
        Sb2[(Rb + rbase + j) * 64 + o0]      = pk(Sx0[j]) | (pk(Sy0[j]) << 16);
        Sb2[(Rb + rbase + j) * 64 + o0 + 16] = pk(Sx1[j]) | (pk(Sy1[j]) << 16);
    }
}

// Two output channels per inverse FFT (twiddle-table version).
__global__ __launch_bounds__(512) void k_ifft2(const uint* __restrict__ Sb2,
                                               float* __restrict__ deltas) {
    __shared__ float2 a[NN];
    __shared__ float2 twc[8192];
    const int b = blockIdx.x >> 5, op = blockIdx.x & 31;
    const int tid = threadIdx.x;
    for (int idx = tid; idx < 4097; idx += 512) {
        int r = (idx == 4096) ? 1 : 2 * idx;
        uint2 w = *(const uint2*)&Sb2[((size_t)b * NP + idx) * 64 + op * 2];
        float2 A = unpk2(w.x), B = unpk2(w.y);
        a[r] = make_float2(A.x - B.y, A.y + B.x);
        int fn = br13(r);
        int q = br13((8192 - fn) & 8191);
        if (q != r) a[q] = make_float2(A.x + B.y, B.x - A.y);
    }
    build_tw<512>(twc);
    __syncthreads();
    fft_dit<512>(a, twc);
    for (int l = tid; l < LL; l += 512)
        *(float2*)&deltas[((size_t)b * LL + l) * DD + op * 2] = make_float2(a[l].x, a[l].y);
}

// deltas += AR-U
__global__ __launch_bounds__(256) void k_aru(const float* __restrict__ x,
                                             const float* __restrict__ m_u,
                                             float* __restrict__ deltas) {
    __shared__ float mu_s[64 * 193];
    __shared__ float xs[34 * 64];
    const int tid = threadIdx.x;
    const int b = blockIdx.x >> 7;
    const int l0 = (blockIdx.x & 127) * 32;
    for (int idx = tid; idx < 64 * 192; idx += 256) {
        int o = idx / 192;
        int rem = idx - o * 192;
        mu_s[o * 193 + rem] = m_u[idx];
    }
    for (int idx = tid; idx < 34 * 64; idx += 256) {
        int rr = idx >> 6, i = idx & 63;
        int gl = l0 - 2 + rr;
        xs[idx] = (gl >= 0) ? x[((size_t)b * LL + gl) * DD + i] : 0.f;
    }
    __syncthreads();
    const int o = tid & 63, lsub = tid >> 6;
    for (int lb = 0; lb < 8; ++lb) {
        int ll = lsub * 8 + lb;
        int r = ll + 2;
        float acc = 0.f;
#pragma unroll
        for (int i = 0; i < 64; ++i) {
            int mb = o * 193 + i * 3;
            acc += mu_s[mb]     * xs[r * 64 + i]
                 + mu_s[mb + 1] * xs[(r - 1) * 64 + i]
                 + mu_s[mb + 2] * xs[(r - 2) * 64 + i];
        }
        deltas[((size_t)b * LL + l0 + ll) * DD + o] += acc;
    }
}

// First squaring with companion matrix built on the fly from m_y.
__global__ __launch_bounds__(256) void k_matsq1(const float* __restrict__ m_y,
                                                float* __restrict__ C) {
    int idx = blockIdx.x * 256 + threadIdx.x;
    int r = idx >> 7, c = idx & 127;
    if (r >= 64) { C[idx] = m_y[(r - 64) * 128 + c]; return; }
    float acc = (c < 64) ? m_y[r * 128 + 64 + c] : 0.f;
#pragma unroll
    for (int i = 0; i < 64; ++i) acc += m_y[r * 128 + i] * m_y[i * 128 + c];
    C[idx] = acc;
}

__global__ __launch_bounds__(256) void k_matsq(const float* __restrict__ A,
                                               float* __restrict__ C) {
    int idx = blockIdx.x * 256 + threadIdx.x;
    int r = idx >> 7, c = idx & 127;
    float acc = 0.f;
#pragma unroll
    for (int i = 0; i < 128; ++i) acc += A[r * 128 + i] * A[i * 128 + c];
    C[idx] = acc;
}

// ---- hierarchical boundary-scan helpers (row-half in 64 regs, no spill) ----
__device__ __forceinline__ void load_rowhalf(const float* __restrict__ P, int r, int h,
                                             float* __restrict__ p) {
#pragma unroll
    for (int i4 = 0; i4 < 16; ++i4) {
        float4 v = *(const float4*)&P[r * 128 + h * 64 + i4 * 4];
        p[4 * i4] = v.x; p[4 * i4 + 1] = v.y; p[4 * i4 + 2] = v.z; p[4 * i4 + 3] = v.w;
    }
}
__device__ __forceinline__ float dot64(const float* __restrict__ p, const float* s) {
    float a0 = 0.f, a1 = 0.f, a2 = 0.f, a3 = 0.f;
#pragma unroll
    for (int i4 = 0; i4 < 16; ++i4) {
        float4 w = *(const float4*)&s[i4 * 4];
        a0 += p[4 * i4] * w.x;  a1 += p[4 * i4 + 1] * w.y;
        a2 += p[4 * i4 + 2] * w.z;  a3 += p[4 * i4 + 3] * w.w;
    }
    return (a0 + a1) + (a2 + a3);
}

// Generic affine scan: per block, zero-init scan over `count` inputs with matrix P.
// partial[k] = state before step k; terminal = state after all steps.
__global__ __launch_bounds__(256, 1) void k_scan(const float* __restrict__ P,
                                                 const float* __restrict__ in,
                                                 float* __restrict__ partial,
                                                 float* __restrict__ terminal,
                                                 const int count) {
    const int bx = blockIdx.x;
    const int tid = threadIdx.x;
    const int r = tid & 127, h = tid >> 7;
    __shared__ __align__(16) float scur[128];
    __shared__ float pacc[256];
    float p[64];
    load_rowhalf(P, r, h, p);
    if (tid < 128) scur[tid] = 0.f;
    __syncthreads();
    const size_t base = (size_t)bx * count * 128;
    for (int k = 0; k < count; ++k) {
        if (tid < 128) partial[base + (size_t)k * 128 + tid] = scur[tid];
        pacc[tid] = dot64(p, &scur[h * 64]);
        __syncthreads();
        if (tid < 128) scur[tid] = pacc[tid] + pacc[tid + 128] + in[base + (size_t)k * 128 + tid];
        __syncthreads();
    }
    if (tid < 128) terminal[(size_t)bx * 128 + tid] = scur[tid];
}

// Generic fixup: out[k] = P^k * Sinit + q[k].
__global__ __launch_bounds__(256, 1) void k_fixupg(const float* __restrict__ P,
                                                   const float* __restrict__ Sinit,
                                                   const float* __restrict__ q,
                                                   float* __restrict__ out,
                                                   const int count) {
    const int bx = blockIdx.x;
    const int tid = threadIdx.x;
    const int r = tid & 127, h = tid >> 7;
    __shared__ __align__(16) float scur[128];
    __shared__ float pacc[256];
    float p[64];
    load_rowhalf(P, r, h, p);
    if (tid < 128) scur[tid] = Sinit[(size_t)bx * 128 + tid];
    __syncthreads();
    const size_t base = (size_t)bx * count * 128;
    for (int k = 0; k < count; ++k) {
        if (tid < 128) out[base + (size_t)k * 128 + tid] = scur[tid] + q[base + (size_t)k * 128 + tid];
        if (k == count - 1) break;
        pacc[tid] = dot64(p, &scur[h * 64]);
        __syncthreads();
        if (tid < 128) scur[tid] = pacc[tid] + pacc[tid + 128];
        __syncthreads();
    }
}

// Per-chunk local recurrence (CH=16 steps), 2-wave split.
__global__ __launch_bounds__(128, 1) void k_chunk_local(const float* __restrict__ deltas,
                                                        const float* __restrict__ m_y,
                                                        float* __restrict__ term) {
    const int b = blockIdx.x >> 8, j = blockIdx.x & 255;
    const int tid = threadIdx.x;
    const int o = tid & 63, h = tid >> 6;
    __shared__ __align__(16) float y1s[64];
    __shared__ __align__(16) float y2s[64];
    __shared__ float pacc[128];
    float m1[32], m2[32];
#pragma unroll
    for (int i4 = 0; i4 < 8; ++i4) {
        float4 v1 = *(const float4*)&m_y[o * 128 + h * 32 + i4 * 4];
        float4 v2 = *(const float4*)&m_y[o * 128 + 64 + h * 32 + i4 * 4];
        m1[4 * i4] = v1.x; m1[4 * i4 + 1] = v1.y; m1[4 * i4 + 2] = v1.z; m1[4 * i4 + 3] = v1.w;
        m2[4 * i4] = v2.x; m2[4 * i4 + 1] = v2.y; m2[4 * i4 + 2] = v2.z; m2[4 * i4 + 3] = v2.w;
    }
    if (tid < 64) { y1s[tid] = 0.f; y2s[tid] = 0.f; }
    __syncthreads();
    const float* dl = &deltas[(((size_t)b * LL) + j * CH) * DD + o];
    for (int t = 0; t < CH; ++t) {
        float a0 = 0.f, a1 = 0.f, a2 = 0.f, a3 = 0.f;
#pragma unroll
        for (int i4 = 0; i4 < 8; ++i4) {
            float4 w1 = *(const float4*)&y1s[h * 32 + i4 * 4];
            float4 w2 = *(const float4*)&y2s[h * 32 + i4 * 4];
            a0 += m1[4 * i4] * w1.x + m2[4 * i4] * w2.x;
            a1 += m1[4 * i4 + 1] * w1.y + m2[4 * i4 + 1] * w2.y;
            a2 += m1[4 * i4 + 2] * w1.z + m2[4 * i4 + 2] * w2.z;
            a3 += m1[4 * i4 + 3] * w1.w + m2[4 * i4 + 3] * w2.w;
        }
        pacc[tid] = (a0 + a1) + (a2 + a3);
        __syncthreads();
        if (h == 0) {
            float outv = pacc[o] + pacc[o + 64] + dl[t * DD];
            y2s[o] = y1s[o];
            y1s[o] = outv;
        }
        __syncthreads();
    }
    if (tid < 64) {
        term[((size_t)b * NCH + j) * 128 + o] = y1s[o];
        term[((size_t)b * NCH + j) * 128 + 64 + o] = y2s[o];
    }
}

// Per-chunk final recurrence with true initial states; writes outputs.
__global__ __launch_bounds__(128, 1) void k_chunk_final(const float* __restrict__ deltas,
                                                        const float* __restrict__ m_y,
                                                        const float* __restrict__ sstate,
                                                        float* __restrict__ out) {
    const int b = blockIdx.x >> 8, j = blockIdx.x & 255;
    const int tid = threadIdx.x;
    const int o = tid & 63, h = tid >> 6;
    __shared__ __align__(16) float y1s[64];
    __shared__ __align__(16) float y2s[64];
    __shared__ float pacc[128];
    float m1[32], m2[32];
#pragma unroll
    for (int i4 = 0; i4 < 8; ++i4) {
        float4 v1 = *(const float4*)&m_y[o * 128 + h * 32 + i4 * 4];
        float4 v2 = *(const float4*)&m_y[o * 128 + 64 + h * 32 + i4 * 4];
        m1[4 * i4] = v1.x; m1[4 * i4 + 1] = v1.y; m1[4 * i4 + 2] = v1.z; m1[4 * i4 + 3] = v1.w;
        m2[4 * i4] = v2.x; m2[4 * i4 + 1] = v2.y; m2[4 * i4 + 2] = v2.z; m2[4 * i4 + 3] = v2.w;
    }
    if (tid < 64) {
        y1s[tid] = sstate[((size_t)b * NCH + j) * 128 + tid];
        y2s[tid] = sstate[((size_t)b * NCH + j) * 128 + 64 + tid];
    }
    __syncthreads();
    const size_t base = (((size_t)b * LL) + j * CH) * DD + o;
    for (int t = 0; t < CH; ++t) {
        float a0 = 0.f, a1 = 0.f, a2 = 0.f, a3 = 0.f;
#pragma unroll
        for (int i4 = 0; i4 < 8; ++i4) {
            float4 w1 = *(const float4*)&y1s[h * 32 + i4 * 4];
            float4 w2 = *(const float4*)&y2s[h * 32 + i4 * 4];
            a0 += m1[4 * i4] * w1.x + m2[4 * i4] * w2.x;
            a1 += m1[4 * i4 + 1] * w1.y + m2[4 * i4 + 1] * w2.y;
            a2 += m1[4 * i4 + 2] * w1.z + m2[4 * i4 + 2] * w2.z;
            a3 += m1[4 * i4 + 3] * w1.w + m2[4 * i4 + 3] * w2.w;
        }
        pacc[tid] = (a0 + a1) + (a2 + a3);
        __syncthreads();
        if (h == 0) {
            float outv = pacc[o] + pacc[o + 64] + deltas[base + (size_t)t * DD];
            out[base + (size_t)t * DD] = outv;
            y2s[o] = y1s[o];
            y1s[o] = outv;
        }
        __syncthreads();
    }
}

extern "C" void kernel_launch(void* const* d_in, const int* in_sizes, int n_in,
                              void* d_out, int out_size, void* d_ws, size_t ws_size,
                              hipStream_t stream) {
    const float* x        = (const float*)d_in[0];
    const float* m_y      = (const float*)d_in[1];
    const float* m_u      = (const float*)d_in[2];
    const float* m_phi    = (const float*)d_in[3];
    const float* eig_vals = (const float*)d_in[4];
    const float* eig_vecs = (const float*)d_in[5];
    float* out = (float*)d_out;

    char* ws = (char*)d_ws;
    size_t off = 0;
    auto alloc = [&](size_t bytes) -> void* {
        void* p = ws + off;
        off += (bytes + 255) & ~(size_t)255;
        return p;
    };
    float2* Vb   = (float2*)alloc((size_t)NN * KK * sizeof(float2));          // 1.6 MB
    u16*    Uxp  = (u16*)alloc((size_t)BB * NP * 64 * sizeof(u16));           // 4.2 MB
    u16*    Uyp  = (u16*)alloc((size_t)BB * NP * 64 * sizeof(u16));           // 4.2 MB
    uint*   Sb2  = (uint*)alloc((size_t)BB * NP * 64 * sizeof(uint));         // 8.5 MB
    float*  deltas = (float*)alloc((size_t)BB * LL * DD * sizeof(float));     // 8.4 MB
    uint*   mp2  = (uint*)alloc((size_t)KK * 64 * 32 * sizeof(uint));         // 0.2 MB
    float*  mats = (float*)alloc((size_t)5 * 128 * 128 * sizeof(float));
    float*  term = (float*)alloc((size_t)BB * NCH * 128 * sizeof(float));     // 1 MB
    float*  sst  = (float*)alloc((size_t)BB * NCH * 128 * sizeof(float));     // 1 MB
    float*  qbuf = (float*)alloc((size_t)BB * NCH * 128 * sizeof(float));     // 1 MB
    float*  Qg   = (float*)alloc((size_t)BB * 32 * 128 * sizeof(float));
    float*  q2   = (float*)alloc((size_t)BB * 32 * 128 * sizeof(float));
    float*  Sgt  = (float*)alloc((size_t)BB * 32 * 128 * sizeof(float));
    float*  Qsg  = (float*)alloc((size_t)BB * 4 * 128 * sizeof(float));
    float*  Ssg  = (float*)alloc((size_t)BB * 4 * 128 * sizeof(float));
    float*  dmy  = (float*)alloc((size_t)8 * 128 * sizeof(float));

    k_pack<<<dim3(192), dim3(256), 0, stream>>>(m_phi, mp2);
    k_fft_filters<<<dim3(24), dim3(256), 0, stream>>>(eig_vals, eig_vecs, Vb);
    k_fft_x2<<<dim3(256), dim3(512), 0, stream>>>(x, Uxp, Uyp);

    float* T1    = mats;
    float* T2    = mats + 16384;
    float* P16   = mats + 32768;
    float* P128  = mats + 49152;
    float* P1024 = mats + 65536;
    k_matsq1<<<dim3(64), dim3(256), 0, stream>>>(m_y, T1);   // M^2
    k_matsq<<<dim3(64), dim3(256), 0, stream>>>(T1, T2);     // M^4
    k_matsq<<<dim3(64), dim3(256), 0, stream>>>(T2, T1);     // M^8
    k_matsq<<<dim3(64), dim3(256), 0, stream>>>(T1, P16);    // M^16
    k_matsq<<<dim3(64), dim3(256), 0, stream>>>(P16, T1);    // M^32
    k_matsq<<<dim3(64), dim3(256), 0, stream>>>(T1, T2);     // M^64
    k_matsq<<<dim3(64), dim3(256), 0, stream>>>(T2, P128);   // M^128
    k_matsq<<<dim3(64), dim3(256), 0, stream>>>(P128, T1);   // M^256
    k_matsq<<<dim3(64), dim3(256), 0, stream>>>(T1, T2);     // M^512
    k_matsq<<<dim3(64), dim3(256), 0, stream>>>(T2, P1024);  // M^1024

    k_modulate5<<<dim3(129, 8), dim3(256), 0, stream>>>(Vb, Uxp, Uyp, mp2, Sb2);
    k_ifft2<<<dim3(256), dim3(512), 0, stream>>>(Sb2, deltas);
    k_aru<<<dim3(1024), dim3(256), 0, stream>>>(x, m_u, deltas);

    k_chunk_local<<<dim3(2048), dim3(128), 0, stream>>>(deltas, m_y, term);
    k_scan<<<dim3(256), dim3(256), 0, stream>>>(P16, term, qbuf, Qg, 8);    // (b,g<32)
    k_scan<<<dim3(32), dim3(256), 0, stream>>>(P128, Qg, q2, Qsg, 8);       // (b,sg<4)
    k_scan<<<dim3(8), dim3(256), 0, stream>>>(P1024, Qsg, Ssg, dmy, 4);     // per b
    k_fixupg<<<dim3(32), dim3(256), 0, stream>>>(P128, Ssg, q2, Sgt, 8);    // group inits
    k_fixupg<<<dim3(256), dim3(256), 0, stream>>>(P16, Sgt, qbuf, sst, 8);  // chunk inits
    k_chunk_final<<<dim3(2048), dim3(128), 0, stream>>>(deltas, m_y, sst, out);
}

// Round 11
// 278.006 us; speedup vs baseline: 12.0756x; 1.1007x over previous
//
#include <hip/hip_runtime.h>
#include <math.h>

#define BB 8
#define LL 4096
#define DD 64
#define KK 24
#define NN 8192
#define LOGN 13
#define NP 4128     // padded half-spectrum rows per batch (129 tiles * 32)
#define NCH 256     // chunks per batch
#define CH 16       // timesteps per chunk

typedef unsigned int uint;
typedef unsigned short u16;
typedef __attribute__((ext_vector_type(8))) short bf16x8;
typedef __attribute__((ext_vector_type(4))) float f32x4;

__device__ __forceinline__ float bfl(uint u) {
    union { uint u; float f; } v; v.u = u << 16; return v.f;
}
__device__ __forceinline__ float bfh(uint u) {
    union { uint u; float f; } v; v.u = u & 0xFFFF0000u; return v.f;
}
__device__ __forceinline__ uint pk(float x) {
    union { float f; uint u; } v; v.f = x;
    return (v.u + 0x7FFFu + ((v.u >> 16) & 1u)) >> 16;
}
__device__ __forceinline__ float2 unpk2(uint u) {
    return make_float2(bfl(u), bfh(u));
}
__device__ __forceinline__ int br13(int v) { return (int)(__brev((uint)v) >> 19); }

// ---------------- FFT primitives with LDS twiddle table ----------------
template<int NT>
__device__ __forceinline__ void build_tw(float2* twc) {
    const int tid = threadIdx.x;
    for (int i = tid; i < 8192; i += NT) {
        if (i == 0) { twc[0] = make_float2(1.f, 0.f); continue; }
        int lh = 31 - __builtin_clz((uint)i);
        int j = i - (1 << lh);
        float ang = -6.28318530717958647692f * (float)j / (float)(2 << lh);
        float sn, cs;
        __sincosf(ang, &sn, &cs);
        twc[i] = make_float2(cs, sn);
    }
}

template<int NT>
__device__ __forceinline__ void fft_dif(float2* a, const float2* __restrict__ twc) {
    const int tid = threadIdx.x;
    for (int lh = LOGN - 1; lh >= 0; --lh) {
        const int half = 1 << lh;
#pragma unroll
        for (int bb = 0; bb < NN / 2 / NT; ++bb) {
            int t = tid + bb * NT;
            int j = t & (half - 1);
            int i0 = ((t >> lh) << (lh + 1)) + j;
            float2 u = a[i0], v = a[i0 + half];
            float2 w = twc[half + j];
            float cs = w.x, sn = w.y;
            float dx = u.x - v.x, dy = u.y - v.y;
            a[i0] = make_float2(u.x + v.x, u.y + v.y);
            a[i0 + half] = make_float2(dx * cs - dy * sn, dx * sn + dy * cs);
        }
        __syncthreads();
    }
}

template<int NT>
__device__ __forceinline__ void fft_dit(float2* a, const float2* __restrict__ twc) {
    const int tid = threadIdx.x;
    for (int lh = 0; lh < LOGN; ++lh) {
        const int half = 1 << lh;
#pragma unroll
        for (int bb = 0; bb < NN / 2 / NT; ++bb) {
            int t = tid + bb * NT;
            int j = t & (half - 1);
            int i0 = ((t >> lh) << (lh + 1)) + j;
            float2 u = a[i0], v = a[i0 + half];
            float2 w = twc[half + j];
            float cs = w.x, sn = -w.y;      // conjugate for inverse
            float wx = v.x * cs - v.y * sn;
            float wy = v.x * sn + v.y * cs;
            a[i0] = make_float2(u.x + wx, u.y + wy);
            a[i0 + half] = make_float2(u.x - wx, u.y - wy);
        }
        __syncthreads();
    }
}

// ---------------- kernels ----------------

// Pack m_phi into o-major bf16 c-pair table: mp2[k][o][cpair] (for MFMA B-frags).
__global__ __launch_bounds__(256) void k_pack(const float* __restrict__ mphi,
                                              uint* __restrict__ mp2) {
    int idx = blockIdx.x * 256 + threadIdx.x;
    if (idx >= KK * 64 * 32) return;
    int k = idx >> 11;
    int rem = idx & 2047;
    int o = rem >> 5, cp = rem & 31;
    int c = cp * 2;
    uint v = pk(mphi[(k * 64 + c) * 64 + o]) | (pk(mphi[(k * 64 + c + 1) * 64 + o]) << 16);
    mp2[idx] = v;
}

// V[f,k] = FFT(eig_vecs[:,k] * lambda_k^0.25 / N), bit-reversed bins, fp32
__global__ __launch_bounds__(256) void k_fft_filters(const float* __restrict__ eig_vals,
                                                     const float* __restrict__ eig_vecs,
                                                     float2* __restrict__ Vb) {
    __shared__ float2 a[NN];
    __shared__ float2 twc[8192];
    const int k = blockIdx.x, tid = threadIdx.x;
    const float alpha = powf(eig_vals[k], 0.25f) * (1.0f / (float)NN);
    for (int t = tid; t < LL; t += 256)
        a[t] = make_float2(eig_vecs[t * KK + k] * alpha, 0.f);
    for (int t = LL + tid; t < NN; t += 256)
        a[t] = make_float2(0.f, 0.f);
    build_tw<256>(twc);
    __syncthreads();
    fft_dif<256>(a, twc);
    for (int r = tid; r < NN; r += 256)
        Vb[(size_t)r * KK + k] = a[r];
}

// Two real channels per complex FFT: z = x[:,c] + i x[:,c+1].
// Plane-major output: Uxp/Uyp[(b*32+cp)*NP + idx] (uint packs ch 2cp | 2cp+1).
// XCD swizzle: b = blockIdx & 7 so same-batch blocks share one L2 for x reads.
__global__ __launch_bounds__(512) void k_fft_x2(const float* __restrict__ x,
                                                uint* __restrict__ Uxp,
                                                uint* __restrict__ Uyp) {
    __shared__ float2 a[NN];
    __shared__ float2 twc[8192];
    const int b = blockIdx.x & 7, cp = blockIdx.x >> 3;
    const int tid = threadIdx.x;
    for (int l = tid; l < LL; l += 512)
        a[l] = *(const float2*)&x[((size_t)b * LL + l) * DD + 2 * cp];
    for (int l = LL + tid; l < NN; l += 512)
        a[l] = make_float2(0.f, 0.f);
    build_tw<512>(twc);
    __syncthreads();
    fft_dif<512>(a, twc);
    const size_t plane = ((size_t)b * 32 + cp) * NP;
    for (int idx = tid; idx < 4097; idx += 512) {
        int r = (idx == 4096) ? 1 : 2 * idx;
        int fn = br13(r);
        int q = br13((8192 - fn) & 8191);
        float2 Z = a[r], W = a[q];
        float ucx = 0.5f * (Z.x + W.x), ucy = 0.5f * (Z.y - W.y);
        float upx = 0.5f * (Z.y + W.y), upy = 0.5f * (W.x - Z.x);
        Uxp[plane + idx] = pk(ucx) | (pk(upx) << 16);
        Uyp[plane + idx] = pk(ucy) | (pk(upy) << 16);
    }
}

// MFMA modulate (plane-major U in, per-o plane-major S out).
__global__ __launch_bounds__(256) void k_modulate5(const float2* __restrict__ Vb,
                                                   const uint* __restrict__ Uxp,
                                                   const uint* __restrict__ Uyp,
                                                   const uint* __restrict__ mp2,
                                                   uint* __restrict__ Sb2) {
    __shared__ u16 Uxs[32][72];
    __shared__ u16 Uys[32][72];
    __shared__ u16 mpT[2][64][72];
    __shared__ float2 Vt[32][24];
    const int tid = threadIdx.x;
    const int pt = blockIdx.x;
    const int b  = blockIdx.y;
    const int p0 = pt * 32;

    // stage U tile from c-pair planes: 32 rows x 32 planes, both x/y
    for (int i = tid; i < 1024; i += 256) {
        int cp = i >> 5, row = i & 31;
        uint vx = Uxp[((size_t)b * 32 + cp) * NP + p0 + row];
        uint vy = Uyp[((size_t)b * 32 + cp) * NP + p0 + row];
        *(uint*)&Uxs[row][cp * 2] = vx;
        *(uint*)&Uys[row][cp * 2] = vy;
    }
    {   // stage mphi k=0: full c-range
        int o = tid >> 2, seg = tid & 3;
        const uint4* src = (const uint4*)&mp2[(size_t)o * 32 + seg * 8];
        uint4 m0 = src[0], m1 = src[1];
        *(uint4*)&mpT[0][o][seg * 16] = m0;
        *(uint4*)&mpT[0][o][seg * 16 + 8] = m1;
    }
    for (int i = tid; i < 768; i += 256) {
        int pi = i / 24, kk = i - pi * 24;
        int pidx = p0 + pi; if (pidx > 4096) pidx = 4096;
        int r = (pidx == 4096) ? 1 : 2 * pidx;
        Vt[pi][kk] = Vb[(size_t)r * KK + kk];
    }
    __syncthreads();

    const int lane = tid & 63, w = tid >> 6;
    const int rt = w & 1, chalf = w >> 1;
    const int lrow = lane & 15, lk = lane >> 4;
    const u16* axp = &Uxs[rt * 16 + lrow][lk * 8];
    const u16* ayp = &Uys[rt * 16 + lrow][lk * 8];

    float Sx0[4] = {0.f, 0.f, 0.f, 0.f}, Sy0[4] = {0.f, 0.f, 0.f, 0.f};
    float Sx1[4] = {0.f, 0.f, 0.f, 0.f}, Sy1[4] = {0.f, 0.f, 0.f, 0.f};

    for (int k = 0; k < KK; ++k) {
        const int cur = k & 1;
        bf16x8 ax0 = *(const bf16x8*)(axp);
        bf16x8 ax1 = *(const bf16x8*)(axp + 32);
        bf16x8 ay0 = *(const bf16x8*)(ayp);
        bf16x8 ay1 = *(const bf16x8*)(ayp + 32);
        const u16* bp0 = &mpT[cur][chalf * 32 + lrow][lk * 8];
        const u16* bp1 = &mpT[cur][chalf * 32 + 16 + lrow][lk * 8];
        bf16x8 b00 = *(const bf16x8*)(bp0);
        bf16x8 b01 = *(const bf16x8*)(bp0 + 32);
        bf16x8 b10 = *(const bf16x8*)(bp1);
        bf16x8 b11 = *(const bf16x8*)(bp1 + 32);
        float2 v0 = Vt[rt * 16 + lk * 4 + 0][k];
        float2 v1 = Vt[rt * 16 + lk * 4 + 1][k];
        float2 v2 = Vt[rt * 16 + lk * 4 + 2][k];
        float2 v3 = Vt[rt * 16 + lk * 4 + 3][k];
        if (k + 1 < KK) {
            int o = tid >> 2, seg = tid & 3;
            const uint4* src = (const uint4*)&mp2[((size_t)(k + 1) * 64 + o) * 32 + seg * 8];
            uint4 m0 = src[0], m1 = src[1];
            *(uint4*)&mpT[cur ^ 1][o][seg * 16] = m0;
            *(uint4*)&mpT[cur ^ 1][o][seg * 16 + 8] = m1;
        }
        f32x4 z = {0.f, 0.f, 0.f, 0.f};
        f32x4 Wx0 = __builtin_amdgcn_mfma_f32_16x16x32_bf16(ax0, b00, z, 0, 0, 0);
        Wx0 = __builtin_amdgcn_mfma_f32_16x16x32_bf16(ax1, b01, Wx0, 0, 0, 0);
        f32x4 Wy0 = __builtin_amdgcn_mfma_f32_16x16x32_bf16(ay0, b00, z, 0, 0, 0);
        Wy0 = __builtin_amdgcn_mfma_f32_16x16x32_bf16(ay1, b01, Wy0, 0, 0, 0);
        f32x4 Wx1 = __builtin_amdgcn_mfma_f32_16x16x32_bf16(ax0, b10, z, 0, 0, 0);
        Wx1 = __builtin_amdgcn_mfma_f32_16x16x32_bf16(ax1, b11, Wx1, 0, 0, 0);
        f32x4 Wy1 = __builtin_amdgcn_mfma_f32_16x16x32_bf16(ay0, b10, z, 0, 0, 0);
        Wy1 = __builtin_amdgcn_mfma_f32_16x16x32_bf16(ay1, b11, Wy1, 0, 0, 0);
        Sx0[0] += v0.x * Wx0[0] - v0.y * Wy0[0];  Sy0[0] += v0.x * Wy0[0] + v0.y * Wx0[0];
        Sx0[1] += v1.x * Wx0[1] - v1.y * Wy0[1];  Sy0[1] += v1.x * Wy0[1] + v1.y * Wx0[1];
        Sx0[2] += v2.x * Wx0[2] - v2.y * Wy0[2];  Sy0[2] += v2.x * Wy0[2] + v2.y * Wx0[2];
        Sx0[3] += v3.x * Wx0[3] - v3.y * Wy0[3];  Sy0[3] += v3.x * Wy0[3] + v3.y * Wx0[3];
        Sx1[0] += v0.x * Wx1[0] - v0.y * Wy1[0];  Sy1[0] += v0.x * Wy1[0] + v0.y * Wx1[0];
        Sx1[1] += v1.x * Wx1[1] - v1.y * Wy1[1];  Sy1[1] += v1.x * Wy1[1] + v1.y * Wx1[1];
        Sx1[2] += v2.x * Wx1[2] - v2.y * Wy1[2];  Sy1[2] += v2.x * Wy1[2] + v2.y * Wx1[2];
        Sx1[3] += v3.x * Wx1[3] - v3.y * Wy1[3];  Sy1[3] += v3.x * Wy1[3] + v3.y * Wx1[3];
        __syncthreads();
    }
    const int rbase = rt * 16 + lk * 4;
    const int o0 = chalf * 32 + lrow;
    const size_t pl0 = ((size_t)b * 64 + o0) * NP + p0 + rbase;
    const size_t pl1 = ((size_t)b * 64 + o0 + 16) * NP + p0 + rbase;
#pragma unroll
    for (int j = 0; j < 4; ++j) {
        Sb2[pl0 + j] = pk(Sx0[j]) | (pk(Sy0[j]) << 16);
        Sb2[pl1 + j] = pk(Sx1[j]) | (pk(Sy1[j]) << 16);
    }
}

// Two output channels per inverse FFT; plane-major S in, plane-major deltas out.
__global__ __launch_bounds__(512) void k_ifft2(const uint* __restrict__ Sb2,
                                               float* __restrict__ deltas) {
    __shared__ float2 a[NN];
    __shared__ float2 twc[8192];
    const int b = blockIdx.x & 7, op = blockIdx.x >> 3;
    const int tid = threadIdx.x;
    const uint* s0 = &Sb2[((size_t)b * 64 + op * 2) * NP];
    const uint* s1 = &Sb2[((size_t)b * 64 + op * 2 + 1) * NP];
    for (int idx = tid; idx < 4097; idx += 512) {
        int r = (idx == 4096) ? 1 : 2 * idx;
        float2 A = unpk2(s0[idx]), B = unpk2(s1[idx]);
        a[r] = make_float2(A.x - B.y, A.y + B.x);
        int fn = br13(r);
        int q = br13((8192 - fn) & 8191);
        if (q != r) a[q] = make_float2(A.x + B.y, B.x - A.y);
    }
    build_tw<512>(twc);
    __syncthreads();
    fft_dit<512>(a, twc);
    float* d0 = &deltas[((size_t)b * 64 + op * 2) * LL];
    float* d1 = &deltas[((size_t)b * 64 + op * 2 + 1) * LL];
    for (int l = tid; l < LL; l += 512) {
        d0[l] = a[l].x;
        d1[l] = a[l].y;
    }
}

// deltas += AR-U (plane-major deltas; 128 l's per block -> contiguous RMW runs)
__global__ __launch_bounds__(256) void k_aru(const float* __restrict__ x,
                                             const float* __restrict__ m_u,
                                             float* __restrict__ deltas) {
    __shared__ float mu_s[64 * 193];
    __shared__ float xs[130 * 64];
    const int tid = threadIdx.x;
    const int b = blockIdx.x >> 5;
    const int l0 = (blockIdx.x & 31) * 128;
    for (int idx = tid; idx < 64 * 192; idx += 256) {
        int o = idx / 192;
        int rem = idx - o * 192;
        mu_s[o * 193 + rem] = m_u[idx];
    }
    for (int idx = tid; idx < 130 * 64; idx += 256) {
        int rr = idx >> 6, i = idx & 63;
        int gl = l0 - 2 + rr;
        xs[idx] = (gl >= 0) ? x[((size_t)b * LL + gl) * DD + i] : 0.f;
    }
    __syncthreads();
    const int o = tid & 63, lsub = tid >> 6;
    float* dp = &deltas[((size_t)b * 64 + o) * LL + l0 + lsub * 32];
    for (int lb = 0; lb < 32; ++lb) {
        int ll = lsub * 32 + lb;
        int r = ll + 2;
        float acc = 0.f;
#pragma unroll
        for (int i = 0; i < 64; ++i) {
            int mb = o * 193 + i * 3;
            acc += mu_s[mb]     * xs[r * 64 + i]
                 + mu_s[mb + 1] * xs[(r - 1) * 64 + i]
                 + mu_s[mb + 2] * xs[(r - 2) * 64 + i];
        }
        dp[lb] += acc;
    }
}

// First squaring with companion matrix built on the fly from m_y.
__global__ __launch_bounds__(256) void k_matsq1(const float* __restrict__ m_y,
                                                float* __restrict__ C) {
    int idx = blockIdx.x * 256 + threadIdx.x;
    int r = idx >> 7, c = idx & 127;
    if (r >= 64) { C[idx] = m_y[(r - 64) * 128 + c]; return; }
    float acc = (c < 64) ? m_y[r * 128 + 64 + c] : 0.f;
#pragma unroll
    for (int i = 0; i < 64; ++i) acc += m_y[r * 128 + i] * m_y[i * 128 + c];
    C[idx] = acc;
}

__global__ __launch_bounds__(256) void k_matsq(const float* __restrict__ A,
                                               float* __restrict__ C) {
    int idx = blockIdx.x * 256 + threadIdx.x;
    int r = idx >> 7, c = idx & 127;
    float acc = 0.f;
#pragma unroll
    for (int i = 0; i < 128; ++i) acc += A[r * 128 + i] * A[i * 128 + c];
    C[idx] = acc;
}

// ---- hierarchical boundary-scan helpers ----
__device__ __forceinline__ void load_rowhalf(const float* __restrict__ P, int r, int h,
                                             float* __restrict__ p) {
#pragma unroll
    for (int i4 = 0; i4 < 16; ++i4) {
        float4 v = *(const float4*)&P[r * 128 + h * 64 + i4 * 4];
        p[4 * i4] = v.x; p[4 * i4 + 1] = v.y; p[4 * i4 + 2] = v.z; p[4 * i4 + 3] = v.w;
    }
}
__device__ __forceinline__ float dot64(const float* __restrict__ p, const float* s) {
    float a0 = 0.f, a1 = 0.f, a2 = 0.f, a3 = 0.f;
#pragma unroll
    for (int i4 = 0; i4 < 16; ++i4) {
        float4 w = *(const float4*)&s[i4 * 4];
        a0 += p[4 * i4] * w.x;  a1 += p[4 * i4 + 1] * w.y;
        a2 += p[4 * i4 + 2] * w.z;  a3 += p[4 * i4 + 3] * w.w;
    }
    return (a0 + a1) + (a2 + a3);
}

// Generic affine scan: per block, zero-init scan over `count` inputs with matrix P.
__global__ __launch_bounds__(256, 1) void k_scan(const float* __restrict__ P,
                                                 const float* __restrict__ in,
                                                 float* __restrict__ partial,
                                                 float* __restrict__ terminal,
                                                 const int count) {
    const int bx = blockIdx.x;
    const int tid = threadIdx.x;
    const int r = tid & 127, h = tid >> 7;
    __shared__ __align__(16) float scur[128];
    __shared__ float pacc[256];
    float p[64];
    load_rowhalf(P, r, h, p);
    if (tid < 128) scur[tid] = 0.f;
    __syncthreads();
    const size_t base = (size_t)bx * count * 128;
    for (int k = 0; k < count; ++k) {
        if (tid < 128) partial[base + (size_t)k * 128 + tid] = scur[tid];
        pacc[tid] = dot64(p, &scur[h * 64]);
        __syncthreads();
        if (tid < 128) scur[tid] = pacc[tid] + pacc[tid + 128] + in[base + (size_t)k * 128 + tid];
        __syncthreads();
    }
    if (tid < 128) terminal[(size_t)bx * 128 + tid] = scur[tid];
}

// Generic fixup: out[k] = P^k * Sinit + q[k].
__global__ __launch_bounds__(256, 1) void k_fixupg(const float* __restrict__ P,
                                                   const float* __restrict__ Sinit,
                                                   const float* __restrict__ q,
                                                   float* __restrict__ out,
                                                   const int count) {
    const int bx = blockIdx.x;
    const int tid = threadIdx.x;
    const int r = tid & 127, h = tid >> 7;
    __shared__ __align__(16) float scur[128];
    __shared__ float pacc[256];
    float p[64];
    load_rowhalf(P, r, h, p);
    if (tid < 128) scur[tid] = Sinit[(size_t)bx * 128 + tid];
    __syncthreads();
    const size_t base = (size_t)bx * count * 128;
    for (int k = 0; k < count; ++k) {
        if (tid < 128) out[base + (size_t)k * 128 + tid] = scur[tid] + q[base + (size_t)k * 128 + tid];
        if (k == count - 1) break;
        pacc[tid] = dot64(p, &scur[h * 64]);
        __syncthreads();
        if (tid < 128) scur[tid] = pacc[tid] + pacc[tid + 128];
        __syncthreads();
    }
}

// Per-chunk local recurrence (CH=16 steps), 2-wave split; plane-major deltas.
__global__ __launch_bounds__(128, 1) void k_chunk_local(const float* __restrict__ deltas,
                                                        const float* __restrict__ m_y,
                                                        float* __restrict__ term) {
    const int b = blockIdx.x >> 8, j = blockIdx.x & 255;
    const int tid = threadIdx.x;
    const int o = tid & 63, h = tid >> 6;
    __shared__ __align__(16) float y1s[64];
    __shared__ __align__(16) float y2s[64];
    __shared__ float pacc[128];
    float m1[32], m2[32];
#pragma unroll
    for (int i4 = 0; i4 < 8; ++i4) {
        float4 v1 = *(const float4*)&m_y[o * 128 + h * 32 + i4 * 4];
        float4 v2 = *(const float4*)&m_y[o * 128 + 64 + h * 32 + i4 * 4];
        m1[4 * i4] = v1.x; m1[4 * i4 + 1] = v1.y; m1[4 * i4 + 2] = v1.z; m1[4 * i4 + 3] = v1.w;
        m2[4 * i4] = v2.x; m2[4 * i4 + 1] = v2.y; m2[4 * i4 + 2] = v2.z; m2[4 * i4 + 3] = v2.w;
    }
    if (tid < 64) { y1s[tid] = 0.f; y2s[tid] = 0.f; }
    __syncthreads();
    const float* dl = &deltas[((size_t)b * 64 + o) * LL + j * CH];
    for (int t = 0; t < CH; ++t) {
        float a0 = 0.f, a1 = 0.f, a2 = 0.f, a3 = 0.f;
#pragma unroll
        for (int i4 = 0; i4 < 8; ++i4) {
            float4 w1 = *(const float4*)&y1s[h * 32 + i4 * 4];
            float4 w2 = *(const float4*)&y2s[h * 32 + i4 * 4];
            a0 += m1[4 * i4] * w1.x + m2[4 * i4] * w2.x;
            a1 += m1[4 * i4 + 1] * w1.y + m2[4 * i4 + 1] * w2.y;
            a2 += m1[4 * i4 + 2] * w1.z + m2[4 * i4 + 2] * w2.z;
            a3 += m1[4 * i4 + 3] * w1.w + m2[4 * i4 + 3] * w2.w;
        }
        pacc[tid] = (a0 + a1) + (a2 + a3);
        __syncthreads();
        if (h == 0) {
            float outv = pacc[o] + pacc[o + 64] + dl[t];
            y2s[o] = y1s[o];
            y1s[o] = outv;
        }
        __syncthreads();
    }
    if (tid < 64) {
        term[((size_t)b * NCH + j) * 128 + o] = y1s[o];
        term[((size_t)b * NCH + j) * 128 + 64 + o] = y2s[o];
    }
}

// Per-chunk final recurrence with true initial states; writes row-major out.
__global__ __launch_bounds__(128, 1) void k_chunk_final(const float* __restrict__ deltas,
                                                        const float* __restrict__ m_y,
                                                        const float* __restrict__ sstate,
                                                        float* __restrict__ out) {
    const int b = blockIdx.x >> 8, j = blockIdx.x & 255;
    const int tid = threadIdx.x;
    const int o = tid & 63, h = tid >> 6;
    __shared__ __align__(16) float y1s[64];
    __shared__ __align__(16) float y2s[64];
    __shared__ float pacc[128];
    float m1[32], m2[32];
#pragma unroll
    for (int i4 = 0; i4 < 8; ++i4) {
        float4 v1 = *(const float4*)&m_y[o * 128 + h * 32 + i4 * 4];
        float4 v2 = *(const float4*)&m_y[o * 128 + 64 + h * 32 + i4 * 4];
        m1[4 * i4] = v1.x; m1[4 * i4 + 1] = v1.y; m1[4 * i4 + 2] = v1.z; m1[4 * i4 + 3] = v1.w;
        m2[4 * i4] = v2.x; m2[4 * i4 + 1] = v2.y; m2[4 * i4 + 2] = v2.z; m2[4 * i4 + 3] = v2.w;
    }
    if (tid < 64) {
        y1s[tid] = sstate[((size_t)b * NCH + j) * 128 + tid];
        y2s[tid] = sstate[((size_t)b * NCH + j) * 128 + 64 + tid];
    }
    __syncthreads();
    const float* dl = &deltas[((size_t)b * 64 + o) * LL + j * CH];
    const size_t obase = (((size_t)b * LL) + j * CH) * DD + o;
    for (int t = 0; t < CH; ++t) {
        float a0 = 0.f, a1 = 0.f, a2 = 0.f, a3 = 0.f;
#pragma unroll
        for (int i4 = 0; i4 < 8; ++i4) {
            float4 w1 = *(const float4*)&y1s[h * 32 + i4 * 4];
            float4 w2 = *(const float4*)&y2s[h * 32 + i4 * 4];
            a0 += m1[4 * i4] * w1.x + m2[4 * i4] * w2.x;
            a1 += m1[4 * i4 + 1] * w1.y + m2[4 * i4 + 1] * w2.y;
            a2 += m1[4 * i4 + 2] * w1.z + m2[4 * i4 + 2] * w2.z;
            a3 += m1[4 * i4 + 3] * w1.w + m2[4 * i4 + 3] * w2.w;
        }
        pacc[tid] = (a0 + a1) + (a2 + a3);
        __syncthreads();
        if (h == 0) {
            float outv = pacc[o] + pacc[o + 64] + dl[t];
            out[obase + (size_t)t * DD] = outv;
            y2s[o] = y1s[o];
            y1s[o] = outv;
        }
        __syncthreads();
    }
}

extern "C" void kernel_launch(void* const* d_in, const int* in_sizes, int n_in,
                              void* d_out, int out_size, void* d_ws, size_t ws_size,
                              hipStream_t stream) {
    const float* x        = (const float*)d_in[0];
    const float* m_y      = (const float*)d_in[1];
    const float* m_u      = (const float*)d_in[2];
    const float* m_phi    = (const float*)d_in[3];
    const float* eig_vals = (const float*)d_in[4];
    const float* eig_vecs = (const float*)d_in[5];
    float* out = (float*)d_out;

    char* ws = (char*)d_ws;
    size_t off = 0;
    auto alloc = [&](size_t bytes) -> void* {
        void* p = ws + off;
        off += (bytes + 255) & ~(size_t)255;
        return p;
    };
    float2* Vb   = (float2*)alloc((size_t)NN * KK * sizeof(float2));          // 1.6 MB
    uint*   Uxp  = (uint*)alloc((size_t)BB * 32 * NP * sizeof(uint));         // 4.2 MB
    uint*   Uyp  = (uint*)alloc((size_t)BB * 32 * NP * sizeof(uint));         // 4.2 MB
    uint*   Sb2  = (uint*)alloc((size_t)BB * 64 * NP * sizeof(uint));         // 8.5 MB
    float*  deltas = (float*)alloc((size_t)BB * 64 * LL * sizeof(float));     // 8.4 MB (plane-major)
    uint*   mp2  = (uint*)alloc((size_t)KK * 64 * 32 * sizeof(uint));         // 0.2 MB
    float*  mats = (float*)alloc((size_t)5 * 128 * 128 * sizeof(float));
    float*  term = (float*)alloc((size_t)BB * NCH * 128 * sizeof(float));
    float*  sst  = (float*)alloc((size_t)BB * NCH * 128 * sizeof(float));
    float*  qbuf = (float*)alloc((size_t)BB * NCH * 128 * sizeof(float));
    float*  Qg   = (float*)alloc((size_t)BB * 32 * 128 * sizeof(float));
    float*  q2   = (float*)alloc((size_t)BB * 32 * 128 * sizeof(float));
    float*  Sgt  = (float*)alloc((size_t)BB * 32 * 128 * sizeof(float));
    float*  Qsg  = (float*)alloc((size_t)BB * 4 * 128 * sizeof(float));
    float*  Ssg  = (float*)alloc((size_t)BB * 4 * 128 * sizeof(float));
    float*  dmy  = (float*)alloc((size_t)8 * 128 * sizeof(float));

    k_pack<<<dim3(192), dim3(256), 0, stream>>>(m_phi, mp2);
    k_fft_filters<<<dim3(24), dim3(256), 0, stream>>>(eig_vals, eig_vecs, Vb);
    k_fft_x2<<<dim3(256), dim3(512), 0, stream>>>(x, Uxp, Uyp);

    float* T1    = mats;
    float* T2    = mats + 16384;
    float* P16   = mats + 32768;
    float* P128  = mats + 49152;
    float* P1024 = mats + 65536;
    k_matsq1<<<dim3(64), dim3(256), 0, stream>>>(m_y, T1);   // M^2
    k_matsq<<<dim3(64), dim3(256), 0, stream>>>(T1, T2);     // M^4
    k_matsq<<<dim3(64), dim3(256), 0, stream>>>(T2, T1);     // M^8
    k_matsq<<<dim3(64), dim3(256), 0, stream>>>(T1, P16);    // M^16
    k_matsq<<<dim3(64), dim3(256), 0, stream>>>(P16, T1);    // M^32
    k_matsq<<<dim3(64), dim3(256), 0, stream>>>(T1, T2);     // M^64
    k_matsq<<<dim3(64), dim3(256), 0, stream>>>(T2, P128);   // M^128
    k_matsq<<<dim3(64), dim3(256), 0, stream>>>(P128, T1);   // M^256
    k_matsq<<<dim3(64), dim3(256), 0, stream>>>(T1, T2);     // M^512
    k_matsq<<<dim3(64), dim3(256), 0, stream>>>(T2, P1024);  // M^1024

    k_modulate5<<<dim3(129, 8), dim3(256), 0, stream>>>(Vb, Uxp, Uyp, mp2, Sb2);
    k_ifft2<<<dim3(256), dim3(512), 0, stream>>>(Sb2, deltas);
    k_aru<<<dim3(256), dim3(256), 0, stream>>>(x, m_u, deltas);

    k_chunk_local<<<dim3(2048), dim3(128), 0, stream>>>(deltas, m_y, term);
    k_scan<<<dim3(256), dim3(256), 0, stream>>>(P16, term, qbuf, Qg, 8);
    k_scan<<<dim3(32), dim3(256), 0, stream>>>(P128, Qg, q2, Qsg, 8);
    k_scan<<<dim3(8), dim3(256), 0, stream>>>(P1024, Qsg, Ssg, dmy, 4);
    k_fixupg<<<dim3(32), dim3(256), 0, stream>>>(P128, Ssg, q2, Sgt, 8);
    k_fixupg<<<dim3(256), dim3(256), 0, stream>>>(P16, Sgt, qbuf, sst, 8);
    k_chunk_final<<<dim3(2048), dim3(128), 0, stream>>>(deltas, m_y, sst, out);
}

// Round 12
// 242.452 us; speedup vs baseline: 13.8464x; 1.1466x over previous
//
#include <hip/hip_runtime.h>
#include <math.h>

#define BB 8
#define LL 4096
#define DD 64
#define KK 24
#define KT 27       // 24 spectral filters + 3 AR-U taps
#define NN 8192
#define LOGN 13
#define NP 4128     // padded half-spectrum rows per batch (129 tiles * 32)
#define NCH 256     // chunks per batch
#define CH 16       // timesteps per chunk

typedef unsigned int uint;
typedef unsigned short u16;
typedef __attribute__((ext_vector_type(8))) short bf16x8;
typedef __attribute__((ext_vector_type(4))) float f32x4;

__device__ __forceinline__ float bfl(uint u) {
    union { uint u; float f; } v; v.u = u << 16; return v.f;
}
__device__ __forceinline__ float bfh(uint u) {
    union { uint u; float f; } v; v.u = u & 0xFFFF0000u; return v.f;
}
__device__ __forceinline__ uint pk(float x) {
    union { float f; uint u; } v; v.f = x;
    return (v.u + 0x7FFFu + ((v.u >> 16) & 1u)) >> 16;
}
__device__ __forceinline__ float2 unpk2(uint u) {
    return make_float2(bfl(u), bfh(u));
}
__device__ __forceinline__ int br13(int v) { return (int)(__brev((uint)v) >> 19); }

// ---------------- FFT primitives with LDS twiddle table ----------------
template<int NT>
__device__ __forceinline__ void build_tw(float2* twc) {
    const int tid = threadIdx.x;
    for (int i = tid; i < 8192; i += NT) {
        if (i == 0) { twc[0] = make_float2(1.f, 0.f); continue; }
        int lh = 31 - __builtin_clz((uint)i);
        int j = i - (1 << lh);
        float ang = -6.28318530717958647692f * (float)j / (float)(2 << lh);
        float sn, cs;
        __sincosf(ang, &sn, &cs);
        twc[i] = make_float2(cs, sn);
    }
}

template<int NT>
__device__ __forceinline__ void fft_dif(float2* a, const float2* __restrict__ twc) {
    const int tid = threadIdx.x;
    for (int lh = LOGN - 1; lh >= 0; --lh) {
        const int half = 1 << lh;
#pragma unroll
        for (int bb = 0; bb < NN / 2 / NT; ++bb) {
            int t = tid + bb * NT;
            int j = t & (half - 1);
            int i0 = ((t >> lh) << (lh + 1)) + j;
            float2 u = a[i0], v = a[i0 + half];
            float2 w = twc[half + j];
            float cs = w.x, sn = w.y;
            float dx = u.x - v.x, dy = u.y - v.y;
            a[i0] = make_float2(u.x + v.x, u.y + v.y);
            a[i0 + half] = make_float2(dx * cs - dy * sn, dx * sn + dy * cs);
        }
        __syncthreads();
    }
}

template<int NT>
__device__ __forceinline__ void fft_dit(float2* a, const float2* __restrict__ twc) {
    const int tid = threadIdx.x;
    for (int lh = 0; lh < LOGN; ++lh) {
        const int half = 1 << lh;
#pragma unroll
        for (int bb = 0; bb < NN / 2 / NT; ++bb) {
            int t = tid + bb * NT;
            int j = t & (half - 1);
            int i0 = ((t >> lh) << (lh + 1)) + j;
            float2 u = a[i0], v = a[i0 + half];
            float2 w = twc[half + j];
            float cs = w.x, sn = -w.y;      // conjugate for inverse
            float wx = v.x * cs - v.y * sn;
            float wy = v.x * sn + v.y * cs;
            a[i0] = make_float2(u.x + wx, u.y + wy);
            a[i0 + half] = make_float2(u.x - wx, u.y - wy);
        }
        __syncthreads();
    }
}

// ---------------- kernels ----------------

// Pack 27 B-slabs, o-major bf16 c-pair: slabs 0..23 = m_phi[k], 24..26 = m_u[:,:,ku].
__global__ __launch_bounds__(256) void k_pack(const float* __restrict__ mphi,
                                              const float* __restrict__ mu,
                                              uint* __restrict__ mp2) {
    int idx = blockIdx.x * 256 + threadIdx.x;
    if (idx >= KT * 2048) return;
    int k = idx >> 11;
    int rem = idx & 2047;
    int o = rem >> 5, cp = rem & 31;
    int c = cp * 2;
    uint v;
    if (k < KK) {
        v = pk(mphi[(k * 64 + c) * 64 + o]) | (pk(mphi[(k * 64 + c + 1) * 64 + o]) << 16);
    } else {
        int ku = k - KK;
        v = pk(mu[(o * 64 + c) * 3 + ku]) | (pk(mu[(o * 64 + c + 1) * 3 + ku]) << 16);
    }
    mp2[idx] = v;
}

// V[f,k] = FFT(eig_vecs[:,k] * lambda_k^0.25 / N), bit-reversed bins, fp32
__global__ __launch_bounds__(256) void k_fft_filters(const float* __restrict__ eig_vals,
                                                     const float* __restrict__ eig_vecs,
                                                     float2* __restrict__ Vb) {
    __shared__ float2 a[NN];
    __shared__ float2 twc[8192];
    const int k = blockIdx.x, tid = threadIdx.x;
    const float alpha = powf(eig_vals[k], 0.25f) * (1.0f / (float)NN);
    for (int t = tid; t < LL; t += 256)
        a[t] = make_float2(eig_vecs[t * KK + k] * alpha, 0.f);
    for (int t = LL + tid; t < NN; t += 256)
        a[t] = make_float2(0.f, 0.f);
    build_tw<256>(twc);
    __syncthreads();
    fft_dif<256>(a, twc);
    for (int r = tid; r < NN; r += 256)
        Vb[(size_t)r * KK + k] = a[r];
}

// Two real channels per complex FFT: z = x[:,c] + i x[:,c+1]. Plane-major U out.
__global__ __launch_bounds__(512) void k_fft_x2(const float* __restrict__ x,
                                                uint* __restrict__ Uxp,
                                                uint* __restrict__ Uyp) {
    __shared__ float2 a[NN];
    __shared__ float2 twc[8192];
    const int b = blockIdx.x & 7, cp = blockIdx.x >> 3;
    const int tid = threadIdx.x;
    for (int l = tid; l < LL; l += 512)
        a[l] = *(const float2*)&x[((size_t)b * LL + l) * DD + 2 * cp];
    for (int l = LL + tid; l < NN; l += 512)
        a[l] = make_float2(0.f, 0.f);
    build_tw<512>(twc);
    __syncthreads();
    fft_dif<512>(a, twc);
    const size_t plane = ((size_t)b * 32 + cp) * NP;
    for (int idx = tid; idx < 4097; idx += 512) {
        int r = (idx == 4096) ? 1 : 2 * idx;
        int fn = br13(r);
        int q = br13((8192 - fn) & 8191);
        float2 Z = a[r], W = a[q];
        float ucx = 0.5f * (Z.x + W.x), ucy = 0.5f * (Z.y - W.y);
        float upx = 0.5f * (Z.y + W.y), upy = 0.5f * (W.x - Z.x);
        Uxp[plane + idx] = pk(ucx) | (pk(upx) << 16);
        Uyp[plane + idx] = pk(ucy) | (pk(upy) << 16);
    }
}

// MFMA modulate over 27 slabs (24 spectral filters + 3 AR-U taps with phase scales).
__global__ __launch_bounds__(256) void k_modulate5(const float2* __restrict__ Vb,
                                                   const uint* __restrict__ Uxp,
                                                   const uint* __restrict__ Uyp,
                                                   const uint* __restrict__ mp2,
                                                   uint* __restrict__ Sb2) {
    __shared__ u16 Uxs[32][72];
    __shared__ u16 Uys[32][72];
    __shared__ u16 mpT[2][64][72];
    __shared__ float2 Vt[32][28];
    const int tid = threadIdx.x;
    const int pt = blockIdx.x;
    const int b  = blockIdx.y;
    const int p0 = pt * 32;

    // stage U tile from c-pair planes: 32 rows x 32 planes, both x/y
    for (int i = tid; i < 1024; i += 256) {
        int cp = i >> 5, row = i & 31;
        uint vx = Uxp[((size_t)b * 32 + cp) * NP + p0 + row];
        uint vy = Uyp[((size_t)b * 32 + cp) * NP + p0 + row];
        *(uint*)&Uxs[row][cp * 2] = vx;
        *(uint*)&Uys[row][cp * 2] = vy;
    }
    {   // stage B slab k=0: full c-range
        int o = tid >> 2, seg = tid & 3;
        const uint4* src = (const uint4*)&mp2[(size_t)o * 32 + seg * 8];
        uint4 m0 = src[0], m1 = src[1];
        *(uint4*)&mpT[0][o][seg * 16] = m0;
        *(uint4*)&mpT[0][o][seg * 16 + 8] = m1;
    }
    for (int i = tid; i < 768; i += 256) {   // stage V (32 pos x 24 k)
        int pi = i / 24, kk = i - pi * 24;
        int pidx = p0 + pi; if (pidx > 4096) pidx = 4096;
        int r = (pidx == 4096) ? 1 : 2 * pidx;
        Vt[pi][kk] = Vb[(size_t)r * KK + kk];
    }
    for (int pi = tid; pi < 32; pi += 256) { // AR-U phase scales e^{-i*f*ku*2pi/N}/N
        int pidx = p0 + pi; if (pidx > 4096) pidx = 4096;
        int r = (pidx == 4096) ? 1 : 2 * pidx;
        int f = br13(r);
        const float invN = 1.f / 8192.f;
        float ph = -6.28318530717958647692f * (float)f * invN;
        float s1, c1, s2, c2;
        __sincosf(ph, &s1, &c1);
        __sincosf(2.f * ph, &s2, &c2);
        Vt[pi][24] = make_float2(invN, 0.f);
        Vt[pi][25] = make_float2(c1 * invN, s1 * invN);
        Vt[pi][26] = make_float2(c2 * invN, s2 * invN);
    }
    __syncthreads();

    const int lane = tid & 63, w = tid >> 6;
    const int rt = w & 1, chalf = w >> 1;
    const int lrow = lane & 15, lk = lane >> 4;
    const u16* axp = &Uxs[rt * 16 + lrow][lk * 8];
    const u16* ayp = &Uys[rt * 16 + lrow][lk * 8];

    float Sx0[4] = {0.f, 0.f, 0.f, 0.f}, Sy0[4] = {0.f, 0.f, 0.f, 0.f};
    float Sx1[4] = {0.f, 0.f, 0.f, 0.f}, Sy1[4] = {0.f, 0.f, 0.f, 0.f};

    for (int k = 0; k < KT; ++k) {
        const int cur = k & 1;
        bf16x8 ax0 = *(const bf16x8*)(axp);
        bf16x8 ax1 = *(const bf16x8*)(axp + 32);
        bf16x8 ay0 = *(const bf16x8*)(ayp);
        bf16x8 ay1 = *(const bf16x8*)(ayp + 32);
        const u16* bp0 = &mpT[cur][chalf * 32 + lrow][lk * 8];
        const u16* bp1 = &mpT[cur][chalf * 32 + 16 + lrow][lk * 8];
        bf16x8 b00 = *(const bf16x8*)(bp0);
        bf16x8 b01 = *(const bf16x8*)(bp0 + 32);
        bf16x8 b10 = *(const bf16x8*)(bp1);
        bf16x8 b11 = *(const bf16x8*)(bp1 + 32);
        float2 v0 = Vt[rt * 16 + lk * 4 + 0][k];
        float2 v1 = Vt[rt * 16 + lk * 4 + 1][k];
        float2 v2 = Vt[rt * 16 + lk * 4 + 2][k];
        float2 v3 = Vt[rt * 16 + lk * 4 + 3][k];
        if (k + 1 < KT) {
            int o = tid >> 2, seg = tid & 3;
            const uint4* src = (const uint4*)&mp2[((size_t)(k + 1) * 64 + o) * 32 + seg * 8];
            uint4 m0 = src[0], m1 = src[1];
            *(uint4*)&mpT[cur ^ 1][o][seg * 16] = m0;
            *(uint4*)&mpT[cur ^ 1][o][seg * 16 + 8] = m1;
        }
        f32x4 z = {0.f, 0.f, 0.f, 0.f};
        f32x4 Wx0 = __builtin_amdgcn_mfma_f32_16x16x32_bf16(ax0, b00, z, 0, 0, 0);
        Wx0 = __builtin_amdgcn_mfma_f32_16x16x32_bf16(ax1, b01, Wx0, 0, 0, 0);
        f32x4 Wy0 = __builtin_amdgcn_mfma_f32_16x16x32_bf16(ay0, b00, z, 0, 0, 0);
        Wy0 = __builtin_amdgcn_mfma_f32_16x16x32_bf16(ay1, b01, Wy0, 0, 0, 0);
        f32x4 Wx1 = __builtin_amdgcn_mfma_f32_16x16x32_bf16(ax0, b10, z, 0, 0, 0);
        Wx1 = __builtin_amdgcn_mfma_f32_16x16x32_bf16(ax1, b11, Wx1, 0, 0, 0);
        f32x4 Wy1 = __builtin_amdgcn_mfma_f32_16x16x32_bf16(ay0, b10, z, 0, 0, 0);
        Wy1 = __builtin_amdgcn_mfma_f32_16x16x32_bf16(ay1, b11, Wy1, 0, 0, 0);
        Sx0[0] += v0.x * Wx0[0] - v0.y * Wy0[0];  Sy0[0] += v0.x * Wy0[0] + v0.y * Wx0[0];
        Sx0[1] += v1.x * Wx0[1] - v1.y * Wy0[1];  Sy0[1] += v1.x * Wy0[1] + v1.y * Wx0[1];
        Sx0[2] += v2.x * Wx0[2] - v2.y * Wy0[2];  Sy0[2] += v2.x * Wy0[2] + v2.y * Wx0[2];
        Sx0[3] += v3.x * Wx0[3] - v3.y * Wy0[3];  Sy0[3] += v3.x * Wy0[3] + v3.y * Wx0[3];
        Sx1[0] += v0.x * Wx1[0] - v0.y * Wy1[0];  Sy1[0] += v0.x * Wy1[0] + v0.y * Wx1[0];
        Sx1[1] += v1.x * Wx1[1] - v1.y * Wy1[1];  Sy1[1] += v1.x * Wy1[1] + v1.y * Wx1[1];
        Sx1[2] += v2.x * Wx1[2] - v2.y * Wy1[2];  Sy1[2] += v2.x * Wy1[2] + v2.y * Wx1[2];
        Sx1[3] += v3.x * Wx1[3] - v3.y * Wy1[3];  Sy1[3] += v3.x * Wy1[3] + v3.y * Wx1[3];
        __syncthreads();
    }
    const int rbase = rt * 16 + lk * 4;
    const int o0 = chalf * 32 + lrow;
    const size_t pl0 = ((size_t)b * 64 + o0) * NP + p0 + rbase;
    const size_t pl1 = ((size_t)b * 64 + o0 + 16) * NP + p0 + rbase;
#pragma unroll
    for (int j = 0; j < 4; ++j) {
        Sb2[pl0 + j] = pk(Sx0[j]) | (pk(Sy0[j]) << 16);
        Sb2[pl1 + j] = pk(Sx1[j]) | (pk(Sy1[j]) << 16);
    }
}

// Two output channels per inverse FFT; plane-major S in, plane-major deltas out.
__global__ __launch_bounds__(512) void k_ifft2(const uint* __restrict__ Sb2,
                                               float* __restrict__ deltas) {
    __shared__ float2 a[NN];
    __shared__ float2 twc[8192];
    const int b = blockIdx.x & 7, op = blockIdx.x >> 3;
    const int tid = threadIdx.x;
    const uint* s0 = &Sb2[((size_t)b * 64 + op * 2) * NP];
    const uint* s1 = &Sb2[((size_t)b * 64 + op * 2 + 1) * NP];
    for (int idx = tid; idx < 4097; idx += 512) {
        int r = (idx == 4096) ? 1 : 2 * idx;
        float2 A = unpk2(s0[idx]), B = unpk2(s1[idx]);
        a[r] = make_float2(A.x - B.y, A.y + B.x);
        int fn = br13(r);
        int q = br13((8192 - fn) & 8191);
        if (q != r) a[q] = make_float2(A.x + B.y, B.x - A.y);
    }
    build_tw<512>(twc);
    __syncthreads();
    fft_dit<512>(a, twc);
    float* d0 = &deltas[((size_t)b * 64 + op * 2) * LL];
    float* d1 = &deltas[((size_t)b * 64 + op * 2 + 1) * LL];
    for (int l = tid; l < LL; l += 512) {
        d0[l] = a[l].x;
        d1[l] = a[l].y;
    }
}

// First squaring with companion matrix built on the fly from m_y.
__global__ __launch_bounds__(256) void k_matsq1(const float* __restrict__ m_y,
                                                float* __restrict__ C) {
    int idx = blockIdx.x * 256 + threadIdx.x;
    int r = idx >> 7, c = idx & 127;
    if (r >= 64) { C[idx] = m_y[(r - 64) * 128 + c]; return; }
    float acc = (c < 64) ? m_y[r * 128 + 64 + c] : 0.f;
#pragma unroll
    for (int i = 0; i < 64; ++i) acc += m_y[r * 128 + i] * m_y[i * 128 + c];
    C[idx] = acc;
}

__global__ __launch_bounds__(256) void k_matsq(const float* __restrict__ A,
                                               float* __restrict__ C) {
    int idx = blockIdx.x * 256 + threadIdx.x;
    int r = idx >> 7, c = idx & 127;
    float acc = 0.f;
#pragma unroll
    for (int i = 0; i < 128; ++i) acc += A[r * 128 + i] * A[i * 128 + c];
    C[idx] = acc;
}

// ---- hierarchical boundary-scan helpers ----
__device__ __forceinline__ void load_rowhalf(const float* __restrict__ P, int r, int h,
                                             float* __restrict__ p) {
#pragma unroll
    for (int i4 = 0; i4 < 16; ++i4) {
        float4 v = *(const float4*)&P[r * 128 + h * 64 + i4 * 4];
        p[4 * i4] = v.x; p[4 * i4 + 1] = v.y; p[4 * i4 + 2] = v.z; p[4 * i4 + 3] = v.w;
    }
}
__device__ __forceinline__ float dot64(const float* __restrict__ p, const float* s) {
    float a0 = 0.f, a1 = 0.f, a2 = 0.f, a3 = 0.f;
#pragma unroll
    for (int i4 = 0; i4 < 16; ++i4) {
        float4 w = *(const float4*)&s[i4 * 4];
        a0 += p[4 * i4] * w.x;  a1 += p[4 * i4 + 1] * w.y;
        a2 += p[4 * i4 + 2] * w.z;  a3 += p[4 * i4 + 3] * w.w;
    }
    return (a0 + a1) + (a2 + a3);
}

// Generic affine scan: per block, zero-init scan over `count` inputs with matrix P.
__global__ __launch_bounds__(256, 1) void k_scan(const float* __restrict__ P,
                                                 const float* __restrict__ in,
                                                 float* __restrict__ partial,
                                                 float* __restrict__ terminal,
                                                 const int count) {
    const int bx = blockIdx.x;
    const int tid = threadIdx.x;
    const int r = tid & 127, h = tid >> 7;
    __shared__ __align__(16) float scur[128];
    __shared__ float pacc[256];
    float p[64];
    load_rowhalf(P, r, h, p);
    if (tid < 128) scur[tid] = 0.f;
    __syncthreads();
    const size_t base = (size_t)bx * count * 128;
    for (int k = 0; k < count; ++k) {
        if (tid < 128) partial[base + (size_t)k * 128 + tid] = scur[tid];
        pacc[tid] = dot64(p, &scur[h * 64]);
        __syncthreads();
        if (tid < 128) scur[tid] = pacc[tid] + pacc[tid + 128] + in[base + (size_t)k * 128 + tid];
        __syncthreads();
    }
    if (tid < 128) terminal[(size_t)bx * 128 + tid] = scur[tid];
}

// Generic fixup: out[k] = P^k * Sinit + q[k].
__global__ __launch_bounds__(256, 1) void k_fixupg(const float* __restrict__ P,
                                                   const float* __restrict__ Sinit,
                                                   const float* __restrict__ q,
                                                   float* __restrict__ out,
                                                   const int count) {
    const int bx = blockIdx.x;
    const int tid = threadIdx.x;
    const int r = tid & 127, h = tid >> 7;
    __shared__ __align__(16) float scur[128];
    __shared__ float pacc[256];
    float p[64];
    load_rowhalf(P, r, h, p);
    if (tid < 128) scur[tid] = Sinit[(size_t)bx * 128 + tid];
    __syncthreads();
    const size_t base = (size_t)bx * count * 128;
    for (int k = 0; k < count; ++k) {
        if (tid < 128) out[base + (size_t)k * 128 + tid] = scur[tid] + q[base + (size_t)k * 128 + tid];
        if (k == count - 1) break;
        pacc[tid] = dot64(p, &scur[h * 64]);
        __syncthreads();
        if (tid < 128) scur[tid] = pacc[tid] + pacc[tid + 128];
        __syncthreads();
    }
}

// Per-chunk local recurrence (CH=16 steps), 2-wave split; plane-major deltas.
__global__ __launch_bounds__(128, 1) void k_chunk_local(const float* __restrict__ deltas,
                                                        const float* __restrict__ m_y,
                                                        float* __restrict__ term) {
    const int b = blockIdx.x >> 8, j = blockIdx.x & 255;
    const int tid = threadIdx.x;
    const int o = tid & 63, h = tid >> 6;
    __shared__ __align__(16) float y1s[64];
    __shared__ __align__(16) float y2s[64];
    __shared__ float pacc[128];
    float m1[32], m2[32];
#pragma unroll
    for (int i4 = 0; i4 < 8; ++i4) {
        float4 v1 = *(const float4*)&m_y[o * 128 + h * 32 + i4 * 4];
        float4 v2 = *(const float4*)&m_y[o * 128 + 64 + h * 32 + i4 * 4];
        m1[4 * i4] = v1.x; m1[4 * i4 + 1] = v1.y; m1[4 * i4 + 2] = v1.z; m1[4 * i4 + 3] = v1.w;
        m2[4 * i4] = v2.x; m2[4 * i4 + 1] = v2.y; m2[4 * i4 + 2] = v2.z; m2[4 * i4 + 3] = v2.w;
    }
    if (tid < 64) { y1s[tid] = 0.f; y2s[tid] = 0.f; }
    __syncthreads();
    const float* dl = &deltas[((size_t)b * 64 + o) * LL + j * CH];
    for (int t = 0; t < CH; ++t) {
        float a0 = 0.f, a1 = 0.f, a2 = 0.f, a3 = 0.f;
#pragma unroll
        for (int i4 = 0; i4 < 8; ++i4) {
            float4 w1 = *(const float4*)&y1s[h * 32 + i4 * 4];
            float4 w2 = *(const float4*)&y2s[h * 32 + i4 * 4];
            a0 += m1[4 * i4] * w1.x + m2[4 * i4] * w2.x;
            a1 += m1[4 * i4 + 1] * w1.y + m2[4 * i4 + 1] * w2.y;
            a2 += m1[4 * i4 + 2] * w1.z + m2[4 * i4 + 2] * w2.z;
            a3 += m1[4 * i4 + 3] * w1.w + m2[4 * i4 + 3] * w2.w;
        }
        pacc[tid] = (a0 + a1) + (a2 + a3);
        __syncthreads();
        if (h == 0) {
            float outv = pacc[o] + pacc[o + 64] + dl[t];
            y2s[o] = y1s[o];
            y1s[o] = outv;
        }
        __syncthreads();
    }
    if (tid < 64) {
        term[((size_t)b * NCH + j) * 128 + o] = y1s[o];
        term[((size_t)b * NCH + j) * 128 + 64 + o] = y2s[o];
    }
}

// Per-chunk final recurrence with true initial states; writes row-major out.
__global__ __launch_bounds__(128, 1) void k_chunk_final(const float* __restrict__ deltas,
                                                        const float* __restrict__ m_y,
                                                        const float* __restrict__ sstate,
                                                        float* __restrict__ out) {
    const int b = blockIdx.x >> 8, j = blockIdx.x & 255;
    const int tid = threadIdx.x;
    const int o = tid & 63, h = tid >> 6;
    __shared__ __align__(16) float y1s[64];
    __shared__ __align__(16) float y2s[64];
    __shared__ float pacc[128];
    float m1[32], m2[32];
#pragma unroll
    for (int i4 = 0; i4 < 8; ++i4) {
        float4 v1 = *(const float4*)&m_y[o * 128 + h * 32 + i4 * 4];
        float4 v2 = *(const float4*)&m_y[o * 128 + 64 + h * 32 + i4 * 4];
        m1[4 * i4] = v1.x; m1[4 * i4 + 1] = v1.y; m1[4 * i4 + 2] = v1.z; m1[4 * i4 + 3] = v1.w;
        m2[4 * i4] = v2.x; m2[4 * i4 + 1] = v2.y; m2[4 * i4 + 2] = v2.z; m2[4 * i4 + 3] = v2.w;
    }
    if (tid < 64) {
        y1s[tid] = sstate[((size_t)b * NCH + j) * 128 + tid];
        y2s[tid] = sstate[((size_t)b * NCH + j) * 128 + 64 + tid];
    }
    __syncthreads();
    const float* dl = &deltas[((size_t)b * 64 + o) * LL + j * CH];
    const size_t obase = (((size_t)b * LL) + j * CH) * DD + o;
    for (int t = 0; t < CH; ++t) {
        float a0 = 0.f, a1 = 0.f, a2 = 0.f, a3 = 0.f;
#pragma unroll
        for (int i4 = 0; i4 < 8; ++i4) {
            float4 w1 = *(const float4*)&y1s[h * 32 + i4 * 4];
            float4 w2 = *(const float4*)&y2s[h * 32 + i4 * 4];
            a0 += m1[4 * i4] * w1.x + m2[4 * i4] * w2.x;
            a1 += m1[4 * i4 + 1] * w1.y + m2[4 * i4 + 1] * w2.y;
            a2 += m1[4 * i4 + 2] * w1.z + m2[4 * i4 + 2] * w2.z;
            a3 += m1[4 * i4 + 3] * w1.w + m2[4 * i4 + 3] * w2.w;
        }
        pacc[tid] = (a0 + a1) + (a2 + a3);
        __syncthreads();
        if (h == 0) {
            float outv = pacc[o] + pacc[o + 64] + dl[t];
            out[obase + (size_t)t * DD] = outv;
            y2s[o] = y1s[o];
            y1s[o] = outv;
        }
        __syncthreads();
    }
}

extern "C" void kernel_launch(void* const* d_in, const int* in_sizes, int n_in,
                              void* d_out, int out_size, void* d_ws, size_t ws_size,
                              hipStream_t stream) {
    const float* x        = (const float*)d_in[0];
    const float* m_y      = (const float*)d_in[1];
    const float* m_u      = (const float*)d_in[2];
    const float* m_phi    = (const float*)d_in[3];
    const float* eig_vals = (const float*)d_in[4];
    const float* eig_vecs = (const float*)d_in[5];
    float* out = (float*)d_out;

    char* ws = (char*)d_ws;
    size_t off = 0;
    auto alloc = [&](size_t bytes) -> void* {
        void* p = ws + off;
        off += (bytes + 255) & ~(size_t)255;
        return p;
    };
    float2* Vb   = (float2*)alloc((size_t)NN * KK * sizeof(float2));          // 1.6 MB
    uint*   Uxp  = (uint*)alloc((size_t)BB * 32 * NP * sizeof(uint));         // 4.2 MB
    uint*   Uyp  = (uint*)alloc((size_t)BB * 32 * NP * sizeof(uint));         // 4.2 MB
    uint*   Sb2  = (uint*)alloc((size_t)BB * 64 * NP * sizeof(uint));         // 8.5 MB
    float*  deltas = (float*)alloc((size_t)BB * 64 * LL * sizeof(float));     // 8.4 MB (plane-major)
    uint*   mp2  = (uint*)alloc((size_t)KT * 64 * 32 * sizeof(uint));         // 0.22 MB
    float*  mats = (float*)alloc((size_t)5 * 128 * 128 * sizeof(float));
    float*  term = (float*)alloc((size_t)BB * NCH * 128 * sizeof(float));
    float*  sst  = (float*)alloc((size_t)BB * NCH * 128 * sizeof(float));
    float*  qbuf = (float*)alloc((size_t)BB * NCH * 128 * sizeof(float));
    float*  Qg   = (float*)alloc((size_t)BB * 32 * 128 * sizeof(float));
    float*  q2   = (float*)alloc((size_t)BB * 32 * 128 * sizeof(float));
    float*  Sgt  = (float*)alloc((size_t)BB * 32 * 128 * sizeof(float));
    float*  Qsg  = (float*)alloc((size_t)BB * 4 * 128 * sizeof(float));
    float*  Ssg  = (float*)alloc((size_t)BB * 4 * 128 * sizeof(float));
    float*  dmy  = (float*)alloc((size_t)8 * 128 * sizeof(float));

    k_pack<<<dim3(216), dim3(256), 0, stream>>>(m_phi, m_u, mp2);
    k_fft_filters<<<dim3(24), dim3(256), 0, stream>>>(eig_vals, eig_vecs, Vb);
    k_fft_x2<<<dim3(256), dim3(512), 0, stream>>>(x, Uxp, Uyp);

    float* T1    = mats;
    float* T2    = mats + 16384;
    float* P16   = mats + 32768;
    float* P128  = mats + 49152;
    float* P1024 = mats + 65536;
    k_matsq1<<<dim3(64), dim3(256), 0, stream>>>(m_y, T1);   // M^2
    k_matsq<<<dim3(64), dim3(256), 0, stream>>>(T1, T2);     // M^4
    k_matsq<<<dim3(64), dim3(256), 0, stream>>>(T2, T1);     // M^8
    k_matsq<<<dim3(64), dim3(256), 0, stream>>>(T1, P16);    // M^16
    k_matsq<<<dim3(64), dim3(256), 0, stream>>>(P16, T1);    // M^32
    k_matsq<<<dim3(64), dim3(256), 0, stream>>>(T1, T2);     // M^64
    k_matsq<<<dim3(64), dim3(256), 0, stream>>>(T2, P128);   // M^128
    k_matsq<<<dim3(64), dim3(256), 0, stream>>>(P128, T1);   // M^256
    k_matsq<<<dim3(64), dim3(256), 0, stream>>>(T1, T2);     // M^512
    k_matsq<<<dim3(64), dim3(256), 0, stream>>>(T2, P1024);  // M^1024

    k_modulate5<<<dim3(129, 8), dim3(256), 0, stream>>>(Vb, Uxp, Uyp, mp2, Sb2);
    k_ifft2<<<dim3(256), dim3(512), 0, stream>>>(Sb2, deltas);

    k_chunk_local<<<dim3(2048), dim3(128), 0, stream>>>(deltas, m_y, term);
    k_scan<<<dim3(256), dim3(256), 0, stream>>>(P16, term, qbuf, Qg, 8);
    k_scan<<<dim3(32), dim3(256), 0, stream>>>(P128, Qg, q2, Qsg, 8);
    k_scan<<<dim3(8), dim3(256), 0, stream>>>(P1024, Qsg, Ssg, dmy, 4);
    k_fixupg<<<dim3(32), dim3(256), 0, stream>>>(P128, Ssg, q2, Sgt, 8);
    k_fixupg<<<dim3(256), dim3(256), 0, stream>>>(P16, Sgt, qbuf, sst, 8);
    k_chunk_final<<<dim3(2048), dim3(128), 0, stream>>>(deltas, m_y, sst, out);
}